// Round 6
// baseline (937.545 us; speedup 1.0000x reference)
//
#include <hip/hip_runtime.h>
#include <math.h>

// M3GNet-like GNN forward. N=10000 nodes, E=160000 edges, T=1200000 triplets,
// D=256, DM=64, H=1024, L=3, output = scalar mean energy (fp32).
//
// R22: k_ffn_fused load/compute phase separation. R21 measured VGPR=36:
// the compiler chose a min-pressure schedule ({load -> wait -> MFMA} per
// fragment) because loads were interleaved with MFMAs in source -> ~8
// exposed L2 latencies (~2000cy) per kc iteration -> 98us for a ~2us-of-
// MFMA kernel. Fix: per iteration, load ALL W2 frags + next-iter W1 frags
// + next b1 into named arrays first, then compute. W2 latency hides under
// ffn1+silu+LDS; W1(kc+1)/b1(kc+1) hide under the whole iteration.

#define DM 64
#define DMODEL 256
#define HDIM 1024

#define BSH 9            // log2(edges per bucket)
#define NBMAX 320        // max buckets (E <= 163840)
#define CAPB 4608        // passB LDS staging capacity (bucket ~3840+-62)

typedef unsigned short bf16_t;
typedef __attribute__((ext_vector_type(8))) short s8v;    // 8 bf16 (4 VGPRs)
typedef __attribute__((ext_vector_type(4))) float f4;     // MFMA acc

__device__ __forceinline__ bf16_t f2bf(float f) {
    unsigned int u = __float_as_uint(f);
    return (bf16_t)((u + 0x7FFFu + ((u >> 16) & 1u)) >> 16);   // RNE
}
__device__ __forceinline__ float bf_lo(unsigned int u) {
    return __uint_as_float(u << 16);
}
__device__ __forceinline__ float bf_hi(unsigned int u) {
    return __uint_as_float(u & 0xFFFF0000u);
}
__device__ __forceinline__ float silu_f(float u) {
    return u * __builtin_amdgcn_rcpf(1.f + __expf(-u));
}

__global__ void k_embed(const int* __restrict__ an, const float* __restrict__ emb,
                        bf16_t* __restrict__ x) {
    int n = blockIdx.x;
    int d = threadIdx.x;
    x[n * DMODEL + d] = f2bf(emb[an[n] * DMODEL + d]);
}

__global__ void k_edge_geom(const float* __restrict__ r, float* __restrict__ bl,
                            float* __restrict__ rn, int E) {
    int e = blockIdx.x * blockDim.x + threadIdx.x;
    if (e >= E) return;
    float a = r[e * 3 + 0], b = r[e * 3 + 1], c = r[e * 3 + 2];
    float l = sqrtf(a * a + b * b + c * c);
    bl[e] = l;
    float inv = 1.0f / l;
    rn[e * 3 + 0] = a * inv;
    rn[e * 3 + 1] = b * inv;
    rn[e * 3 + 2] = c * inv;
}

__global__ void k_hist(const int* __restrict__ idx, int* __restrict__ cnt, int M) {
    int t = blockIdx.x * blockDim.x + threadIdx.x;
    if (t < M) atomicAdd(&cnt[idx[t]], 1);
}

// ---- 3-phase exclusive scan (used for edge-CSR over N) ----
__global__ __launch_bounds__(256) void k_scan_part(
    const int* __restrict__ cnt, int* __restrict__ bsum, int M) {
    __shared__ int sm[4];
    int tid = threadIdx.x;
    int i = blockIdx.x * 256 + tid;
    int v = (i < M) ? cnt[i] : 0;
    for (int off = 32; off > 0; off >>= 1) v += __shfl_xor(v, off, 64);
    if ((tid & 63) == 0) sm[tid >> 6] = v;
    __syncthreads();
    if (tid == 0) bsum[blockIdx.x] = sm[0] + sm[1] + sm[2] + sm[3];
}

__global__ __launch_bounds__(1024) void k_scan_mid(int* __restrict__ bsum, int nb) {
    __shared__ int sm[1024];
    int tid = threadIdx.x;
    int v = (tid < nb) ? bsum[tid] : 0;
    sm[tid] = v;
    __syncthreads();
    for (int off = 1; off < 1024; off <<= 1) {
        int u = (tid >= off) ? sm[tid - off] : 0;
        __syncthreads();
        sm[tid] += u;
        __syncthreads();
    }
    if (tid < nb) bsum[tid] = sm[tid] - v;
}

__global__ __launch_bounds__(256) void k_scan_final(
    const int* __restrict__ cnt, const int* __restrict__ bsum,
    int* __restrict__ rowp, int M, int total) {
    __shared__ int sm[256];
    int tid = threadIdx.x;
    int i = blockIdx.x * 256 + tid;
    int v = (i < M) ? cnt[i] : 0;
    sm[tid] = v;
    __syncthreads();
    for (int off = 1; off < 256; off <<= 1) {
        int u = (tid >= off) ? sm[tid - off] : 0;
        __syncthreads();
        sm[tid] += u;
        __syncthreads();
    }
    if (i < M) rowp[i] = bsum[blockIdx.x] + sm[tid] - v;
    if (i == 0) rowp[M] = total;
}

// ---- two-level bucket sort of triplets by t_dst ----
// bucket b holds edges [b*512, b*512+512)

__global__ __launch_bounds__(512) void k_bhist(
    const int* __restrict__ td, int* __restrict__ gbcnt, int T, int NB) {
    __shared__ int h[NBMAX];
    int tid = threadIdx.x;
    for (int i = tid; i < NBMAX; i += 512) h[i] = 0;
    __syncthreads();
    int t0 = blockIdx.x * 4096;
    #pragma unroll
    for (int i = 0; i < 8; ++i) {
        int t = t0 + tid + i * 512;
        if (t < T) atomicAdd(&h[td[t] >> BSH], 1);
    }
    __syncthreads();
    for (int b = tid; b < NB; b += 512)
        if (h[b]) atomicAdd(&gbcnt[b], h[b]);
}

__global__ __launch_bounds__(512) void k_bscan(
    const int* __restrict__ gbcnt, int* __restrict__ bbase, int NB, int total) {
    __shared__ int sm[512];
    int tid = threadIdx.x;
    int v = (tid < NB) ? gbcnt[tid] : 0;
    sm[tid] = v;
    __syncthreads();
    for (int off = 1; off < 512; off <<= 1) {
        int u = (tid >= off) ? sm[tid - off] : 0;
        __syncthreads();
        sm[tid] += u;
        __syncthreads();
    }
    if (tid < NB) bbase[tid] = sm[tid] - v;
    if (tid == 0) bbase[NB] = total;
}

// passA: bin 4096 triplets into LDS by bucket, flush runs coalesced.
__global__ __launch_bounds__(512) void k_passA(
    const int* __restrict__ ts, const int* __restrict__ td,
    const float* __restrict__ rn, const int* __restrict__ bbase,
    int* __restrict__ bcur, int2* __restrict__ ipair, float* __restrict__ idv,
    int T, int NB) {
    __shared__ int   std_[4096];
    __shared__ int   ssrc[4096];
    __shared__ float sdv[4096];
    __shared__ int lbcnt[NBMAX], lbase[NBMAX], lpos[NBMAX], lgst[NBMAX],
                   lbb[NBMAX];
    __shared__ int ssc[512];
    int tid = threadIdx.x;
    int t0 = blockIdx.x * 4096;
    int total = min(4096, T - t0);
    for (int i = tid; i < NBMAX; i += 512) lbcnt[i] = 0;
    for (int i = tid; i < NB; i += 512) lbb[i] = bbase[i];
    __syncthreads();
    int   mtd[8], msrc[8];
    float md[8];
    #pragma unroll
    for (int i = 0; i < 8; ++i) {
        int idx = tid + i * 512;
        mtd[i] = -1;
        if (idx < total) {
            int t = t0 + idx;
            int a = ts[t], b = td[t];
            float d = rn[a * 3 + 0] * rn[b * 3 + 0]
                    + rn[a * 3 + 1] * rn[b * 3 + 1]
                    + rn[a * 3 + 2] * rn[b * 3 + 2];
            d = fminf(1.0f, fmaxf(-1.0f, d));
            mtd[i] = b; msrc[i] = a; md[i] = d;
            atomicAdd(&lbcnt[b >> BSH], 1);
        }
    }
    __syncthreads();
    // scan block-local bucket counts (NB <= 320 <= 512)
    int v = (tid < NB) ? lbcnt[tid] : 0;
    ssc[tid] = v;
    __syncthreads();
    for (int off = 1; off < 512; off <<= 1) {
        int u = (tid >= off) ? ssc[tid - off] : 0;
        __syncthreads();
        ssc[tid] += u;
        __syncthreads();
    }
    if (tid < NB) {
        int ex = ssc[tid] - v;
        lbase[tid] = ex;
        lpos[tid] = ex;
    }
    __syncthreads();
    // place into LDS staging grouped by bucket
    #pragma unroll
    for (int i = 0; i < 8; ++i) {
        if (mtd[i] >= 0) {
            int bin = mtd[i] >> BSH;
            int p = atomicAdd(&lpos[bin], 1);
            std_[p] = mtd[i]; ssrc[p] = msrc[i]; sdv[p] = md[i];
        }
    }
    __syncthreads();
    // reserve global runs: one atomic per (block, bucket)
    for (int b = tid; b < NB; b += 512)
        if (lbcnt[b]) lgst[b] = atomicAdd(&bcur[b], lbcnt[b]);
    __syncthreads();
    // coalesced flush of runs
    for (int j = tid; j < total; j += 512) {
        int bin = std_[j] >> BSH;
        int dest = lbb[bin] + lgst[bin] + (j - lbase[bin]);
        ipair[dest] = make_int2(std_[j], ssrc[j]);
        idv[dest] = sdv[j];
    }
}

// passB: one block per bucket; in-LDS edge hist + scan -> rowp (coalesced)
// and final packed placement flushed coalesced.
__global__ __launch_bounds__(512) void k_passB(
    const int2* __restrict__ ipair, const float* __restrict__ idv,
    const int* __restrict__ bbase, int2* __restrict__ packed,
    int* __restrict__ rowp, int E, int T) {
    __shared__ int2 spk[CAPB];
    __shared__ int hcnt[512], lcur[512], ssc[512];
    int tid = threadIdx.x;
    int b = blockIdx.x;
    int ibeg = bbase[b], iend = bbase[b + 1];
    int nb = iend - ibeg;
    int e0 = b << BSH;
    hcnt[tid] = 0;
    __syncthreads();
    for (int j = ibeg + tid; j < iend; j += 512)
        atomicAdd(&hcnt[ipair[j].x - e0], 1);
    __syncthreads();
    int v = hcnt[tid];
    ssc[tid] = v;
    __syncthreads();
    for (int off = 1; off < 512; off <<= 1) {
        int u = (tid >= off) ? ssc[tid - off] : 0;
        __syncthreads();
        ssc[tid] += u;
        __syncthreads();
    }
    int excl = ssc[tid] - v;
    lcur[tid] = excl;
    int e = e0 + tid;
    if (e < E) rowp[e] = ibeg + excl;
    if (b == 0 && tid == 0) rowp[E] = T;
    __syncthreads();
    bool staged = (nb <= CAPB);
    for (int j = ibeg + tid; j < iend; j += 512) {
        int2 pr = ipair[j];
        int pos = atomicAdd(&lcur[pr.x - e0], 1);
        int2 out = make_int2(pr.y, __float_as_int(idv[j]));
        if (staged) spk[pos] = out;
        else packed[ibeg + pos] = out;
    }
    __syncthreads();
    if (staged)
        for (int j = tid; j < nb; j += 512) packed[ibeg + j] = spk[j];
}

__global__ void k_escatter(const int* __restrict__ gd, const int* __restrict__ erowp,
                           int* __restrict__ cursor, int* __restrict__ eord, int E) {
    int e = blockIdx.x * blockDim.x + threadIdx.x;
    if (e >= E) return;
    int n = gd[e];
    int pos = erowp[n] + atomicAdd(&cursor[n], 1);
    eord[pos] = e;
}

// ---- degree bucket sort of edges (by triplet-segment length) ----
__global__ __launch_bounds__(256) void k_deghist(
    const int* __restrict__ rowp, int* __restrict__ dcnt, int E) {
    __shared__ int h[256];
    int tid = threadIdx.x;
    h[tid] = 0;
    __syncthreads();
    int e = blockIdx.x * 256 + tid;
    if (e < E) {
        int d = rowp[e + 1] - rowp[e];
        if (d > 255) d = 255;
        atomicAdd(&h[d], 1);
    }
    __syncthreads();
    if (h[tid]) atomicAdd(&dcnt[tid], h[tid]);
}

__global__ __launch_bounds__(256) void k_degscatter(
    const int* __restrict__ rowp, const int* __restrict__ doff,
    int* __restrict__ dcur, int* __restrict__ eperm, int E) {
    __shared__ int lcnt[256];
    __shared__ int base[256];
    int tid = threadIdx.x;
    lcnt[tid] = 0;
    __syncthreads();
    int e = blockIdx.x * 256 + tid;
    int d = 0, rk = 0;
    if (e < E) {
        d = rowp[e + 1] - rowp[e];
        if (d > 255) d = 255;
        rk = atomicAdd(&lcnt[d], 1);
    }
    __syncthreads();
    if (lcnt[tid]) base[tid] = atomicAdd(&dcur[tid], lcnt[tid]);
    __syncthreads();
    if (e < E) eperm[doff[d] + base[d] + rk] = e;
}

// 32x32 tiled transpose + cast: src fp32 [K][Nn] -> dst bf16 [Nn][K].
__global__ __launch_bounds__(256) void k_castT(
    const float* __restrict__ src, bf16_t* __restrict__ dst, int K, int Nn) {
    __shared__ float tile[32][33];
    int k0 = blockIdx.x * 32, n0 = blockIdx.y * 32;
    int tx = threadIdx.x & 31, ty = threadIdx.x >> 5;
    #pragma unroll
    for (int i = 0; i < 4; ++i) {
        int row = ty + i * 8;
        tile[row][tx] = src[(size_t)(k0 + row) * Nn + n0 + tx];
    }
    __syncthreads();
    #pragma unroll
    for (int i = 0; i < 4; ++i) {
        int row = ty + i * 8;
        dst[(size_t)(n0 + row) * K + k0 + tx] = f2bf(tile[tx][row]);
    }
}

// MFMA node_proj: xs = x@Wsrc + bs, xd = x@Wdst + bd (fp32 out).
__global__ __launch_bounds__(256) void k_node_proj(
    const bf16_t* __restrict__ xb,
    const bf16_t* __restrict__ Wst, const float* __restrict__ bs,
    const bf16_t* __restrict__ Wdt, const float* __restrict__ bd,
    float* __restrict__ xs, float* __restrict__ xd, int N) {
    int tid = threadIdx.x;
    int w = tid >> 6, lane = tid & 63;
    int col = lane & 15, quad = lane >> 4;
    int m0 = blockIdx.x * 64 + w * 16;
    f4 as[4] = {{0.f,0.f,0.f,0.f},{0.f,0.f,0.f,0.f},
                {0.f,0.f,0.f,0.f},{0.f,0.f,0.f,0.f}};
    f4 ad[4] = {{0.f,0.f,0.f,0.f},{0.f,0.f,0.f,0.f},
                {0.f,0.f,0.f,0.f},{0.f,0.f,0.f,0.f}};
    #pragma unroll
    for (int k0 = 0; k0 < DMODEL; k0 += 32) {
        s8v a = *(const s8v*)&xb[(size_t)(m0 + col) * DMODEL + k0 + quad * 8];
        #pragma unroll
        for (int t = 0; t < 4; ++t) {
            s8v b1v = *(const s8v*)&Wst[(size_t)(t * 16 + col) * DMODEL + k0 + quad * 8];
            as[t] = __builtin_amdgcn_mfma_f32_16x16x32_bf16(a, b1v, as[t], 0, 0, 0);
            s8v b2v = *(const s8v*)&Wdt[(size_t)(t * 16 + col) * DMODEL + k0 + quad * 8];
            ad[t] = __builtin_amdgcn_mfma_f32_16x16x32_bf16(a, b2v, ad[t], 0, 0, 0);
        }
    }
    #pragma unroll
    for (int t = 0; t < 4; ++t) {
        int c = t * 16 + col;
        float bsv = bs[c], bdv = bd[c];
        #pragma unroll
        for (int r = 0; r < 4; ++r) {
            int m = m0 + quad * 4 + r;
            if (m < N) {
                xs[(size_t)m * DM + c] = as[t][r] + bsv;
                xd[(size_t)m * DM + c] = ad[t][r] + bdv;
            }
        }
    }
}

// MFMA k_xij: xij[e][c] = (RBF(bl[e]) @ Wedge)[c] + xs[gs[e]][c] + xd[gd[e]][c] + be[c]
__global__ __launch_bounds__(256) void k_xij(
    const float* __restrict__ bl, const bf16_t* __restrict__ Wedgt,
    const float* __restrict__ be,
    const float* __restrict__ xs, const float* __restrict__ xd,
    const int* __restrict__ gs, const int* __restrict__ gd,
    bf16_t* __restrict__ xij, int E) {
    int tid = threadIdx.x;
    int w = tid >> 6, lane = tid & 63;
    int col = lane & 15, quad = lane >> 4;
    int m0 = blockIdx.x * 64 + w * 16;
    const float step = 8.0f / 255.0f;
    const float gamma = (255.0f / 8.0f) * (255.0f / 8.0f);
    int me = m0 + col;
    float blv = (me < E) ? bl[me] : 0.f;
    f4 acc[4] = {{0.f,0.f,0.f,0.f},{0.f,0.f,0.f,0.f},
                 {0.f,0.f,0.f,0.f},{0.f,0.f,0.f,0.f}};
    #pragma unroll
    for (int k0 = 0; k0 < DMODEL; k0 += 32) {
        s8v a;
        #pragma unroll
        for (int j = 0; j < 8; ++j) {
            float c = (float)(k0 + quad * 8 + j) * step;
            float dd = blv - c;
            a[j] = (short)f2bf(__expf(-gamma * dd * dd));
        }
        #pragma unroll
        for (int t = 0; t < 4; ++t) {
            s8v b = *(const s8v*)&Wedgt[(size_t)(t * 16 + col) * DMODEL + k0 + quad * 8];
            acc[t] = __builtin_amdgcn_mfma_f32_16x16x32_bf16(a, b, acc[t], 0, 0, 0);
        }
    }
    #pragma unroll
    for (int r = 0; r < 4; ++r) {
        int e = m0 + quad * 4 + r;
        if (e >= E) continue;
        int s = gs[e], d2 = gd[e];
        #pragma unroll
        for (int t = 0; t < 4; ++t) {
            int c = t * 16 + col;
            float v = acc[t][r] + xs[(size_t)s * DM + c] + xd[(size_t)d2 * DM + c] + be[c];
            xij[(size_t)e * DM + c] = f2bf(v);
        }
    }
}

// Fused logit+softmax+attend: 4 lanes per edge (degree-sorted via eperm),
// 16 channels per lane. Chebyshev T_k(d) for cos(k*theta); 2-shfl reduce.
__global__ __launch_bounds__(256) void k_edge_attn(
    const bf16_t* __restrict__ xij, const int2* __restrict__ packed,
    const int* __restrict__ rowp, const float* __restrict__ attn_l,
    const int* __restrict__ eperm, bf16_t* __restrict__ msg, int E) {
    int gtid = blockIdx.x * 256 + threadIdx.x;
    int ei = gtid >> 2;
    if (ei >= E) return;
    int q = gtid & 3;                  // channel block [16q, 16q+16)
    int e = eperm[ei];
    int beg = rowp[e], end = rowp[e + 1];

    float av[16];
    #pragma unroll
    for (int c = 0; c < 16; ++c) av[c] = attn_l[q * 16 + c];

    // my 16 channels of this edge's xij row (32B)
    uint4 xe0, xe1;
    {
        const uint4* xer = (const uint4*)&xij[(size_t)e * DM + q * 16];
        xe0 = xer[0]; xe1 = xer[1];
    }
    float acc[16];
    #pragma unroll
    for (int c = 0; c < 16; ++c) acc[c] = 0.f;
    float den = 0.f;

    if (beg < end) {
        // depth-1 pipeline priming
        int2 pk0 = packed[beg];
        int2 pk1 = (beg + 1 < end) ? packed[beg + 1] : pk0;
        const uint4* s0 = (const uint4*)&xij[(size_t)pk0.x * DM + q * 16];
        uint4 nsa = s0[0], nsb = s0[1];
        for (int p = beg; p < end; ++p) {
            float d = __int_as_float(pk0.y);
            uint4 xa = nsa, xb = nsb;
            if (p + 1 < end) {
                const uint4* sn = (const uint4*)&xij[(size_t)pk1.x * DM + q * 16];
                nsa = sn[0]; nsb = sn[1];
                pk0 = pk1;
                if (p + 2 < end) pk1 = packed[p + 2];
            }
            float d2 = d + d;
            // ladder: seeds T_{16q}, T_{16q+1} via 2TmTn = T_{m+n} + T_{|m-n|}
            float t2  = fmaf(d2, d, -1.f);
            float t3  = fmaf(d2, t2, -d);
            float t4  = fmaf(t2 + t2, t2, -1.f);
            float t7  = fmaf(t4 + t4, t3, -d);
            float t8  = fmaf(t4 + t4, t4, -1.f);
            float t15 = fmaf(t8 + t8, t7, -d);
            float t16 = fmaf(t8 + t8, t8, -1.f);
            float t17 = fmaf(t16 + t16, d, -t15);
            float t31 = fmaf(t16 + t16, t15, -d);
            float t32 = fmaf(t16 + t16, t16, -1.f);
            float t33 = fmaf(t32 + t32, d, -t31);
            float t48 = fmaf(t32 + t32, t16, -t16);
            float t49 = fmaf(t32 + t32, t17, -t15);
            float za, zb;                        // T_{16q}, T_{16q+1}
            if (q == 0)      { za = 1.f;  zb = d;   }
            else if (q == 1) { za = t16;  zb = t17; }
            else if (q == 2) { za = t32;  zb = t33; }
            else             { za = t48;  zb = t49; }
            float logit = 0.f;
            #define CH2(uw, ew, c)                                            \
            {                                                                 \
                float u0 = za + bf_lo(uw) + bf_lo(ew);                        \
                float zn = fmaf(d2, zb, -za); za = zb; zb = zn;               \
                float u1 = za + bf_hi(uw) + bf_hi(ew);                        \
                zn = fmaf(d2, zb, -za); za = zb; zb = zn;                     \
                logit = fmaf(silu_f(u0), av[c], logit);                       \
                logit = fmaf(silu_f(u1), av[c + 1], logit);                   \
            }
            CH2(xa.x, xe0.x, 0);
            CH2(xa.y, xe0.y, 2);
            CH2(xa.z, xe0.z, 4);
            CH2(xa.w, xe0.w, 6);
            CH2(xb.x, xe1.x, 8);
            CH2(xb.y, xe1.y, 10);
            CH2(xb.z, xe1.z, 12);
            CH2(xb.w, xe1.w, 14);
            #undef CH2
            // sum logit across the 4-lane group
            logit += __shfl_xor(logit, 1, 64);
            logit += __shfl_xor(logit, 2, 64);
            float wg = __expf(logit);
            den += wg;
            acc[0]  = fmaf(wg, bf_lo(xa.x), acc[0]);
            acc[1]  = fmaf(wg, bf_hi(xa.x), acc[1]);
            acc[2]  = fmaf(wg, bf_lo(xa.y), acc[2]);
            acc[3]  = fmaf(wg, bf_hi(xa.y), acc[3]);
            acc[4]  = fmaf(wg, bf_lo(xa.z), acc[4]);
            acc[5]  = fmaf(wg, bf_hi(xa.z), acc[5]);
            acc[6]  = fmaf(wg, bf_lo(xa.w), acc[6]);
            acc[7]  = fmaf(wg, bf_hi(xa.w), acc[7]);
            acc[8]  = fmaf(wg, bf_lo(xb.x), acc[8]);
            acc[9]  = fmaf(wg, bf_hi(xb.x), acc[9]);
            acc[10] = fmaf(wg, bf_lo(xb.y), acc[10]);
            acc[11] = fmaf(wg, bf_hi(xb.y), acc[11]);
            acc[12] = fmaf(wg, bf_lo(xb.z), acc[12]);
            acc[13] = fmaf(wg, bf_hi(xb.z), acc[13]);
            acc[14] = fmaf(wg, bf_lo(xb.w), acc[14]);
            acc[15] = fmaf(wg, bf_hi(xb.w), acc[15]);
        }
    }
    float inv = (den > 0.f) ? 1.f / den : 0.f;
    uint4 o0, o1;
    o0.x = (unsigned int)f2bf(acc[0] * inv)  | ((unsigned int)f2bf(acc[1] * inv) << 16);
    o0.y = (unsigned int)f2bf(acc[2] * inv)  | ((unsigned int)f2bf(acc[3] * inv) << 16);
    o0.z = (unsigned int)f2bf(acc[4] * inv)  | ((unsigned int)f2bf(acc[5] * inv) << 16);
    o0.w = (unsigned int)f2bf(acc[6] * inv)  | ((unsigned int)f2bf(acc[7] * inv) << 16);
    o1.x = (unsigned int)f2bf(acc[8] * inv)  | ((unsigned int)f2bf(acc[9] * inv) << 16);
    o1.y = (unsigned int)f2bf(acc[10] * inv) | ((unsigned int)f2bf(acc[11] * inv) << 16);
    o1.z = (unsigned int)f2bf(acc[12] * inv) | ((unsigned int)f2bf(acc[13] * inv) << 16);
    o1.w = (unsigned int)f2bf(acc[14] * inv) | ((unsigned int)f2bf(acc[15] * inv) << 16);
    uint4* op = (uint4*)&msg[(size_t)e * DM + q * 16];
    op[0] = o0;
    op[1] = o1;
}

// thread per (node, channel-quad): sum bf16 msg -> bf16 ft.
__global__ __launch_bounds__(256) void k_aggregate(
    const bf16_t* __restrict__ msg, const int* __restrict__ erowp,
    const int* __restrict__ eord, bf16_t* __restrict__ ft, int N) {
    int gtid = blockIdx.x * 256 + threadIdx.x;
    int n = gtid >> 4;
    if (n >= N) return;
    int quad = gtid & 15;
    int beg = erowp[n], end = erowp[n + 1];
    float a0 = 0.f, a1 = 0.f, a2 = 0.f, a3 = 0.f;
    for (int j = beg; j < end; ++j) {
        uint2 uv = *(const uint2*)&msg[(size_t)eord[j] * DM + quad * 4];
        a0 += bf_lo(uv.x); a1 += bf_hi(uv.x);
        a2 += bf_lo(uv.y); a3 += bf_hi(uv.y);
    }
    ushort4 o = {f2bf(a0), f2bf(a1), f2bf(a2), f2bf(a3)};
    *(ushort4*)&ft[(size_t)n * DM + quad * 4] = o;
}

// Fused FFN: x = silu(ft@W1 + b1) @ W2 + b2; h never leaves the CU.
// Grid (N/64, 4): blockIdx.y owns 64 output cols. Block = 64 rows, 4 waves;
// wave = 16 rows x 64 cols. Per kc iteration: LOAD PHASE (all 8 W2 frags,
// all 8 next-iter W1 frags, next b1 quad into named arrays) then COMPUTE
// PHASE (ffn1 MFMA -> silu -> LDS relayout -> ffn2 MFMA) with no loads in
// between. R21's interleaved source let the compiler pick a VGPR=36
// min-pressure schedule with ~8 exposed L2 latencies per iteration.
__global__ __launch_bounds__(256) void k_ffn_fused(
    const bf16_t* __restrict__ ft, const bf16_t* __restrict__ W1t,
    const float* __restrict__ b1, const bf16_t* __restrict__ W2t,
    const float* __restrict__ b2, bf16_t* __restrict__ x, int N) {
    __shared__ bf16_t hld[4][16 * 72];
    int tid = threadIdx.x;
    int w = tid >> 6, lane = tid & 63;
    int col = lane & 15, quad = lane >> 4;
    int m0 = blockIdx.x * 64 + w * 16;
    int c0 = blockIdx.y * 64;                 // this block's output columns
    bf16_t* myl = hld[w];

    // ft A-fragments for this wave's 16 rows (k = 0..63), held all kernel
    s8v fa0 = *(const s8v*)&ft[(size_t)(m0 + col) * DM + quad * 8];
    s8v fa1 = *(const s8v*)&ft[(size_t)(m0 + col) * DM + 32 + quad * 8];

    f4 acc[4] = {{0.f,0.f,0.f,0.f},{0.f,0.f,0.f,0.f},
                 {0.f,0.f,0.f,0.f},{0.f,0.f,0.f,0.f}};

    // prefetch kc=0 W1 fragments + b1 values
    s8v w1a[4], w1b[4];
    float bcur[4];
    #pragma unroll
    for (int th = 0; th < 4; ++th) {
        const bf16_t* p = &W1t[(size_t)(th * 16 + col) * DM + quad * 8];
        w1a[th] = *(const s8v*)p;
        w1b[th] = *(const s8v*)(p + 32);
        bcur[th] = b1[th * 16 + col];
    }

    #pragma unroll 1
    for (int kc = 0; kc < 16; ++kc) {         // h-col chunks of 64
        int ch0 = kc * 64;
        int chn = (kc < 15) ? ch0 + 64 : ch0;  // clamped next-chunk base
        // ---- LOAD PHASE: issue everything this iteration needs ----
        s8v w2a[4], w2b[4];
        #pragma unroll
        for (int t2 = 0; t2 < 4; ++t2) {
            const bf16_t* p =
                &W2t[(size_t)(c0 + t2 * 16 + col) * HDIM + ch0 + quad * 8];
            w2a[t2] = *(const s8v*)p;
            w2b[t2] = *(const s8v*)(p + 32);
        }
        s8v n1a[4], n1b[4];
        float bnxt[4];
        #pragma unroll
        for (int th = 0; th < 4; ++th) {
            const bf16_t* p = &W1t[(size_t)(chn + th * 16 + col) * DM + quad * 8];
            n1a[th] = *(const s8v*)p;
            n1b[th] = *(const s8v*)(p + 32);
            bnxt[th] = b1[chn + th * 16 + col];
        }
        // ---- COMPUTE PHASE: no global loads below ----
        // ffn1: h[m0..+16][ch0..+64] = silu(ft @ W1 + b1) -> LDS
        #pragma unroll
        for (int th = 0; th < 4; ++th) {
            f4 hv = {0.f, 0.f, 0.f, 0.f};
            hv = __builtin_amdgcn_mfma_f32_16x16x32_bf16(fa0, w1a[th], hv, 0, 0, 0);
            hv = __builtin_amdgcn_mfma_f32_16x16x32_bf16(fa1, w1b[th], hv, 0, 0, 0);
            #pragma unroll
            for (int r = 0; r < 4; ++r)
                myl[(quad * 4 + r) * 72 + th * 16 + col] =
                    f2bf(silu_f(hv[r] + bcur[th]));
        }
        // A-fragments of h (wave-private tile; compiler emits lgkmcnt waits)
        s8v ha0 = *(const s8v*)&myl[col * 72 + quad * 8];
        s8v ha1 = *(const s8v*)&myl[col * 72 + 32 + quad * 8];
        // ffn2 partial: acc += h_chunk @ W2[ch0..ch0+64][c0..c0+64]
        #pragma unroll
        for (int t2 = 0; t2 < 4; ++t2) {
            acc[t2] = __builtin_amdgcn_mfma_f32_16x16x32_bf16(ha0, w2a[t2], acc[t2], 0, 0, 0);
            acc[t2] = __builtin_amdgcn_mfma_f32_16x16x32_bf16(ha1, w2b[t2], acc[t2], 0, 0, 0);
        }
        // rotate W1 pipeline
        #pragma unroll
        for (int th = 0; th < 4; ++th) {
            w1a[th] = n1a[th];
            w1b[th] = n1b[th];
            bcur[th] = bnxt[th];
        }
    }
    #pragma unroll
    for (int t2 = 0; t2 < 4; ++t2) {
        int c = c0 + t2 * 16 + col;
        float bb = b2[c];
        #pragma unroll
        for (int r = 0; r < 4; ++r) {
            int m = m0 + quad * 4 + r;
            if (m < N) x[(size_t)m * DMODEL + c] = f2bf(acc[t2][r] + bb);
        }
    }
}

// grid-stride dot over bf16 x, one atomic per block.
__global__ __launch_bounds__(256) void k_out_reduce(
    const bf16_t* __restrict__ x, const float* __restrict__ Wfc,
    float* __restrict__ acc, int NT) {
    __shared__ float sm[4];
    int tid = threadIdx.x;
    float v = 0.f;
    int np = NT / 2;
    const unsigned int* xp = (const unsigned int*)x;
    for (int i = blockIdx.x * blockDim.x + tid; i < np; i += gridDim.x * blockDim.x) {
        unsigned int u = xp[i];
        int c = (2 * i) & (DMODEL - 1);
        v = fmaf(bf_lo(u), Wfc[c], v);
        v = fmaf(bf_hi(u), Wfc[c + 1], v);
    }
    for (int off = 32; off > 0; off >>= 1) v += __shfl_xor(v, off, 64);
    if ((tid & 63) == 0) sm[tid >> 6] = v;
    __syncthreads();
    if (tid == 0) {
        float s = sm[0] + sm[1] + sm[2] + sm[3];
        atomicAdd(acc, s);
    }
}

__global__ void k_out_final(const float* __restrict__ acc, const float* __restrict__ bfc,
                            float* __restrict__ out, float invN) {
    out[0] = acc[0] * invN + bfc[0];
}

extern "C" void kernel_launch(void* const* d_in, const int* in_sizes, int n_in,
                              void* d_out, int out_size, void* d_ws, size_t ws_size,
                              hipStream_t stream) {
    const int*   an    = (const int*)d_in[0];
    const int*   gs    = (const int*)d_in[1];
    const int*   gd    = (const int*)d_in[2];
    const int*   ts    = (const int*)d_in[3];
    const int*   td    = (const int*)d_in[4];
    const float* r     = (const float*)d_in[5];
    const float* emb   = (const float*)d_in[6];
    const float* Wsrc  = (const float*)d_in[7];
    const float* bsrc  = (const float*)d_in[8];
    const float* Wdst  = (const float*)d_in[9];
    const float* bdst  = (const float*)d_in[10];
    const float* Wedge = (const float*)d_in[11];
    const float* bedge = (const float*)d_in[12];
    const float* attn  = (const float*)d_in[13];
    const float* W1    = (const float*)d_in[14];
    const float* b1    = (const float*)d_in[15];
    const float* W2    = (const float*)d_in[16];
    const float* b2    = (const float*)d_in[17];
    const float* Wfc   = (const float*)d_in[18];
    const float* bfc   = (const float*)d_in[19];

    const int N = in_sizes[0];
    const int E = in_sizes[1];
    const int T = in_sizes[3];
    const int NB = (E + 511) >> BSH;          // triplet-sort buckets

    char* w = (char*)d_ws;
    size_t off = 0;
    auto alloc = [&](size_t bytes) {
        void* p = w + off;
        off += (bytes + 255) & ~(size_t)255;
        return p;
    };
    bf16_t* xb     = (bf16_t*)alloc((size_t)(N + 64) * DMODEL * 2);
    float*  rn     = (float*) alloc((size_t)E * 3 * 4);
    float*  bl     = (float*) alloc(((size_t)E + 64) * 4);
    int*    rowp   = (int*)   alloc(((size_t)E + 1) * 4);
    int*    bsum   = (int*)   alloc(4096);
    int2*   packed = (int2*)  alloc((size_t)T * 8);
    int2*   ipair  = (int2*)  alloc((size_t)T * 8);
    float*  idv    = (float*) alloc((size_t)T * 4);
    int*    gbcnt  = (int*)   alloc(NBMAX * 4);
    int*    bbase  = (int*)   alloc((NBMAX + 1) * 4);
    int*    bcur   = (int*)   alloc(NBMAX * 4);
    int*    ecnt   = (int*)   alloc((size_t)N * 4);
    int*    erowp  = (int*)   alloc(((size_t)N + 1) * 4);
    int*    eord   = (int*)   alloc((size_t)E * 4);
    int*    eperm  = (int*)   alloc((size_t)E * 4);
    int*    dcnt   = (int*)   alloc(1024);
    int*    dcur   = (int*)   alloc(1024);
    float*  xs     = (float*) alloc((size_t)N * DM * 4);
    float*  xd     = (float*) alloc((size_t)N * DM * 4);
    bf16_t* xij    = (bf16_t*)alloc((size_t)E * DM * 2);
    bf16_t* msg    = (bf16_t*)alloc((size_t)E * DM * 2);
    bf16_t* ft     = (bf16_t*)alloc((size_t)(N + 64) * DM * 2);
    bf16_t* W1t    = (bf16_t*)alloc((size_t)3 * HDIM * DM * 2);
    bf16_t* W2t    = (bf16_t*)alloc((size_t)3 * DMODEL * HDIM * 2);
    bf16_t* Wedgt  = (bf16_t*)alloc((size_t)3 * DM * DMODEL * 2);
    bf16_t* Wst    = (bf16_t*)alloc((size_t)3 * DM * DMODEL * 2);
    bf16_t* Wdt    = (bf16_t*)alloc((size_t)3 * DM * DMODEL * 2);
    float*  accs   = (float*) alloc(64);
    (void)ws_size; (void)n_in; (void)out_size;

    const int nbScanN = (N + 255) / 256;
    const int nbT = (T + 4095) / 4096;

    // ---- setup (layer-invariant) ----
    k_embed<<<N, 256, 0, stream>>>(an, emb, xb);
    k_edge_geom<<<(E + 255) / 256, 256, 0, stream>>>(r, bl, rn, E);
    for (int l = 0; l < 3; ++l) {
        k_castT<<<dim3(DM / 32, HDIM / 32), 256, 0, stream>>>(
            W1 + (size_t)l * DM * HDIM, W1t + (size_t)l * HDIM * DM, DM, HDIM);
        k_castT<<<dim3(HDIM / 32, DMODEL / 32), 256, 0, stream>>>(
            W2 + (size_t)l * HDIM * DMODEL, W2t + (size_t)l * DMODEL * HDIM,
            HDIM, DMODEL);
        k_castT<<<dim3(DMODEL / 32, DM / 32), 256, 0, stream>>>(
            Wedge + (size_t)l * DMODEL * DM, Wedgt + (size_t)l * DM * DMODEL,
            DMODEL, DM);
        k_castT<<<dim3(DMODEL / 32, DM / 32), 256, 0, stream>>>(
            Wsrc + (size_t)l * DMODEL * DM, Wst + (size_t)l * DM * DMODEL,
            DMODEL, DM);
        k_castT<<<dim3(DMODEL / 32, DM / 32), 256, 0, stream>>>(
            Wdst + (size_t)l * DMODEL * DM, Wdt + (size_t)l * DM * DMODEL,
            DMODEL, DM);
    }
    // triplet CSR by t_dst: two-level bucket sort, all writes coalesced
    hipMemsetAsync(gbcnt, 0, NBMAX * 4, stream);
    hipMemsetAsync(bcur, 0, NBMAX * 4, stream);
    k_bhist<<<nbT, 512, 0, stream>>>(td, gbcnt, T, NB);
    k_bscan<<<1, 512, 0, stream>>>(gbcnt, bbase, NB, T);
    k_passA<<<nbT, 512, 0, stream>>>(ts, td, rn, bbase, bcur, ipair, idv, T, NB);
    k_passB<<<NB, 512, 0, stream>>>(ipair, idv, bbase, packed, rowp, E, T);
    // degree-sorted edge permutation (for k_edge_attn load balance)
    hipMemsetAsync(dcnt, 0, 1024, stream);
    hipMemsetAsync(dcur, 0, 1024, stream);
    k_deghist<<<(E + 255) / 256, 256, 0, stream>>>(rowp, dcnt, E);
    k_scan_mid<<<1, 1024, 0, stream>>>(dcnt, 256);
    k_degscatter<<<(E + 255) / 256, 256, 0, stream>>>(rowp, dcnt, dcur, eperm, E);
    // edge CSR by gd
    hipMemsetAsync(ecnt, 0, (size_t)N * 4, stream);
    k_hist<<<(E + 255) / 256, 256, 0, stream>>>(gd, ecnt, E);
    k_scan_part<<<nbScanN, 256, 0, stream>>>(ecnt, bsum, N);
    k_scan_mid<<<1, 1024, 0, stream>>>(bsum, nbScanN);
    k_scan_final<<<nbScanN, 256, 0, stream>>>(ecnt, bsum, erowp, N, E);
    hipMemsetAsync(ecnt, 0, (size_t)N * 4, stream);
    k_escatter<<<(E + 255) / 256, 256, 0, stream>>>(gd, erowp, ecnt, eord, E);

    // ---- layers ----
    for (int l = 0; l < 3; ++l) {
        k_node_proj<<<(N + 63) / 64, 256, 0, stream>>>(
            xb, Wst + (size_t)l * DM * DMODEL, bsrc + l * DM,
            Wdt + (size_t)l * DM * DMODEL, bdst + l * DM, xs, xd, N);
        k_xij<<<(E + 63) / 64, 256, 0, stream>>>(
            bl, Wedgt + (size_t)l * DM * DMODEL, bedge + l * DM,
            xs, xd, gs, gd, xij, E);
        k_edge_attn<<<(E * 4 + 255) / 256, 256, 0, stream>>>(
            xij, packed, rowp, attn + l * DM, eperm, msg, E);
        k_aggregate<<<(N * 16 + 255) / 256, 256, 0, stream>>>(
            msg, erowp, eord, ft, N);
        k_ffn_fused<<<dim3((N + 63) / 64, 4), 256, 0, stream>>>(
            ft, W1t + (size_t)l * HDIM * DM, b1 + l * HDIM,
            W2t + (size_t)l * DMODEL * HDIM, b2 + l * DMODEL, xb, N);
    }

    // ---- output head ----
    hipMemsetAsync(accs, 0, 4, stream);
    k_out_reduce<<<120, 256, 0, stream>>>(xb, Wfc, accs, N * DMODEL);
    k_out_final<<<1, 1, 0, stream>>>(accs, bfc, (float*)d_out, 1.0f / (float)N);
}

// Round 7
// 755.701 us; speedup vs baseline: 1.2406x; 1.2406x over previous
//
#include <hip/hip_runtime.h>
#include <math.h>

// M3GNet-like GNN forward. N=10000 nodes, E=160000 edges, T=1200000 triplets,
// D=256, DM=64, H=1024, L=3, output = scalar mean energy (fp32).
//
// R23: k_ffn_fused weights -> LDS double-buffer. R21/R22 proved hipcc will
// not hold global-load prefetch in VGPRs across the kc loop (VGPR 72,
// ~14K-cycle serial chain per iteration = serialized L2 latencies; 97us).
// The compiler DOES schedule ds_read->MFMA near-optimally (m97 evidence),
// so: per iteration, stage next {W1,W2} 64x64 chunk global->reg (16 VGPR),
// compute current chunk from LDS (pad-72 rows: frag reads 2-way = free),
// barrier, ds_write staged regs to alternate buffer, barrier. b1 lives in
// LDS too (loaded once). Numerics bit-identical to R19's unfused path.

#define DM 64
#define DMODEL 256
#define HDIM 1024

#define BSH 9            // log2(edges per bucket)
#define NBMAX 320        // max buckets (E <= 163840)
#define CAPB 4608        // passB LDS staging capacity (bucket ~3840+-62)

typedef unsigned short bf16_t;
typedef __attribute__((ext_vector_type(8))) short s8v;    // 8 bf16 (4 VGPRs)
typedef __attribute__((ext_vector_type(4))) float f4;     // MFMA acc

__device__ __forceinline__ bf16_t f2bf(float f) {
    unsigned int u = __float_as_uint(f);
    return (bf16_t)((u + 0x7FFFu + ((u >> 16) & 1u)) >> 16);   // RNE
}
__device__ __forceinline__ float bf_lo(unsigned int u) {
    return __uint_as_float(u << 16);
}
__device__ __forceinline__ float bf_hi(unsigned int u) {
    return __uint_as_float(u & 0xFFFF0000u);
}
__device__ __forceinline__ float silu_f(float u) {
    return u * __builtin_amdgcn_rcpf(1.f + __expf(-u));
}

__global__ void k_embed(const int* __restrict__ an, const float* __restrict__ emb,
                        bf16_t* __restrict__ x) {
    int n = blockIdx.x;
    int d = threadIdx.x;
    x[n * DMODEL + d] = f2bf(emb[an[n] * DMODEL + d]);
}

__global__ void k_edge_geom(const float* __restrict__ r, float* __restrict__ bl,
                            float* __restrict__ rn, int E) {
    int e = blockIdx.x * blockDim.x + threadIdx.x;
    if (e >= E) return;
    float a = r[e * 3 + 0], b = r[e * 3 + 1], c = r[e * 3 + 2];
    float l = sqrtf(a * a + b * b + c * c);
    bl[e] = l;
    float inv = 1.0f / l;
    rn[e * 3 + 0] = a * inv;
    rn[e * 3 + 1] = b * inv;
    rn[e * 3 + 2] = c * inv;
}

__global__ void k_hist(const int* __restrict__ idx, int* __restrict__ cnt, int M) {
    int t = blockIdx.x * blockDim.x + threadIdx.x;
    if (t < M) atomicAdd(&cnt[idx[t]], 1);
}

// ---- 3-phase exclusive scan (used for edge-CSR over N) ----
__global__ __launch_bounds__(256) void k_scan_part(
    const int* __restrict__ cnt, int* __restrict__ bsum, int M) {
    __shared__ int sm[4];
    int tid = threadIdx.x;
    int i = blockIdx.x * 256 + tid;
    int v = (i < M) ? cnt[i] : 0;
    for (int off = 32; off > 0; off >>= 1) v += __shfl_xor(v, off, 64);
    if ((tid & 63) == 0) sm[tid >> 6] = v;
    __syncthreads();
    if (tid == 0) bsum[blockIdx.x] = sm[0] + sm[1] + sm[2] + sm[3];
}

__global__ __launch_bounds__(1024) void k_scan_mid(int* __restrict__ bsum, int nb) {
    __shared__ int sm[1024];
    int tid = threadIdx.x;
    int v = (tid < nb) ? bsum[tid] : 0;
    sm[tid] = v;
    __syncthreads();
    for (int off = 1; off < 1024; off <<= 1) {
        int u = (tid >= off) ? sm[tid - off] : 0;
        __syncthreads();
        sm[tid] += u;
        __syncthreads();
    }
    if (tid < nb) bsum[tid] = sm[tid] - v;
}

__global__ __launch_bounds__(256) void k_scan_final(
    const int* __restrict__ cnt, const int* __restrict__ bsum,
    int* __restrict__ rowp, int M, int total) {
    __shared__ int sm[256];
    int tid = threadIdx.x;
    int i = blockIdx.x * 256 + tid;
    int v = (i < M) ? cnt[i] : 0;
    sm[tid] = v;
    __syncthreads();
    for (int off = 1; off < 256; off <<= 1) {
        int u = (tid >= off) ? sm[tid - off] : 0;
        __syncthreads();
        sm[tid] += u;
        __syncthreads();
    }
    if (i < M) rowp[i] = bsum[blockIdx.x] + sm[tid] - v;
    if (i == 0) rowp[M] = total;
}

// ---- two-level bucket sort of triplets by t_dst ----
// bucket b holds edges [b*512, b*512+512)

__global__ __launch_bounds__(512) void k_bhist(
    const int* __restrict__ td, int* __restrict__ gbcnt, int T, int NB) {
    __shared__ int h[NBMAX];
    int tid = threadIdx.x;
    for (int i = tid; i < NBMAX; i += 512) h[i] = 0;
    __syncthreads();
    int t0 = blockIdx.x * 4096;
    #pragma unroll
    for (int i = 0; i < 8; ++i) {
        int t = t0 + tid + i * 512;
        if (t < T) atomicAdd(&h[td[t] >> BSH], 1);
    }
    __syncthreads();
    for (int b = tid; b < NB; b += 512)
        if (h[b]) atomicAdd(&gbcnt[b], h[b]);
}

__global__ __launch_bounds__(512) void k_bscan(
    const int* __restrict__ gbcnt, int* __restrict__ bbase, int NB, int total) {
    __shared__ int sm[512];
    int tid = threadIdx.x;
    int v = (tid < NB) ? gbcnt[tid] : 0;
    sm[tid] = v;
    __syncthreads();
    for (int off = 1; off < 512; off <<= 1) {
        int u = (tid >= off) ? sm[tid - off] : 0;
        __syncthreads();
        sm[tid] += u;
        __syncthreads();
    }
    if (tid < NB) bbase[tid] = sm[tid] - v;
    if (tid == 0) bbase[NB] = total;
}

// passA: bin 4096 triplets into LDS by bucket, flush runs coalesced.
__global__ __launch_bounds__(512) void k_passA(
    const int* __restrict__ ts, const int* __restrict__ td,
    const float* __restrict__ rn, const int* __restrict__ bbase,
    int* __restrict__ bcur, int2* __restrict__ ipair, float* __restrict__ idv,
    int T, int NB) {
    __shared__ int   std_[4096];
    __shared__ int   ssrc[4096];
    __shared__ float sdv[4096];
    __shared__ int lbcnt[NBMAX], lbase[NBMAX], lpos[NBMAX], lgst[NBMAX],
                   lbb[NBMAX];
    __shared__ int ssc[512];
    int tid = threadIdx.x;
    int t0 = blockIdx.x * 4096;
    int total = min(4096, T - t0);
    for (int i = tid; i < NBMAX; i += 512) lbcnt[i] = 0;
    for (int i = tid; i < NB; i += 512) lbb[i] = bbase[i];
    __syncthreads();
    int   mtd[8], msrc[8];
    float md[8];
    #pragma unroll
    for (int i = 0; i < 8; ++i) {
        int idx = tid + i * 512;
        mtd[i] = -1;
        if (idx < total) {
            int t = t0 + idx;
            int a = ts[t], b = td[t];
            float d = rn[a * 3 + 0] * rn[b * 3 + 0]
                    + rn[a * 3 + 1] * rn[b * 3 + 1]
                    + rn[a * 3 + 2] * rn[b * 3 + 2];
            d = fminf(1.0f, fmaxf(-1.0f, d));
            mtd[i] = b; msrc[i] = a; md[i] = d;
            atomicAdd(&lbcnt[b >> BSH], 1);
        }
    }
    __syncthreads();
    // scan block-local bucket counts (NB <= 320 <= 512)
    int v = (tid < NB) ? lbcnt[tid] : 0;
    ssc[tid] = v;
    __syncthreads();
    for (int off = 1; off < 512; off <<= 1) {
        int u = (tid >= off) ? ssc[tid - off] : 0;
        __syncthreads();
        ssc[tid] += u;
        __syncthreads();
    }
    if (tid < NB) {
        int ex = ssc[tid] - v;
        lbase[tid] = ex;
        lpos[tid] = ex;
    }
    __syncthreads();
    // place into LDS staging grouped by bucket
    #pragma unroll
    for (int i = 0; i < 8; ++i) {
        if (mtd[i] >= 0) {
            int bin = mtd[i] >> BSH;
            int p = atomicAdd(&lpos[bin], 1);
            std_[p] = mtd[i]; ssrc[p] = msrc[i]; sdv[p] = md[i];
        }
    }
    __syncthreads();
    // reserve global runs: one atomic per (block, bucket)
    for (int b = tid; b < NB; b += 512)
        if (lbcnt[b]) lgst[b] = atomicAdd(&bcur[b], lbcnt[b]);
    __syncthreads();
    // coalesced flush of runs
    for (int j = tid; j < total; j += 512) {
        int bin = std_[j] >> BSH;
        int dest = lbb[bin] + lgst[bin] + (j - lbase[bin]);
        ipair[dest] = make_int2(std_[j], ssrc[j]);
        idv[dest] = sdv[j];
    }
}

// passB: one block per bucket; in-LDS edge hist + scan -> rowp (coalesced)
// and final packed placement flushed coalesced.
__global__ __launch_bounds__(512) void k_passB(
    const int2* __restrict__ ipair, const float* __restrict__ idv,
    const int* __restrict__ bbase, int2* __restrict__ packed,
    int* __restrict__ rowp, int E, int T) {
    __shared__ int2 spk[CAPB];
    __shared__ int hcnt[512], lcur[512], ssc[512];
    int tid = threadIdx.x;
    int b = blockIdx.x;
    int ibeg = bbase[b], iend = bbase[b + 1];
    int nb = iend - ibeg;
    int e0 = b << BSH;
    hcnt[tid] = 0;
    __syncthreads();
    for (int j = ibeg + tid; j < iend; j += 512)
        atomicAdd(&hcnt[ipair[j].x - e0], 1);
    __syncthreads();
    int v = hcnt[tid];
    ssc[tid] = v;
    __syncthreads();
    for (int off = 1; off < 512; off <<= 1) {
        int u = (tid >= off) ? ssc[tid - off] : 0;
        __syncthreads();
        ssc[tid] += u;
        __syncthreads();
    }
    int excl = ssc[tid] - v;
    lcur[tid] = excl;
    int e = e0 + tid;
    if (e < E) rowp[e] = ibeg + excl;
    if (b == 0 && tid == 0) rowp[E] = T;
    __syncthreads();
    bool staged = (nb <= CAPB);
    for (int j = ibeg + tid; j < iend; j += 512) {
        int2 pr = ipair[j];
        int pos = atomicAdd(&lcur[pr.x - e0], 1);
        int2 out = make_int2(pr.y, __float_as_int(idv[j]));
        if (staged) spk[pos] = out;
        else packed[ibeg + pos] = out;
    }
    __syncthreads();
    if (staged)
        for (int j = tid; j < nb; j += 512) packed[ibeg + j] = spk[j];
}

__global__ void k_escatter(const int* __restrict__ gd, const int* __restrict__ erowp,
                           int* __restrict__ cursor, int* __restrict__ eord, int E) {
    int e = blockIdx.x * blockDim.x + threadIdx.x;
    if (e >= E) return;
    int n = gd[e];
    int pos = erowp[n] + atomicAdd(&cursor[n], 1);
    eord[pos] = e;
}

// ---- degree bucket sort of edges (by triplet-segment length) ----
__global__ __launch_bounds__(256) void k_deghist(
    const int* __restrict__ rowp, int* __restrict__ dcnt, int E) {
    __shared__ int h[256];
    int tid = threadIdx.x;
    h[tid] = 0;
    __syncthreads();
    int e = blockIdx.x * 256 + tid;
    if (e < E) {
        int d = rowp[e + 1] - rowp[e];
        if (d > 255) d = 255;
        atomicAdd(&h[d], 1);
    }
    __syncthreads();
    if (h[tid]) atomicAdd(&dcnt[tid], h[tid]);
}

__global__ __launch_bounds__(256) void k_degscatter(
    const int* __restrict__ rowp, const int* __restrict__ doff,
    int* __restrict__ dcur, int* __restrict__ eperm, int E) {
    __shared__ int lcnt[256];
    __shared__ int base[256];
    int tid = threadIdx.x;
    lcnt[tid] = 0;
    __syncthreads();
    int e = blockIdx.x * 256 + tid;
    int d = 0, rk = 0;
    if (e < E) {
        d = rowp[e + 1] - rowp[e];
        if (d > 255) d = 255;
        rk = atomicAdd(&lcnt[d], 1);
    }
    __syncthreads();
    if (lcnt[tid]) base[tid] = atomicAdd(&dcur[tid], lcnt[tid]);
    __syncthreads();
    if (e < E) eperm[doff[d] + base[d] + rk] = e;
}

// 32x32 tiled transpose + cast: src fp32 [K][Nn] -> dst bf16 [Nn][K].
__global__ __launch_bounds__(256) void k_castT(
    const float* __restrict__ src, bf16_t* __restrict__ dst, int K, int Nn) {
    __shared__ float tile[32][33];
    int k0 = blockIdx.x * 32, n0 = blockIdx.y * 32;
    int tx = threadIdx.x & 31, ty = threadIdx.x >> 5;
    #pragma unroll
    for (int i = 0; i < 4; ++i) {
        int row = ty + i * 8;
        tile[row][tx] = src[(size_t)(k0 + row) * Nn + n0 + tx];
    }
    __syncthreads();
    #pragma unroll
    for (int i = 0; i < 4; ++i) {
        int row = ty + i * 8;
        dst[(size_t)(n0 + row) * K + k0 + tx] = f2bf(tile[tx][row]);
    }
}

// MFMA node_proj: xs = x@Wsrc + bs, xd = x@Wdst + bd (fp32 out).
__global__ __launch_bounds__(256) void k_node_proj(
    const bf16_t* __restrict__ xb,
    const bf16_t* __restrict__ Wst, const float* __restrict__ bs,
    const bf16_t* __restrict__ Wdt, const float* __restrict__ bd,
    float* __restrict__ xs, float* __restrict__ xd, int N) {
    int tid = threadIdx.x;
    int w = tid >> 6, lane = tid & 63;
    int col = lane & 15, quad = lane >> 4;
    int m0 = blockIdx.x * 64 + w * 16;
    f4 as[4] = {{0.f,0.f,0.f,0.f},{0.f,0.f,0.f,0.f},
                {0.f,0.f,0.f,0.f},{0.f,0.f,0.f,0.f}};
    f4 ad[4] = {{0.f,0.f,0.f,0.f},{0.f,0.f,0.f,0.f},
                {0.f,0.f,0.f,0.f},{0.f,0.f,0.f,0.f}};
    #pragma unroll
    for (int k0 = 0; k0 < DMODEL; k0 += 32) {
        s8v a = *(const s8v*)&xb[(size_t)(m0 + col) * DMODEL + k0 + quad * 8];
        #pragma unroll
        for (int t = 0; t < 4; ++t) {
            s8v b1v = *(const s8v*)&Wst[(size_t)(t * 16 + col) * DMODEL + k0 + quad * 8];
            as[t] = __builtin_amdgcn_mfma_f32_16x16x32_bf16(a, b1v, as[t], 0, 0, 0);
            s8v b2v = *(const s8v*)&Wdt[(size_t)(t * 16 + col) * DMODEL + k0 + quad * 8];
            ad[t] = __builtin_amdgcn_mfma_f32_16x16x32_bf16(a, b2v, ad[t], 0, 0, 0);
        }
    }
    #pragma unroll
    for (int t = 0; t < 4; ++t) {
        int c = t * 16 + col;
        float bsv = bs[c], bdv = bd[c];
        #pragma unroll
        for (int r = 0; r < 4; ++r) {
            int m = m0 + quad * 4 + r;
            if (m < N) {
                xs[(size_t)m * DM + c] = as[t][r] + bsv;
                xd[(size_t)m * DM + c] = ad[t][r] + bdv;
            }
        }
    }
}

// MFMA k_xij: xij[e][c] = (RBF(bl[e]) @ Wedge)[c] + xs[gs[e]][c] + xd[gd[e]][c] + be[c]
__global__ __launch_bounds__(256) void k_xij(
    const float* __restrict__ bl, const bf16_t* __restrict__ Wedgt,
    const float* __restrict__ be,
    const float* __restrict__ xs, const float* __restrict__ xd,
    const int* __restrict__ gs, const int* __restrict__ gd,
    bf16_t* __restrict__ xij, int E) {
    int tid = threadIdx.x;
    int w = tid >> 6, lane = tid & 63;
    int col = lane & 15, quad = lane >> 4;
    int m0 = blockIdx.x * 64 + w * 16;
    const float step = 8.0f / 255.0f;
    const float gamma = (255.0f / 8.0f) * (255.0f / 8.0f);
    int me = m0 + col;
    float blv = (me < E) ? bl[me] : 0.f;
    f4 acc[4] = {{0.f,0.f,0.f,0.f},{0.f,0.f,0.f,0.f},
                 {0.f,0.f,0.f,0.f},{0.f,0.f,0.f,0.f}};
    #pragma unroll
    for (int k0 = 0; k0 < DMODEL; k0 += 32) {
        s8v a;
        #pragma unroll
        for (int j = 0; j < 8; ++j) {
            float c = (float)(k0 + quad * 8 + j) * step;
            float dd = blv - c;
            a[j] = (short)f2bf(__expf(-gamma * dd * dd));
        }
        #pragma unroll
        for (int t = 0; t < 4; ++t) {
            s8v b = *(const s8v*)&Wedgt[(size_t)(t * 16 + col) * DMODEL + k0 + quad * 8];
            acc[t] = __builtin_amdgcn_mfma_f32_16x16x32_bf16(a, b, acc[t], 0, 0, 0);
        }
    }
    #pragma unroll
    for (int r = 0; r < 4; ++r) {
        int e = m0 + quad * 4 + r;
        if (e >= E) continue;
        int s = gs[e], d2 = gd[e];
        #pragma unroll
        for (int t = 0; t < 4; ++t) {
            int c = t * 16 + col;
            float v = acc[t][r] + xs[(size_t)s * DM + c] + xd[(size_t)d2 * DM + c] + be[c];
            xij[(size_t)e * DM + c] = f2bf(v);
        }
    }
}

// Fused logit+softmax+attend: 4 lanes per edge (degree-sorted via eperm),
// 16 channels per lane. Chebyshev T_k(d) for cos(k*theta); 2-shfl reduce.
__global__ __launch_bounds__(256) void k_edge_attn(
    const bf16_t* __restrict__ xij, const int2* __restrict__ packed,
    const int* __restrict__ rowp, const float* __restrict__ attn_l,
    const int* __restrict__ eperm, bf16_t* __restrict__ msg, int E) {
    int gtid = blockIdx.x * 256 + threadIdx.x;
    int ei = gtid >> 2;
    if (ei >= E) return;
    int q = gtid & 3;                  // channel block [16q, 16q+16)
    int e = eperm[ei];
    int beg = rowp[e], end = rowp[e + 1];

    float av[16];
    #pragma unroll
    for (int c = 0; c < 16; ++c) av[c] = attn_l[q * 16 + c];

    // my 16 channels of this edge's xij row (32B)
    uint4 xe0, xe1;
    {
        const uint4* xer = (const uint4*)&xij[(size_t)e * DM + q * 16];
        xe0 = xer[0]; xe1 = xer[1];
    }
    float acc[16];
    #pragma unroll
    for (int c = 0; c < 16; ++c) acc[c] = 0.f;
    float den = 0.f;

    if (beg < end) {
        // depth-1 pipeline priming
        int2 pk0 = packed[beg];
        int2 pk1 = (beg + 1 < end) ? packed[beg + 1] : pk0;
        const uint4* s0 = (const uint4*)&xij[(size_t)pk0.x * DM + q * 16];
        uint4 nsa = s0[0], nsb = s0[1];
        for (int p = beg; p < end; ++p) {
            float d = __int_as_float(pk0.y);
            uint4 xa = nsa, xb = nsb;
            if (p + 1 < end) {
                const uint4* sn = (const uint4*)&xij[(size_t)pk1.x * DM + q * 16];
                nsa = sn[0]; nsb = sn[1];
                pk0 = pk1;
                if (p + 2 < end) pk1 = packed[p + 2];
            }
            float d2 = d + d;
            // ladder: seeds T_{16q}, T_{16q+1} via 2TmTn = T_{m+n} + T_{|m-n|}
            float t2  = fmaf(d2, d, -1.f);
            float t3  = fmaf(d2, t2, -d);
            float t4  = fmaf(t2 + t2, t2, -1.f);
            float t7  = fmaf(t4 + t4, t3, -d);
            float t8  = fmaf(t4 + t4, t4, -1.f);
            float t15 = fmaf(t8 + t8, t7, -d);
            float t16 = fmaf(t8 + t8, t8, -1.f);
            float t17 = fmaf(t16 + t16, d, -t15);
            float t31 = fmaf(t16 + t16, t15, -d);
            float t32 = fmaf(t16 + t16, t16, -1.f);
            float t33 = fmaf(t32 + t32, d, -t31);
            float t48 = fmaf(t32 + t32, t16, -t16);
            float t49 = fmaf(t32 + t32, t17, -t15);
            float za, zb;                        // T_{16q}, T_{16q+1}
            if (q == 0)      { za = 1.f;  zb = d;   }
            else if (q == 1) { za = t16;  zb = t17; }
            else if (q == 2) { za = t32;  zb = t33; }
            else             { za = t48;  zb = t49; }
            float logit = 0.f;
            #define CH2(uw, ew, c)                                            \
            {                                                                 \
                float u0 = za + bf_lo(uw) + bf_lo(ew);                        \
                float zn = fmaf(d2, zb, -za); za = zb; zb = zn;               \
                float u1 = za + bf_hi(uw) + bf_hi(ew);                        \
                zn = fmaf(d2, zb, -za); za = zb; zb = zn;                     \
                logit = fmaf(silu_f(u0), av[c], logit);                       \
                logit = fmaf(silu_f(u1), av[c + 1], logit);                   \
            }
            CH2(xa.x, xe0.x, 0);
            CH2(xa.y, xe0.y, 2);
            CH2(xa.z, xe0.z, 4);
            CH2(xa.w, xe0.w, 6);
            CH2(xb.x, xe1.x, 8);
            CH2(xb.y, xe1.y, 10);
            CH2(xb.z, xe1.z, 12);
            CH2(xb.w, xe1.w, 14);
            #undef CH2
            // sum logit across the 4-lane group
            logit += __shfl_xor(logit, 1, 64);
            logit += __shfl_xor(logit, 2, 64);
            float wg = __expf(logit);
            den += wg;
            acc[0]  = fmaf(wg, bf_lo(xa.x), acc[0]);
            acc[1]  = fmaf(wg, bf_hi(xa.x), acc[1]);
            acc[2]  = fmaf(wg, bf_lo(xa.y), acc[2]);
            acc[3]  = fmaf(wg, bf_hi(xa.y), acc[3]);
            acc[4]  = fmaf(wg, bf_lo(xa.z), acc[4]);
            acc[5]  = fmaf(wg, bf_hi(xa.z), acc[5]);
            acc[6]  = fmaf(wg, bf_lo(xa.w), acc[6]);
            acc[7]  = fmaf(wg, bf_hi(xa.w), acc[7]);
            acc[8]  = fmaf(wg, bf_lo(xb.x), acc[8]);
            acc[9]  = fmaf(wg, bf_hi(xb.x), acc[9]);
            acc[10] = fmaf(wg, bf_lo(xb.y), acc[10]);
            acc[11] = fmaf(wg, bf_hi(xb.y), acc[11]);
            acc[12] = fmaf(wg, bf_lo(xb.z), acc[12]);
            acc[13] = fmaf(wg, bf_hi(xb.z), acc[13]);
            acc[14] = fmaf(wg, bf_lo(xb.w), acc[14]);
            acc[15] = fmaf(wg, bf_hi(xb.w), acc[15]);
        }
    }
    float inv = (den > 0.f) ? 1.f / den : 0.f;
    uint4 o0, o1;
    o0.x = (unsigned int)f2bf(acc[0] * inv)  | ((unsigned int)f2bf(acc[1] * inv) << 16);
    o0.y = (unsigned int)f2bf(acc[2] * inv)  | ((unsigned int)f2bf(acc[3] * inv) << 16);
    o0.z = (unsigned int)f2bf(acc[4] * inv)  | ((unsigned int)f2bf(acc[5] * inv) << 16);
    o0.w = (unsigned int)f2bf(acc[6] * inv)  | ((unsigned int)f2bf(acc[7] * inv) << 16);
    o1.x = (unsigned int)f2bf(acc[8] * inv)  | ((unsigned int)f2bf(acc[9] * inv) << 16);
    o1.y = (unsigned int)f2bf(acc[10] * inv) | ((unsigned int)f2bf(acc[11] * inv) << 16);
    o1.z = (unsigned int)f2bf(acc[12] * inv) | ((unsigned int)f2bf(acc[13] * inv) << 16);
    o1.w = (unsigned int)f2bf(acc[14] * inv) | ((unsigned int)f2bf(acc[15] * inv) << 16);
    uint4* op = (uint4*)&msg[(size_t)e * DM + q * 16];
    op[0] = o0;
    op[1] = o1;
}

// thread per (node, channel-quad): sum bf16 msg -> bf16 ft.
__global__ __launch_bounds__(256) void k_aggregate(
    const bf16_t* __restrict__ msg, const int* __restrict__ erowp,
    const int* __restrict__ eord, bf16_t* __restrict__ ft, int N) {
    int gtid = blockIdx.x * 256 + threadIdx.x;
    int n = gtid >> 4;
    if (n >= N) return;
    int quad = gtid & 15;
    int beg = erowp[n], end = erowp[n + 1];
    float a0 = 0.f, a1 = 0.f, a2 = 0.f, a3 = 0.f;
    for (int j = beg; j < end; ++j) {
        uint2 uv = *(const uint2*)&msg[(size_t)eord[j] * DM + quad * 4];
        a0 += bf_lo(uv.x); a1 += bf_hi(uv.x);
        a2 += bf_lo(uv.y); a3 += bf_hi(uv.y);
    }
    ushort4 o = {f2bf(a0), f2bf(a1), f2bf(a2), f2bf(a3)};
    *(ushort4*)&ft[(size_t)n * DM + quad * 4] = o;
}

// Fused FFN: x = silu(ft@W1 + b1) @ W2 + b2; h never leaves the CU.
// Grid (N/64, 4): blockIdx.y owns 64 output cols. Block = 64 rows, 4 waves.
// Weights stream through double-buffered LDS (pad-72 rows: b128 frag reads
// are 2-way bank-aliased = free). Per kc: issue next {W1,W2} 64x64 chunk
// global->reg, compute current chunk from LDS, barrier, ds_write staged
// regs, barrier. The compiler schedules ds_read->MFMA with fine lgkmcnt;
// the global->MFMA path it refused to pipeline (R21/R22) is gone.
__global__ __launch_bounds__(256) void k_ffn_fused(
    const bf16_t* __restrict__ ft, const bf16_t* __restrict__ W1t,
    const float* __restrict__ b1, const bf16_t* __restrict__ W2t,
    const float* __restrict__ b2, bf16_t* __restrict__ x, int N) {
    __shared__ bf16_t w1s[2][64 * 72];
    __shared__ bf16_t w2s[2][64 * 72];
    __shared__ bf16_t hld[4][16 * 72];
    __shared__ float b1s[HDIM];
    int tid = threadIdx.x;
    int w = tid >> 6, lane = tid & 63;
    int col = lane & 15, quad = lane >> 4;
    int m0 = blockIdx.x * 64 + w * 16;
    int c0 = blockIdx.y * 64;                 // this block's output columns
    bf16_t* myl = hld[w];

    // bias table -> LDS once
    #pragma unroll
    for (int j = 0; j < 4; ++j) b1s[tid + j * 256] = b1[tid + j * 256];

    // ft A-fragments for this wave's 16 rows (k = 0..63), held all kernel
    s8v fa0 = *(const s8v*)&ft[(size_t)(m0 + col) * DM + quad * 8];
    s8v fa1 = *(const s8v*)&ft[(size_t)(m0 + col) * DM + 32 + quad * 8];

    // staging geometry: piece idx = r*256+tid -> row = idx>>3, kblk = idx&7
    int srow0 = tid >> 3;            // r=0 rows 0..31
    int srow1 = 32 + srow0;          // r=1 rows 32..63
    int skb = tid & 7;

    f4 acc[4] = {{0.f,0.f,0.f,0.f},{0.f,0.f,0.f,0.f},
                 {0.f,0.f,0.f,0.f},{0.f,0.f,0.f,0.f}};

    // ---- prologue: stage chunk 0 into buffer 0 ----
    {
        uint4 a0 = *(const uint4*)&W1t[(size_t)srow0 * DM + skb * 8];
        uint4 a1 = *(const uint4*)&W1t[(size_t)srow1 * DM + skb * 8];
        uint4 c0v = *(const uint4*)&W2t[(size_t)(c0 + srow0) * HDIM + skb * 8];
        uint4 c1v = *(const uint4*)&W2t[(size_t)(c0 + srow1) * HDIM + skb * 8];
        *(uint4*)&w1s[0][srow0 * 72 + skb * 8] = a0;
        *(uint4*)&w1s[0][srow1 * 72 + skb * 8] = a1;
        *(uint4*)&w2s[0][srow0 * 72 + skb * 8] = c0v;
        *(uint4*)&w2s[0][srow1 * 72 + skb * 8] = c1v;
    }
    __syncthreads();

    #pragma unroll 1
    for (int kc = 0; kc < 16; ++kc) {         // h-col chunks of 64
        int cb = kc & 1, nb = cb ^ 1;
        int ch0 = kc * 64;
        int chn = (kc < 15) ? ch0 + 64 : ch0;  // clamped (load redundant on last)
        // issue next-chunk global loads into regs (no use until after barrier)
        uint4 na0 = *(const uint4*)&W1t[(size_t)(chn + srow0) * DM + skb * 8];
        uint4 na1 = *(const uint4*)&W1t[(size_t)(chn + srow1) * DM + skb * 8];
        uint4 nc0 = *(const uint4*)&W2t[(size_t)(c0 + srow0) * HDIM + chn + skb * 8];
        uint4 nc1 = *(const uint4*)&W2t[(size_t)(c0 + srow1) * HDIM + chn + skb * 8];
        // ---- compute current chunk entirely from LDS ----
        #pragma unroll
        for (int th = 0; th < 4; ++th) {
            s8v wb0 = *(const s8v*)&w1s[cb][(th * 16 + col) * 72 + quad * 8];
            s8v wb1 = *(const s8v*)&w1s[cb][(th * 16 + col) * 72 + 32 + quad * 8];
            f4 hv = {0.f, 0.f, 0.f, 0.f};
            hv = __builtin_amdgcn_mfma_f32_16x16x32_bf16(fa0, wb0, hv, 0, 0, 0);
            hv = __builtin_amdgcn_mfma_f32_16x16x32_bf16(fa1, wb1, hv, 0, 0, 0);
            float bb = b1s[ch0 + th * 16 + col];
            #pragma unroll
            for (int r = 0; r < 4; ++r)
                myl[(quad * 4 + r) * 72 + th * 16 + col] =
                    f2bf(silu_f(hv[r] + bb));
        }
        // A-fragments of h (wave-private tile; compiler emits lgkmcnt waits)
        s8v ha0 = *(const s8v*)&myl[col * 72 + quad * 8];
        s8v ha1 = *(const s8v*)&myl[col * 72 + 32 + quad * 8];
        #pragma unroll
        for (int t2 = 0; t2 < 4; ++t2) {
            s8v vb0 = *(const s8v*)&w2s[cb][(t2 * 16 + col) * 72 + quad * 8];
            s8v vb1 = *(const s8v*)&w2s[cb][(t2 * 16 + col) * 72 + 32 + quad * 8];
            acc[t2] = __builtin_amdgcn_mfma_f32_16x16x32_bf16(ha0, vb0, acc[t2], 0, 0, 0);
            acc[t2] = __builtin_amdgcn_mfma_f32_16x16x32_bf16(ha1, vb1, acc[t2], 0, 0, 0);
        }
        __syncthreads();                       // all waves done reading buf nb
        if (kc < 15) {
            *(uint4*)&w1s[nb][srow0 * 72 + skb * 8] = na0;
            *(uint4*)&w1s[nb][srow1 * 72 + skb * 8] = na1;
            *(uint4*)&w2s[nb][srow0 * 72 + skb * 8] = nc0;
            *(uint4*)&w2s[nb][srow1 * 72 + skb * 8] = nc1;
        }
        __syncthreads();                       // buf nb ready for next iter
    }
    #pragma unroll
    for (int t2 = 0; t2 < 4; ++t2) {
        int c = c0 + t2 * 16 + col;
        float bb = b2[c];
        #pragma unroll
        for (int r = 0; r < 4; ++r) {
            int m = m0 + quad * 4 + r;
            if (m < N) x[(size_t)m * DMODEL + c] = f2bf(acc[t2][r] + bb);
        }
    }
}

// grid-stride dot over bf16 x, one atomic per block.
__global__ __launch_bounds__(256) void k_out_reduce(
    const bf16_t* __restrict__ x, const float* __restrict__ Wfc,
    float* __restrict__ acc, int NT) {
    __shared__ float sm[4];
    int tid = threadIdx.x;
    float v = 0.f;
    int np = NT / 2;
    const unsigned int* xp = (const unsigned int*)x;
    for (int i = blockIdx.x * blockDim.x + tid; i < np; i += gridDim.x * blockDim.x) {
        unsigned int u = xp[i];
        int c = (2 * i) & (DMODEL - 1);
        v = fmaf(bf_lo(u), Wfc[c], v);
        v = fmaf(bf_hi(u), Wfc[c + 1], v);
    }
    for (int off = 32; off > 0; off >>= 1) v += __shfl_xor(v, off, 64);
    if ((tid & 63) == 0) sm[tid >> 6] = v;
    __syncthreads();
    if (tid == 0) {
        float s = sm[0] + sm[1] + sm[2] + sm[3];
        atomicAdd(acc, s);
    }
}

__global__ void k_out_final(const float* __restrict__ acc, const float* __restrict__ bfc,
                            float* __restrict__ out, float invN) {
    out[0] = acc[0] * invN + bfc[0];
}

extern "C" void kernel_launch(void* const* d_in, const int* in_sizes, int n_in,
                              void* d_out, int out_size, void* d_ws, size_t ws_size,
                              hipStream_t stream) {
    const int*   an    = (const int*)d_in[0];
    const int*   gs    = (const int*)d_in[1];
    const int*   gd    = (const int*)d_in[2];
    const int*   ts    = (const int*)d_in[3];
    const int*   td    = (const int*)d_in[4];
    const float* r     = (const float*)d_in[5];
    const float* emb   = (const float*)d_in[6];
    const float* Wsrc  = (const float*)d_in[7];
    const float* bsrc  = (const float*)d_in[8];
    const float* Wdst  = (const float*)d_in[9];
    const float* bdst  = (const float*)d_in[10];
    const float* Wedge = (const float*)d_in[11];
    const float* bedge = (const float*)d_in[12];
    const float* attn  = (const float*)d_in[13];
    const float* W1    = (const float*)d_in[14];
    const float* b1    = (const float*)d_in[15];
    const float* W2    = (const float*)d_in[16];
    const float* b2    = (const float*)d_in[17];
    const float* Wfc   = (const float*)d_in[18];
    const float* bfc   = (const float*)d_in[19];

    const int N = in_sizes[0];
    const int E = in_sizes[1];
    const int T = in_sizes[3];
    const int NB = (E + 511) >> BSH;          // triplet-sort buckets

    char* w = (char*)d_ws;
    size_t off = 0;
    auto alloc = [&](size_t bytes) {
        void* p = w + off;
        off += (bytes + 255) & ~(size_t)255;
        return p;
    };
    bf16_t* xb     = (bf16_t*)alloc((size_t)(N + 64) * DMODEL * 2);
    float*  rn     = (float*) alloc((size_t)E * 3 * 4);
    float*  bl     = (float*) alloc(((size_t)E + 64) * 4);
    int*    rowp   = (int*)   alloc(((size_t)E + 1) * 4);
    int*    bsum   = (int*)   alloc(4096);
    int2*   packed = (int2*)  alloc((size_t)T * 8);
    int2*   ipair  = (int2*)  alloc((size_t)T * 8);
    float*  idv    = (float*) alloc((size_t)T * 4);
    int*    gbcnt  = (int*)   alloc(NBMAX * 4);
    int*    bbase  = (int*)   alloc((NBMAX + 1) * 4);
    int*    bcur   = (int*)   alloc(NBMAX * 4);
    int*    ecnt   = (int*)   alloc((size_t)N * 4);
    int*    erowp  = (int*)   alloc(((size_t)N + 1) * 4);
    int*    eord   = (int*)   alloc((size_t)E * 4);
    int*    eperm  = (int*)   alloc((size_t)E * 4);
    int*    dcnt   = (int*)   alloc(1024);
    int*    dcur   = (int*)   alloc(1024);
    float*  xs     = (float*) alloc((size_t)N * DM * 4);
    float*  xd     = (float*) alloc((size_t)N * DM * 4);
    bf16_t* xij    = (bf16_t*)alloc((size_t)E * DM * 2);
    bf16_t* msg    = (bf16_t*)alloc((size_t)E * DM * 2);
    bf16_t* ft     = (bf16_t*)alloc((size_t)(N + 64) * DM * 2);
    bf16_t* W1t    = (bf16_t*)alloc((size_t)3 * HDIM * DM * 2);
    bf16_t* W2t    = (bf16_t*)alloc((size_t)3 * DMODEL * HDIM * 2);
    bf16_t* Wedgt  = (bf16_t*)alloc((size_t)3 * DM * DMODEL * 2);
    bf16_t* Wst    = (bf16_t*)alloc((size_t)3 * DM * DMODEL * 2);
    bf16_t* Wdt    = (bf16_t*)alloc((size_t)3 * DM * DMODEL * 2);
    float*  accs   = (float*) alloc(64);
    (void)ws_size; (void)n_in; (void)out_size;

    const int nbScanN = (N + 255) / 256;
    const int nbT = (T + 4095) / 4096;

    // ---- setup (layer-invariant) ----
    k_embed<<<N, 256, 0, stream>>>(an, emb, xb);
    k_edge_geom<<<(E + 255) / 256, 256, 0, stream>>>(r, bl, rn, E);
    for (int l = 0; l < 3; ++l) {
        k_castT<<<dim3(DM / 32, HDIM / 32), 256, 0, stream>>>(
            W1 + (size_t)l * DM * HDIM, W1t + (size_t)l * HDIM * DM, DM, HDIM);
        k_castT<<<dim3(HDIM / 32, DMODEL / 32), 256, 0, stream>>>(
            W2 + (size_t)l * HDIM * DMODEL, W2t + (size_t)l * DMODEL * HDIM,
            HDIM, DMODEL);
        k_castT<<<dim3(DMODEL / 32, DM / 32), 256, 0, stream>>>(
            Wedge + (size_t)l * DMODEL * DM, Wedgt + (size_t)l * DM * DMODEL,
            DMODEL, DM);
        k_castT<<<dim3(DMODEL / 32, DM / 32), 256, 0, stream>>>(
            Wsrc + (size_t)l * DMODEL * DM, Wst + (size_t)l * DM * DMODEL,
            DMODEL, DM);
        k_castT<<<dim3(DMODEL / 32, DM / 32), 256, 0, stream>>>(
            Wdst + (size_t)l * DMODEL * DM, Wdt + (size_t)l * DM * DMODEL,
            DMODEL, DM);
    }
    // triplet CSR by t_dst: two-level bucket sort, all writes coalesced
    hipMemsetAsync(gbcnt, 0, NBMAX * 4, stream);
    hipMemsetAsync(bcur, 0, NBMAX * 4, stream);
    k_bhist<<<nbT, 512, 0, stream>>>(td, gbcnt, T, NB);
    k_bscan<<<1, 512, 0, stream>>>(gbcnt, bbase, NB, T);
    k_passA<<<nbT, 512, 0, stream>>>(ts, td, rn, bbase, bcur, ipair, idv, T, NB);
    k_passB<<<NB, 512, 0, stream>>>(ipair, idv, bbase, packed, rowp, E, T);
    // degree-sorted edge permutation (for k_edge_attn load balance)
    hipMemsetAsync(dcnt, 0, 1024, stream);
    hipMemsetAsync(dcur, 0, 1024, stream);
    k_deghist<<<(E + 255) / 256, 256, 0, stream>>>(rowp, dcnt, E);
    k_scan_mid<<<1, 1024, 0, stream>>>(dcnt, 256);
    k_degscatter<<<(E + 255) / 256, 256, 0, stream>>>(rowp, dcnt, dcur, eperm, E);
    // edge CSR by gd
    hipMemsetAsync(ecnt, 0, (size_t)N * 4, stream);
    k_hist<<<(E + 255) / 256, 256, 0, stream>>>(gd, ecnt, E);
    k_scan_part<<<nbScanN, 256, 0, stream>>>(ecnt, bsum, N);
    k_scan_mid<<<1, 1024, 0, stream>>>(bsum, nbScanN);
    k_scan_final<<<nbScanN, 256, 0, stream>>>(ecnt, bsum, erowp, N, E);
    hipMemsetAsync(ecnt, 0, (size_t)N * 4, stream);
    k_escatter<<<(E + 255) / 256, 256, 0, stream>>>(gd, erowp, ecnt, eord, E);

    // ---- layers ----
    for (int l = 0; l < 3; ++l) {
        k_node_proj<<<(N + 63) / 64, 256, 0, stream>>>(
            xb, Wst + (size_t)l * DM * DMODEL, bsrc + l * DM,
            Wdt + (size_t)l * DM * DMODEL, bdst + l * DM, xs, xd, N);
        k_xij<<<(E + 63) / 64, 256, 0, stream>>>(
            bl, Wedgt + (size_t)l * DM * DMODEL, bedge + l * DM,
            xs, xd, gs, gd, xij, E);
        k_edge_attn<<<(E * 4 + 255) / 256, 256, 0, stream>>>(
            xij, packed, rowp, attn + l * DM, eperm, msg, E);
        k_aggregate<<<(N * 16 + 255) / 256, 256, 0, stream>>>(
            msg, erowp, eord, ft, N);
        k_ffn_fused<<<dim3((N + 63) / 64, 4), 256, 0, stream>>>(
            ft, W1t + (size_t)l * HDIM * DM, b1 + l * HDIM,
            W2t + (size_t)l * DMODEL * HDIM, b2 + l * DMODEL, xb, N);
    }

    // ---- output head ----
    hipMemsetAsync(accs, 0, 4, stream);
    k_out_reduce<<<120, 256, 0, stream>>>(xb, Wfc, accs, N * DMODEL);
    k_out_final<<<1, 1, 0, stream>>>(accs, bfc, (float*)d_out, 1.0f / (float)N);
}

// Round 9
// 719.843 us; speedup vs baseline: 1.3024x; 1.0498x over previous
//
#include <hip/hip_runtime.h>
#include <math.h>

// M3GNet-like GNN forward. N=10000 nodes, E=160000 edges, T=1200000 triplets,
// D=256, DM=64, H=1024, L=3, output = scalar mean energy (fp32).
//
// R24 (resubmit; previous round was an infra failure "container failed
// twice", not a kernel result): LPT-order k_edge_attn. R23's profile:
// VALUBusy 56%, Occupancy 25%, no pipe saturated at 57us vs ~21-30us issue
// floor. Cause: ASCENDING degree sort put the deg~30 edges in the last-
// dispatched blocks -> the machine drains to a few long waves (time-
// averaged occupancy 25% = the tail). Fix: write the degree-sorted
// permutation in DESCENDING order (one line in k_degscatter) -> longest
// waves start first, short waves backfill (classic LPT). Wave-internal
// degree uniformity preserved; output bit-identical.

#define DM 64
#define DMODEL 256
#define HDIM 1024

#define BSH 9            // log2(edges per bucket)
#define NBMAX 320        // max buckets (E <= 163840)
#define CAPB 4608        // passB LDS staging capacity (bucket ~3840+-62)

typedef unsigned short bf16_t;
typedef __attribute__((ext_vector_type(8))) short s8v;    // 8 bf16 (4 VGPRs)
typedef __attribute__((ext_vector_type(4))) float f4;     // MFMA acc

__device__ __forceinline__ bf16_t f2bf(float f) {
    unsigned int u = __float_as_uint(f);
    return (bf16_t)((u + 0x7FFFu + ((u >> 16) & 1u)) >> 16);   // RNE
}
__device__ __forceinline__ float bf_lo(unsigned int u) {
    return __uint_as_float(u << 16);
}
__device__ __forceinline__ float bf_hi(unsigned int u) {
    return __uint_as_float(u & 0xFFFF0000u);
}
__device__ __forceinline__ float silu_f(float u) {
    return u * __builtin_amdgcn_rcpf(1.f + __expf(-u));
}

__global__ void k_embed(const int* __restrict__ an, const float* __restrict__ emb,
                        bf16_t* __restrict__ x) {
    int n = blockIdx.x;
    int d = threadIdx.x;
    x[n * DMODEL + d] = f2bf(emb[an[n] * DMODEL + d]);
}

__global__ void k_edge_geom(const float* __restrict__ r, float* __restrict__ bl,
                            float* __restrict__ rn, int E) {
    int e = blockIdx.x * blockDim.x + threadIdx.x;
    if (e >= E) return;
    float a = r[e * 3 + 0], b = r[e * 3 + 1], c = r[e * 3 + 2];
    float l = sqrtf(a * a + b * b + c * c);
    bl[e] = l;
    float inv = 1.0f / l;
    rn[e * 3 + 0] = a * inv;
    rn[e * 3 + 1] = b * inv;
    rn[e * 3 + 2] = c * inv;
}

__global__ void k_hist(const int* __restrict__ idx, int* __restrict__ cnt, int M) {
    int t = blockIdx.x * blockDim.x + threadIdx.x;
    if (t < M) atomicAdd(&cnt[idx[t]], 1);
}

// ---- 3-phase exclusive scan (used for edge-CSR over N) ----
__global__ __launch_bounds__(256) void k_scan_part(
    const int* __restrict__ cnt, int* __restrict__ bsum, int M) {
    __shared__ int sm[4];
    int tid = threadIdx.x;
    int i = blockIdx.x * 256 + tid;
    int v = (i < M) ? cnt[i] : 0;
    for (int off = 32; off > 0; off >>= 1) v += __shfl_xor(v, off, 64);
    if ((tid & 63) == 0) sm[tid >> 6] = v;
    __syncthreads();
    if (tid == 0) bsum[blockIdx.x] = sm[0] + sm[1] + sm[2] + sm[3];
}

__global__ __launch_bounds__(1024) void k_scan_mid(int* __restrict__ bsum, int nb) {
    __shared__ int sm[1024];
    int tid = threadIdx.x;
    int v = (tid < nb) ? bsum[tid] : 0;
    sm[tid] = v;
    __syncthreads();
    for (int off = 1; off < 1024; off <<= 1) {
        int u = (tid >= off) ? sm[tid - off] : 0;
        __syncthreads();
        sm[tid] += u;
        __syncthreads();
    }
    if (tid < nb) bsum[tid] = sm[tid] - v;
}

__global__ __launch_bounds__(256) void k_scan_final(
    const int* __restrict__ cnt, const int* __restrict__ bsum,
    int* __restrict__ rowp, int M, int total) {
    __shared__ int sm[256];
    int tid = threadIdx.x;
    int i = blockIdx.x * 256 + tid;
    int v = (i < M) ? cnt[i] : 0;
    sm[tid] = v;
    __syncthreads();
    for (int off = 1; off < 256; off <<= 1) {
        int u = (tid >= off) ? sm[tid - off] : 0;
        __syncthreads();
        sm[tid] += u;
        __syncthreads();
    }
    if (i < M) rowp[i] = bsum[blockIdx.x] + sm[tid] - v;
    if (i == 0) rowp[M] = total;
}

// ---- two-level bucket sort of triplets by t_dst ----
// bucket b holds edges [b*512, b*512+512)

__global__ __launch_bounds__(512) void k_bhist(
    const int* __restrict__ td, int* __restrict__ gbcnt, int T, int NB) {
    __shared__ int h[NBMAX];
    int tid = threadIdx.x;
    for (int i = tid; i < NBMAX; i += 512) h[i] = 0;
    __syncthreads();
    int t0 = blockIdx.x * 4096;
    #pragma unroll
    for (int i = 0; i < 8; ++i) {
        int t = t0 + tid + i * 512;
        if (t < T) atomicAdd(&h[td[t] >> BSH], 1);
    }
    __syncthreads();
    for (int b = tid; b < NB; b += 512)
        if (h[b]) atomicAdd(&gbcnt[b], h[b]);
}

__global__ __launch_bounds__(512) void k_bscan(
    const int* __restrict__ gbcnt, int* __restrict__ bbase, int NB, int total) {
    __shared__ int sm[512];
    int tid = threadIdx.x;
    int v = (tid < NB) ? gbcnt[tid] : 0;
    sm[tid] = v;
    __syncthreads();
    for (int off = 1; off < 512; off <<= 1) {
        int u = (tid >= off) ? sm[tid - off] : 0;
        __syncthreads();
        sm[tid] += u;
        __syncthreads();
    }
    if (tid < NB) bbase[tid] = sm[tid] - v;
    if (tid == 0) bbase[NB] = total;
}

// passA: bin 4096 triplets into LDS by bucket, flush runs coalesced.
__global__ __launch_bounds__(512) void k_passA(
    const int* __restrict__ ts, const int* __restrict__ td,
    const float* __restrict__ rn, const int* __restrict__ bbase,
    int* __restrict__ bcur, int2* __restrict__ ipair, float* __restrict__ idv,
    int T, int NB) {
    __shared__ int   std_[4096];
    __shared__ int   ssrc[4096];
    __shared__ float sdv[4096];
    __shared__ int lbcnt[NBMAX], lbase[NBMAX], lpos[NBMAX], lgst[NBMAX],
                   lbb[NBMAX];
    __shared__ int ssc[512];
    int tid = threadIdx.x;
    int t0 = blockIdx.x * 4096;
    int total = min(4096, T - t0);
    for (int i = tid; i < NBMAX; i += 512) lbcnt[i] = 0;
    for (int i = tid; i < NB; i += 512) lbb[i] = bbase[i];
    __syncthreads();
    int   mtd[8], msrc[8];
    float md[8];
    #pragma unroll
    for (int i = 0; i < 8; ++i) {
        int idx = tid + i * 512;
        mtd[i] = -1;
        if (idx < total) {
            int t = t0 + idx;
            int a = ts[t], b = td[t];
            float d = rn[a * 3 + 0] * rn[b * 3 + 0]
                    + rn[a * 3 + 1] * rn[b * 3 + 1]
                    + rn[a * 3 + 2] * rn[b * 3 + 2];
            d = fminf(1.0f, fmaxf(-1.0f, d));
            mtd[i] = b; msrc[i] = a; md[i] = d;
            atomicAdd(&lbcnt[b >> BSH], 1);
        }
    }
    __syncthreads();
    // scan block-local bucket counts (NB <= 320 <= 512)
    int v = (tid < NB) ? lbcnt[tid] : 0;
    ssc[tid] = v;
    __syncthreads();
    for (int off = 1; off < 512; off <<= 1) {
        int u = (tid >= off) ? ssc[tid - off] : 0;
        __syncthreads();
        ssc[tid] += u;
        __syncthreads();
    }
    if (tid < NB) {
        int ex = ssc[tid] - v;
        lbase[tid] = ex;
        lpos[tid] = ex;
    }
    __syncthreads();
    // place into LDS staging grouped by bucket
    #pragma unroll
    for (int i = 0; i < 8; ++i) {
        if (mtd[i] >= 0) {
            int bin = mtd[i] >> BSH;
            int p = atomicAdd(&lpos[bin], 1);
            std_[p] = mtd[i]; ssrc[p] = msrc[i]; sdv[p] = md[i];
        }
    }
    __syncthreads();
    // reserve global runs: one atomic per (block, bucket)
    for (int b = tid; b < NB; b += 512)
        if (lbcnt[b]) lgst[b] = atomicAdd(&bcur[b], lbcnt[b]);
    __syncthreads();
    // coalesced flush of runs
    for (int j = tid; j < total; j += 512) {
        int bin = std_[j] >> BSH;
        int dest = lbb[bin] + lgst[bin] + (j - lbase[bin]);
        ipair[dest] = make_int2(std_[j], ssrc[j]);
        idv[dest] = sdv[j];
    }
}

// passB: one block per bucket; in-LDS edge hist + scan -> rowp (coalesced)
// and final packed placement flushed coalesced.
__global__ __launch_bounds__(512) void k_passB(
    const int2* __restrict__ ipair, const float* __restrict__ idv,
    const int* __restrict__ bbase, int2* __restrict__ packed,
    int* __restrict__ rowp, int E, int T) {
    __shared__ int2 spk[CAPB];
    __shared__ int hcnt[512], lcur[512], ssc[512];
    int tid = threadIdx.x;
    int b = blockIdx.x;
    int ibeg = bbase[b], iend = bbase[b + 1];
    int nb = iend - ibeg;
    int e0 = b << BSH;
    hcnt[tid] = 0;
    __syncthreads();
    for (int j = ibeg + tid; j < iend; j += 512)
        atomicAdd(&hcnt[ipair[j].x - e0], 1);
    __syncthreads();
    int v = hcnt[tid];
    ssc[tid] = v;
    __syncthreads();
    for (int off = 1; off < 512; off <<= 1) {
        int u = (tid >= off) ? ssc[tid - off] : 0;
        __syncthreads();
        ssc[tid] += u;
        __syncthreads();
    }
    int excl = ssc[tid] - v;
    lcur[tid] = excl;
    int e = e0 + tid;
    if (e < E) rowp[e] = ibeg + excl;
    if (b == 0 && tid == 0) rowp[E] = T;
    __syncthreads();
    bool staged = (nb <= CAPB);
    for (int j = ibeg + tid; j < iend; j += 512) {
        int2 pr = ipair[j];
        int pos = atomicAdd(&lcur[pr.x - e0], 1);
        int2 out = make_int2(pr.y, __float_as_int(idv[j]));
        if (staged) spk[pos] = out;
        else packed[ibeg + pos] = out;
    }
    __syncthreads();
    if (staged)
        for (int j = tid; j < nb; j += 512) packed[ibeg + j] = spk[j];
}

__global__ void k_escatter(const int* __restrict__ gd, const int* __restrict__ erowp,
                           int* __restrict__ cursor, int* __restrict__ eord, int E) {
    int e = blockIdx.x * blockDim.x + threadIdx.x;
    if (e >= E) return;
    int n = gd[e];
    int pos = erowp[n] + atomicAdd(&cursor[n], 1);
    eord[pos] = e;
}

// ---- degree bucket sort of edges (by triplet-segment length) ----
__global__ __launch_bounds__(256) void k_deghist(
    const int* __restrict__ rowp, int* __restrict__ dcnt, int E) {
    __shared__ int h[256];
    int tid = threadIdx.x;
    h[tid] = 0;
    __syncthreads();
    int e = blockIdx.x * 256 + tid;
    if (e < E) {
        int d = rowp[e + 1] - rowp[e];
        if (d > 255) d = 255;
        atomicAdd(&h[d], 1);
    }
    __syncthreads();
    if (h[tid]) atomicAdd(&dcnt[tid], h[tid]);
}

__global__ __launch_bounds__(256) void k_degscatter(
    const int* __restrict__ rowp, const int* __restrict__ doff,
    int* __restrict__ dcur, int* __restrict__ eperm, int E) {
    __shared__ int lcnt[256];
    __shared__ int base[256];
    int tid = threadIdx.x;
    lcnt[tid] = 0;
    __syncthreads();
    int e = blockIdx.x * 256 + tid;
    int d = 0, rk = 0;
    if (e < E) {
        d = rowp[e + 1] - rowp[e];
        if (d > 255) d = 255;
        rk = atomicAdd(&lcnt[d], 1);
    }
    __syncthreads();
    if (lcnt[tid]) base[tid] = atomicAdd(&dcur[tid], lcnt[tid]);
    __syncthreads();
    // DESCENDING degree order (LPT): longest-running waves dispatch first,
    // short waves backfill the tail. R23 profile showed the ascending
    // order's tail cost ~2x (occupancy 25%).
    if (e < E) eperm[E - 1 - (doff[d] + base[d] + rk)] = e;
}

// 32x32 tiled transpose + cast: src fp32 [K][Nn] -> dst bf16 [Nn][K].
__global__ __launch_bounds__(256) void k_castT(
    const float* __restrict__ src, bf16_t* __restrict__ dst, int K, int Nn) {
    __shared__ float tile[32][33];
    int k0 = blockIdx.x * 32, n0 = blockIdx.y * 32;
    int tx = threadIdx.x & 31, ty = threadIdx.x >> 5;
    #pragma unroll
    for (int i = 0; i < 4; ++i) {
        int row = ty + i * 8;
        tile[row][tx] = src[(size_t)(k0 + row) * Nn + n0 + tx];
    }
    __syncthreads();
    #pragma unroll
    for (int i = 0; i < 4; ++i) {
        int row = ty + i * 8;
        dst[(size_t)(n0 + row) * K + k0 + tx] = f2bf(tile[tx][row]);
    }
}

// MFMA node_proj: xs = x@Wsrc + bs, xd = x@Wdst + bd (fp32 out).
__global__ __launch_bounds__(256) void k_node_proj(
    const bf16_t* __restrict__ xb,
    const bf16_t* __restrict__ Wst, const float* __restrict__ bs,
    const bf16_t* __restrict__ Wdt, const float* __restrict__ bd,
    float* __restrict__ xs, float* __restrict__ xd, int N) {
    int tid = threadIdx.x;
    int w = tid >> 6, lane = tid & 63;
    int col = lane & 15, quad = lane >> 4;
    int m0 = blockIdx.x * 64 + w * 16;
    f4 as[4] = {{0.f,0.f,0.f,0.f},{0.f,0.f,0.f,0.f},
                {0.f,0.f,0.f,0.f},{0.f,0.f,0.f,0.f}};
    f4 ad[4] = {{0.f,0.f,0.f,0.f},{0.f,0.f,0.f,0.f},
                {0.f,0.f,0.f,0.f},{0.f,0.f,0.f,0.f}};
    #pragma unroll
    for (int k0 = 0; k0 < DMODEL; k0 += 32) {
        s8v a = *(const s8v*)&xb[(size_t)(m0 + col) * DMODEL + k0 + quad * 8];
        #pragma unroll
        for (int t = 0; t < 4; ++t) {
            s8v b1v = *(const s8v*)&Wst[(size_t)(t * 16 + col) * DMODEL + k0 + quad * 8];
            as[t] = __builtin_amdgcn_mfma_f32_16x16x32_bf16(a, b1v, as[t], 0, 0, 0);
            s8v b2v = *(const s8v*)&Wdt[(size_t)(t * 16 + col) * DMODEL + k0 + quad * 8];
            ad[t] = __builtin_amdgcn_mfma_f32_16x16x32_bf16(a, b2v, ad[t], 0, 0, 0);
        }
    }
    #pragma unroll
    for (int t = 0; t < 4; ++t) {
        int c = t * 16 + col;
        float bsv = bs[c], bdv = bd[c];
        #pragma unroll
        for (int r = 0; r < 4; ++r) {
            int m = m0 + quad * 4 + r;
            if (m < N) {
                xs[(size_t)m * DM + c] = as[t][r] + bsv;
                xd[(size_t)m * DM + c] = ad[t][r] + bdv;
            }
        }
    }
}

// MFMA k_xij: xij[e][c] = (RBF(bl[e]) @ Wedge)[c] + xs[gs[e]][c] + xd[gd[e]][c] + be[c]
__global__ __launch_bounds__(256) void k_xij(
    const float* __restrict__ bl, const bf16_t* __restrict__ Wedgt,
    const float* __restrict__ be,
    const float* __restrict__ xs, const float* __restrict__ xd,
    const int* __restrict__ gs, const int* __restrict__ gd,
    bf16_t* __restrict__ xij, int E) {
    int tid = threadIdx.x;
    int w = tid >> 6, lane = tid & 63;
    int col = lane & 15, quad = lane >> 4;
    int m0 = blockIdx.x * 64 + w * 16;
    const float step = 8.0f / 255.0f;
    const float gamma = (255.0f / 8.0f) * (255.0f / 8.0f);
    int me = m0 + col;
    float blv = (me < E) ? bl[me] : 0.f;
    f4 acc[4] = {{0.f,0.f,0.f,0.f},{0.f,0.f,0.f,0.f},
                 {0.f,0.f,0.f,0.f},{0.f,0.f,0.f,0.f}};
    #pragma unroll
    for (int k0 = 0; k0 < DMODEL; k0 += 32) {
        s8v a;
        #pragma unroll
        for (int j = 0; j < 8; ++j) {
            float c = (float)(k0 + quad * 8 + j) * step;
            float dd = blv - c;
            a[j] = (short)f2bf(__expf(-gamma * dd * dd));
        }
        #pragma unroll
        for (int t = 0; t < 4; ++t) {
            s8v b = *(const s8v*)&Wedgt[(size_t)(t * 16 + col) * DMODEL + k0 + quad * 8];
            acc[t] = __builtin_amdgcn_mfma_f32_16x16x32_bf16(a, b, acc[t], 0, 0, 0);
        }
    }
    #pragma unroll
    for (int r = 0; r < 4; ++r) {
        int e = m0 + quad * 4 + r;
        if (e >= E) continue;
        int s = gs[e], d2 = gd[e];
        #pragma unroll
        for (int t = 0; t < 4; ++t) {
            int c = t * 16 + col;
            float v = acc[t][r] + xs[(size_t)s * DM + c] + xd[(size_t)d2 * DM + c] + be[c];
            xij[(size_t)e * DM + c] = f2bf(v);
        }
    }
}

// Fused logit+softmax+attend: 4 lanes per edge (degree-sorted via eperm),
// 16 channels per lane. Chebyshev T_k(d) for cos(k*theta); 2-shfl reduce.
__global__ __launch_bounds__(256) void k_edge_attn(
    const bf16_t* __restrict__ xij, const int2* __restrict__ packed,
    const int* __restrict__ rowp, const float* __restrict__ attn_l,
    const int* __restrict__ eperm, bf16_t* __restrict__ msg, int E) {
    int gtid = blockIdx.x * 256 + threadIdx.x;
    int ei = gtid >> 2;
    if (ei >= E) return;
    int q = gtid & 3;                  // channel block [16q, 16q+16)
    int e = eperm[ei];
    int beg = rowp[e], end = rowp[e + 1];

    float av[16];
    #pragma unroll
    for (int c = 0; c < 16; ++c) av[c] = attn_l[q * 16 + c];

    // my 16 channels of this edge's xij row (32B)
    uint4 xe0, xe1;
    {
        const uint4* xer = (const uint4*)&xij[(size_t)e * DM + q * 16];
        xe0 = xer[0]; xe1 = xer[1];
    }
    float acc[16];
    #pragma unroll
    for (int c = 0; c < 16; ++c) acc[c] = 0.f;
    float den = 0.f;

    if (beg < end) {
        // depth-1 pipeline priming
        int2 pk0 = packed[beg];
        int2 pk1 = (beg + 1 < end) ? packed[beg + 1] : pk0;
        const uint4* s0 = (const uint4*)&xij[(size_t)pk0.x * DM + q * 16];
        uint4 nsa = s0[0], nsb = s0[1];
        for (int p = beg; p < end; ++p) {
            float d = __int_as_float(pk0.y);
            uint4 xa = nsa, xb = nsb;
            if (p + 1 < end) {
                const uint4* sn = (const uint4*)&xij[(size_t)pk1.x * DM + q * 16];
                nsa = sn[0]; nsb = sn[1];
                pk0 = pk1;
                if (p + 2 < end) pk1 = packed[p + 2];
            }
            float d2 = d + d;
            // ladder: seeds T_{16q}, T_{16q+1} via 2TmTn = T_{m+n} + T_{|m-n|}
            float t2  = fmaf(d2, d, -1.f);
            float t3  = fmaf(d2, t2, -d);
            float t4  = fmaf(t2 + t2, t2, -1.f);
            float t7  = fmaf(t4 + t4, t3, -d);
            float t8  = fmaf(t4 + t4, t4, -1.f);
            float t15 = fmaf(t8 + t8, t7, -d);
            float t16 = fmaf(t8 + t8, t8, -1.f);
            float t17 = fmaf(t16 + t16, d, -t15);
            float t31 = fmaf(t16 + t16, t15, -d);
            float t32 = fmaf(t16 + t16, t16, -1.f);
            float t33 = fmaf(t32 + t32, d, -t31);
            float t48 = fmaf(t32 + t32, t16, -t16);
            float t49 = fmaf(t32 + t32, t17, -t15);
            float za, zb;                        // T_{16q}, T_{16q+1}
            if (q == 0)      { za = 1.f;  zb = d;   }
            else if (q == 1) { za = t16;  zb = t17; }
            else if (q == 2) { za = t32;  zb = t33; }
            else             { za = t48;  zb = t49; }
            float logit = 0.f;
            #define CH2(uw, ew, c)                                            \
            {                                                                 \
                float u0 = za + bf_lo(uw) + bf_lo(ew);                        \
                float zn = fmaf(d2, zb, -za); za = zb; zb = zn;               \
                float u1 = za + bf_hi(uw) + bf_hi(ew);                        \
                zn = fmaf(d2, zb, -za); za = zb; zb = zn;                     \
                logit = fmaf(silu_f(u0), av[c], logit);                       \
                logit = fmaf(silu_f(u1), av[c + 1], logit);                   \
            }
            CH2(xa.x, xe0.x, 0);
            CH2(xa.y, xe0.y, 2);
            CH2(xa.z, xe0.z, 4);
            CH2(xa.w, xe0.w, 6);
            CH2(xb.x, xe1.x, 8);
            CH2(xb.y, xe1.y, 10);
            CH2(xb.z, xe1.z, 12);
            CH2(xb.w, xe1.w, 14);
            #undef CH2
            // sum logit across the 4-lane group
            logit += __shfl_xor(logit, 1, 64);
            logit += __shfl_xor(logit, 2, 64);
            float wg = __expf(logit);
            den += wg;
            acc[0]  = fmaf(wg, bf_lo(xa.x), acc[0]);
            acc[1]  = fmaf(wg, bf_hi(xa.x), acc[1]);
            acc[2]  = fmaf(wg, bf_lo(xa.y), acc[2]);
            acc[3]  = fmaf(wg, bf_hi(xa.y), acc[3]);
            acc[4]  = fmaf(wg, bf_lo(xa.z), acc[4]);
            acc[5]  = fmaf(wg, bf_hi(xa.z), acc[5]);
            acc[6]  = fmaf(wg, bf_lo(xa.w), acc[6]);
            acc[7]  = fmaf(wg, bf_hi(xa.w), acc[7]);
            acc[8]  = fmaf(wg, bf_lo(xb.x), acc[8]);
            acc[9]  = fmaf(wg, bf_hi(xb.x), acc[9]);
            acc[10] = fmaf(wg, bf_lo(xb.y), acc[10]);
            acc[11] = fmaf(wg, bf_hi(xb.y), acc[11]);
            acc[12] = fmaf(wg, bf_lo(xb.z), acc[12]);
            acc[13] = fmaf(wg, bf_hi(xb.z), acc[13]);
            acc[14] = fmaf(wg, bf_lo(xb.w), acc[14]);
            acc[15] = fmaf(wg, bf_hi(xb.w), acc[15]);
        }
    }
    float inv = (den > 0.f) ? 1.f / den : 0.f;
    uint4 o0, o1;
    o0.x = (unsigned int)f2bf(acc[0] * inv)  | ((unsigned int)f2bf(acc[1] * inv) << 16);
    o0.y = (unsigned int)f2bf(acc[2] * inv)  | ((unsigned int)f2bf(acc[3] * inv) << 16);
    o0.z = (unsigned int)f2bf(acc[4] * inv)  | ((unsigned int)f2bf(acc[5] * inv) << 16);
    o0.w = (unsigned int)f2bf(acc[6] * inv)  | ((unsigned int)f2bf(acc[7] * inv) << 16);
    o1.x = (unsigned int)f2bf(acc[8] * inv)  | ((unsigned int)f2bf(acc[9] * inv) << 16);
    o1.y = (unsigned int)f2bf(acc[10] * inv) | ((unsigned int)f2bf(acc[11] * inv) << 16);
    o1.z = (unsigned int)f2bf(acc[12] * inv) | ((unsigned int)f2bf(acc[13] * inv) << 16);
    o1.w = (unsigned int)f2bf(acc[14] * inv) | ((unsigned int)f2bf(acc[15] * inv) << 16);
    uint4* op = (uint4*)&msg[(size_t)e * DM + q * 16];
    op[0] = o0;
    op[1] = o1;
}

// thread per (node, channel-quad): sum bf16 msg -> bf16 ft.
__global__ __launch_bounds__(256) void k_aggregate(
    const bf16_t* __restrict__ msg, const int* __restrict__ erowp,
    const int* __restrict__ eord, bf16_t* __restrict__ ft, int N) {
    int gtid = blockIdx.x * 256 + threadIdx.x;
    int n = gtid >> 4;
    if (n >= N) return;
    int quad = gtid & 15;
    int beg = erowp[n], end = erowp[n + 1];
    float a0 = 0.f, a1 = 0.f, a2 = 0.f, a3 = 0.f;
    for (int j = beg; j < end; ++j) {
        uint2 uv = *(const uint2*)&msg[(size_t)eord[j] * DM + quad * 4];
        a0 += bf_lo(uv.x); a1 += bf_hi(uv.x);
        a2 += bf_lo(uv.y); a3 += bf_hi(uv.y);
    }
    ushort4 o = {f2bf(a0), f2bf(a1), f2bf(a2), f2bf(a3)};
    *(ushort4*)&ft[(size_t)n * DM + quad * 4] = o;
}

// Fused FFN: x = silu(ft@W1 + b1) @ W2 + b2; h never leaves the CU.
// Grid (N/64, 4): blockIdx.y owns 64 output cols. Block = 64 rows, 4 waves.
// Weights stream through double-buffered LDS (pad-72 rows: b128 frag reads
// are 2-way bank-aliased = free). Per kc: issue next {W1,W2} 64x64 chunk
// global->reg, compute current chunk from LDS, barrier, ds_write staged
// regs, barrier. The compiler schedules ds_read->MFMA with fine lgkmcnt;
// the global->MFMA path it refused to pipeline (R21/R22) is gone.
__global__ __launch_bounds__(256) void k_ffn_fused(
    const bf16_t* __restrict__ ft, const bf16_t* __restrict__ W1t,
    const float* __restrict__ b1, const bf16_t* __restrict__ W2t,
    const float* __restrict__ b2, bf16_t* __restrict__ x, int N) {
    __shared__ bf16_t w1s[2][64 * 72];
    __shared__ bf16_t w2s[2][64 * 72];
    __shared__ bf16_t hld[4][16 * 72];
    __shared__ float b1s[HDIM];
    int tid = threadIdx.x;
    int w = tid >> 6, lane = tid & 63;
    int col = lane & 15, quad = lane >> 4;
    int m0 = blockIdx.x * 64 + w * 16;
    int c0 = blockIdx.y * 64;                 // this block's output columns
    bf16_t* myl = hld[w];

    // bias table -> LDS once
    #pragma unroll
    for (int j = 0; j < 4; ++j) b1s[tid + j * 256] = b1[tid + j * 256];

    // ft A-fragments for this wave's 16 rows (k = 0..63), held all kernel
    s8v fa0 = *(const s8v*)&ft[(size_t)(m0 + col) * DM + quad * 8];
    s8v fa1 = *(const s8v*)&ft[(size_t)(m0 + col) * DM + 32 + quad * 8];

    // staging geometry: piece idx = r*256+tid -> row = idx>>3, kblk = idx&7
    int srow0 = tid >> 3;            // r=0 rows 0..31
    int srow1 = 32 + srow0;          // r=1 rows 32..63
    int skb = tid & 7;

    f4 acc[4] = {{0.f,0.f,0.f,0.f},{0.f,0.f,0.f,0.f},
                 {0.f,0.f,0.f,0.f},{0.f,0.f,0.f,0.f}};

    // ---- prologue: stage chunk 0 into buffer 0 ----
    {
        uint4 a0 = *(const uint4*)&W1t[(size_t)srow0 * DM + skb * 8];
        uint4 a1 = *(const uint4*)&W1t[(size_t)srow1 * DM + skb * 8];
        uint4 c0v = *(const uint4*)&W2t[(size_t)(c0 + srow0) * HDIM + skb * 8];
        uint4 c1v = *(const uint4*)&W2t[(size_t)(c0 + srow1) * HDIM + skb * 8];
        *(uint4*)&w1s[0][srow0 * 72 + skb * 8] = a0;
        *(uint4*)&w1s[0][srow1 * 72 + skb * 8] = a1;
        *(uint4*)&w2s[0][srow0 * 72 + skb * 8] = c0v;
        *(uint4*)&w2s[0][srow1 * 72 + skb * 8] = c1v;
    }
    __syncthreads();

    #pragma unroll 1
    for (int kc = 0; kc < 16; ++kc) {         // h-col chunks of 64
        int cb = kc & 1, nb = cb ^ 1;
        int ch0 = kc * 64;
        int chn = (kc < 15) ? ch0 + 64 : ch0;  // clamped (load redundant on last)
        // issue next-chunk global loads into regs (no use until after barrier)
        uint4 na0 = *(const uint4*)&W1t[(size_t)(chn + srow0) * DM + skb * 8];
        uint4 na1 = *(const uint4*)&W1t[(size_t)(chn + srow1) * DM + skb * 8];
        uint4 nc0 = *(const uint4*)&W2t[(size_t)(c0 + srow0) * HDIM + chn + skb * 8];
        uint4 nc1 = *(const uint4*)&W2t[(size_t)(c0 + srow1) * HDIM + chn + skb * 8];
        // ---- compute current chunk entirely from LDS ----
        #pragma unroll
        for (int th = 0; th < 4; ++th) {
            s8v wb0 = *(const s8v*)&w1s[cb][(th * 16 + col) * 72 + quad * 8];
            s8v wb1 = *(const s8v*)&w1s[cb][(th * 16 + col) * 72 + 32 + quad * 8];
            f4 hv = {0.f, 0.f, 0.f, 0.f};
            hv = __builtin_amdgcn_mfma_f32_16x16x32_bf16(fa0, wb0, hv, 0, 0, 0);
            hv = __builtin_amdgcn_mfma_f32_16x16x32_bf16(fa1, wb1, hv, 0, 0, 0);
            float bb = b1s[ch0 + th * 16 + col];
            #pragma unroll
            for (int r = 0; r < 4; ++r)
                myl[(quad * 4 + r) * 72 + th * 16 + col] =
                    f2bf(silu_f(hv[r] + bb));
        }
        // A-fragments of h (wave-private tile; compiler emits lgkmcnt waits)
        s8v ha0 = *(const s8v*)&myl[col * 72 + quad * 8];
        s8v ha1 = *(const s8v*)&myl[col * 72 + 32 + quad * 8];
        #pragma unroll
        for (int t2 = 0; t2 < 4; ++t2) {
            s8v vb0 = *(const s8v*)&w2s[cb][(t2 * 16 + col) * 72 + quad * 8];
            s8v vb1 = *(const s8v*)&w2s[cb][(t2 * 16 + col) * 72 + 32 + quad * 8];
            acc[t2] = __builtin_amdgcn_mfma_f32_16x16x32_bf16(ha0, vb0, acc[t2], 0, 0, 0);
            acc[t2] = __builtin_amdgcn_mfma_f32_16x16x32_bf16(ha1, vb1, acc[t2], 0, 0, 0);
        }
        __syncthreads();                       // all waves done reading buf nb
        if (kc < 15) {
            *(uint4*)&w1s[nb][srow0 * 72 + skb * 8] = na0;
            *(uint4*)&w1s[nb][srow1 * 72 + skb * 8] = na1;
            *(uint4*)&w2s[nb][srow0 * 72 + skb * 8] = nc0;
            *(uint4*)&w2s[nb][srow1 * 72 + skb * 8] = nc1;
        }
        __syncthreads();                       // buf nb ready for next iter
    }
    #pragma unroll
    for (int t2 = 0; t2 < 4; ++t2) {
        int c = c0 + t2 * 16 + col;
        float bb = b2[c];
        #pragma unroll
        for (int r = 0; r < 4; ++r) {
            int m = m0 + quad * 4 + r;
            if (m < N) x[(size_t)m * DMODEL + c] = f2bf(acc[t2][r] + bb);
        }
    }
}

// grid-stride dot over bf16 x, one atomic per block.
__global__ __launch_bounds__(256) void k_out_reduce(
    const bf16_t* __restrict__ x, const float* __restrict__ Wfc,
    float* __restrict__ acc, int NT) {
    __shared__ float sm[4];
    int tid = threadIdx.x;
    float v = 0.f;
    int np = NT / 2;
    const unsigned int* xp = (const unsigned int*)x;
    for (int i = blockIdx.x * blockDim.x + tid; i < np; i += gridDim.x * blockDim.x) {
        unsigned int u = xp[i];
        int c = (2 * i) & (DMODEL - 1);
        v = fmaf(bf_lo(u), Wfc[c], v);
        v = fmaf(bf_hi(u), Wfc[c + 1], v);
    }
    for (int off = 32; off > 0; off >>= 1) v += __shfl_xor(v, off, 64);
    if ((tid & 63) == 0) sm[tid >> 6] = v;
    __syncthreads();
    if (tid == 0) {
        float s = sm[0] + sm[1] + sm[2] + sm[3];
        atomicAdd(acc, s);
    }
}

__global__ void k_out_final(const float* __restrict__ acc, const float* __restrict__ bfc,
                            float* __restrict__ out, float invN) {
    out[0] = acc[0] * invN + bfc[0];
}

extern "C" void kernel_launch(void* const* d_in, const int* in_sizes, int n_in,
                              void* d_out, int out_size, void* d_ws, size_t ws_size,
                              hipStream_t stream) {
    const int*   an    = (const int*)d_in[0];
    const int*   gs    = (const int*)d_in[1];
    const int*   gd    = (const int*)d_in[2];
    const int*   ts    = (const int*)d_in[3];
    const int*   td    = (const int*)d_in[4];
    const float* r     = (const float*)d_in[5];
    const float* emb   = (const float*)d_in[6];
    const float* Wsrc  = (const float*)d_in[7];
    const float* bsrc  = (const float*)d_in[8];
    const float* Wdst  = (const float*)d_in[9];
    const float* bdst  = (const float*)d_in[10];
    const float* Wedge = (const float*)d_in[11];
    const float* bedge = (const float*)d_in[12];
    const float* attn  = (const float*)d_in[13];
    const float* W1    = (const float*)d_in[14];
    const float* b1    = (const float*)d_in[15];
    const float* W2    = (const float*)d_in[16];
    const float* b2    = (const float*)d_in[17];
    const float* Wfc   = (const float*)d_in[18];
    const float* bfc   = (const float*)d_in[19];

    const int N = in_sizes[0];
    const int E = in_sizes[1];
    const int T = in_sizes[3];
    const int NB = (E + 511) >> BSH;          // triplet-sort buckets

    char* w = (char*)d_ws;
    size_t off = 0;
    auto alloc = [&](size_t bytes) {
        void* p = w + off;
        off += (bytes + 255) & ~(size_t)255;
        return p;
    };
    bf16_t* xb     = (bf16_t*)alloc((size_t)(N + 64) * DMODEL * 2);
    float*  rn     = (float*) alloc((size_t)E * 3 * 4);
    float*  bl     = (float*) alloc(((size_t)E + 64) * 4);
    int*    rowp   = (int*)   alloc(((size_t)E + 1) * 4);
    int*    bsum   = (int*)   alloc(4096);
    int2*   packed = (int2*)  alloc((size_t)T * 8);
    int2*   ipair  = (int2*)  alloc((size_t)T * 8);
    float*  idv    = (float*) alloc((size_t)T * 4);
    int*    gbcnt  = (int*)   alloc(NBMAX * 4);
    int*    bbase  = (int*)   alloc((NBMAX + 1) * 4);
    int*    bcur   = (int*)   alloc(NBMAX * 4);
    int*    ecnt   = (int*)   alloc((size_t)N * 4);
    int*    erowp  = (int*)   alloc(((size_t)N + 1) * 4);
    int*    eord   = (int*)   alloc((size_t)E * 4);
    int*    eperm  = (int*)   alloc((size_t)E * 4);
    int*    dcnt   = (int*)   alloc(1024);
    int*    dcur   = (int*)   alloc(1024);
    float*  xs     = (float*) alloc((size_t)N * DM * 4);
    float*  xd     = (float*) alloc((size_t)N * DM * 4);
    bf16_t* xij    = (bf16_t*)alloc((size_t)E * DM * 2);
    bf16_t* msg    = (bf16_t*)alloc((size_t)E * DM * 2);
    bf16_t* ft     = (bf16_t*)alloc((size_t)(N + 64) * DM * 2);
    bf16_t* W1t    = (bf16_t*)alloc((size_t)3 * HDIM * DM * 2);
    bf16_t* W2t    = (bf16_t*)alloc((size_t)3 * DMODEL * HDIM * 2);
    bf16_t* Wedgt  = (bf16_t*)alloc((size_t)3 * DM * DMODEL * 2);
    bf16_t* Wst    = (bf16_t*)alloc((size_t)3 * DM * DMODEL * 2);
    bf16_t* Wdt    = (bf16_t*)alloc((size_t)3 * DM * DMODEL * 2);
    float*  accs   = (float*) alloc(64);
    (void)ws_size; (void)n_in; (void)out_size;

    const int nbScanN = (N + 255) / 256;
    const int nbT = (T + 4095) / 4096;

    // ---- setup (layer-invariant) ----
    k_embed<<<N, 256, 0, stream>>>(an, emb, xb);
    k_edge_geom<<<(E + 255) / 256, 256, 0, stream>>>(r, bl, rn, E);
    for (int l = 0; l < 3; ++l) {
        k_castT<<<dim3(DM / 32, HDIM / 32), 256, 0, stream>>>(
            W1 + (size_t)l * DM * HDIM, W1t + (size_t)l * HDIM * DM, DM, HDIM);
        k_castT<<<dim3(HDIM / 32, DMODEL / 32), 256, 0, stream>>>(
            W2 + (size_t)l * HDIM * DMODEL, W2t + (size_t)l * DMODEL * HDIM,
            HDIM, DMODEL);
        k_castT<<<dim3(DMODEL / 32, DM / 32), 256, 0, stream>>>(
            Wedge + (size_t)l * DMODEL * DM, Wedgt + (size_t)l * DM * DMODEL,
            DMODEL, DM);
        k_castT<<<dim3(DMODEL / 32, DM / 32), 256, 0, stream>>>(
            Wsrc + (size_t)l * DMODEL * DM, Wst + (size_t)l * DM * DMODEL,
            DMODEL, DM);
        k_castT<<<dim3(DMODEL / 32, DM / 32), 256, 0, stream>>>(
            Wdst + (size_t)l * DMODEL * DM, Wdt + (size_t)l * DM * DMODEL,
            DMODEL, DM);
    }
    // triplet CSR by t_dst: two-level bucket sort, all writes coalesced
    hipMemsetAsync(gbcnt, 0, NBMAX * 4, stream);
    hipMemsetAsync(bcur, 0, NBMAX * 4, stream);
    k_bhist<<<nbT, 512, 0, stream>>>(td, gbcnt, T, NB);
    k_bscan<<<1, 512, 0, stream>>>(gbcnt, bbase, NB, T);
    k_passA<<<nbT, 512, 0, stream>>>(ts, td, rn, bbase, bcur, ipair, idv, T, NB);
    k_passB<<<NB, 512, 0, stream>>>(ipair, idv, bbase, packed, rowp, E, T);
    // degree-sorted edge permutation (for k_edge_attn load balance)
    hipMemsetAsync(dcnt, 0, 1024, stream);
    hipMemsetAsync(dcur, 0, 1024, stream);
    k_deghist<<<(E + 255) / 256, 256, 0, stream>>>(rowp, dcnt, E);
    k_scan_mid<<<1, 1024, 0, stream>>>(dcnt, 256);
    k_degscatter<<<(E + 255) / 256, 256, 0, stream>>>(rowp, dcnt, dcur, eperm, E);
    // edge CSR by gd
    hipMemsetAsync(ecnt, 0, (size_t)N * 4, stream);
    k_hist<<<(E + 255) / 256, 256, 0, stream>>>(gd, ecnt, E);
    k_scan_part<<<nbScanN, 256, 0, stream>>>(ecnt, bsum, N);
    k_scan_mid<<<1, 1024, 0, stream>>>(bsum, nbScanN);
    k_scan_final<<<nbScanN, 256, 0, stream>>>(ecnt, bsum, erowp, N, E);
    hipMemsetAsync(ecnt, 0, (size_t)N * 4, stream);
    k_escatter<<<(E + 255) / 256, 256, 0, stream>>>(gd, erowp, ecnt, eord, E);

    // ---- layers ----
    for (int l = 0; l < 3; ++l) {
        k_node_proj<<<(N + 63) / 64, 256, 0, stream>>>(
            xb, Wst + (size_t)l * DM * DMODEL, bsrc + l * DM,
            Wdt + (size_t)l * DM * DMODEL, bdst + l * DM, xs, xd, N);
        k_xij<<<(E + 63) / 64, 256, 0, stream>>>(
            bl, Wedgt + (size_t)l * DM * DMODEL, bedge + l * DM,
            xs, xd, gs, gd, xij, E);
        k_edge_attn<<<(E * 4 + 255) / 256, 256, 0, stream>>>(
            xij, packed, rowp, attn + l * DM, eperm, msg, E);
        k_aggregate<<<(N * 16 + 255) / 256, 256, 0, stream>>>(
            msg, erowp, eord, ft, N);
        k_ffn_fused<<<dim3((N + 63) / 64, 4), 256, 0, stream>>>(
            ft, W1t + (size_t)l * HDIM * DM, b1 + l * HDIM,
            W2t + (size_t)l * DMODEL * HDIM, b2 + l * DMODEL, xb, N);
    }

    // ---- output head ----
    hipMemsetAsync(accs, 0, 4, stream);
    k_out_reduce<<<120, 256, 0, stream>>>(xb, Wfc, accs, N * DMODEL);
    k_out_final<<<1, 1, 0, stream>>>(accs, bfc, (float*)d_out, 1.0f / (float)N);
}

// Round 10
// 642.857 us; speedup vs baseline: 1.4584x; 1.1198x over previous
//
#include <hip/hip_runtime.h>
#include <math.h>

// M3GNet-like GNN forward. N=10000 nodes, E=160000 edges, T=1200000 triplets,
// D=256, DM=64, H=1024, L=3, output = scalar mean energy (fp32).
//
// R25: k_xij + k_node_proj weights -> LDS (R23's proven fix). Both showed
// the R21/R22 disease: VGPR=32 min-pressure schedule = {load->wait->MFMA}
// per W fragment, ~6400cy of exposed L2 latency per wave (k_xij: 53us,
// MfmaUtil 3.5%, VALUBusy 25%, nothing saturated). Weights are tiny
// (32KB/layer each): stage once per block into row-padded LDS (pad 264
// bf16 keeps uint4 alignment; b128 frag reads <=2-way bank-aliased=free),
// MFMA reads via ds_read_b128 which hipcc pipelines with fine lgkmcnt.
// Numerics bit-identical.

#define DM 64
#define DMODEL 256
#define HDIM 1024
#define WPAD 264

#define BSH 9            // log2(edges per bucket)
#define NBMAX 320        // max buckets (E <= 163840)
#define CAPB 4608        // passB LDS staging capacity (bucket ~3840+-62)

typedef unsigned short bf16_t;
typedef __attribute__((ext_vector_type(8))) short s8v;    // 8 bf16 (4 VGPRs)
typedef __attribute__((ext_vector_type(4))) float f4;     // MFMA acc

__device__ __forceinline__ bf16_t f2bf(float f) {
    unsigned int u = __float_as_uint(f);
    return (bf16_t)((u + 0x7FFFu + ((u >> 16) & 1u)) >> 16);   // RNE
}
__device__ __forceinline__ float bf_lo(unsigned int u) {
    return __uint_as_float(u << 16);
}
__device__ __forceinline__ float bf_hi(unsigned int u) {
    return __uint_as_float(u & 0xFFFF0000u);
}
__device__ __forceinline__ float silu_f(float u) {
    return u * __builtin_amdgcn_rcpf(1.f + __expf(-u));
}

__global__ void k_embed(const int* __restrict__ an, const float* __restrict__ emb,
                        bf16_t* __restrict__ x) {
    int n = blockIdx.x;
    int d = threadIdx.x;
    x[n * DMODEL + d] = f2bf(emb[an[n] * DMODEL + d]);
}

__global__ void k_edge_geom(const float* __restrict__ r, float* __restrict__ bl,
                            float* __restrict__ rn, int E) {
    int e = blockIdx.x * blockDim.x + threadIdx.x;
    if (e >= E) return;
    float a = r[e * 3 + 0], b = r[e * 3 + 1], c = r[e * 3 + 2];
    float l = sqrtf(a * a + b * b + c * c);
    bl[e] = l;
    float inv = 1.0f / l;
    rn[e * 3 + 0] = a * inv;
    rn[e * 3 + 1] = b * inv;
    rn[e * 3 + 2] = c * inv;
}

__global__ void k_hist(const int* __restrict__ idx, int* __restrict__ cnt, int M) {
    int t = blockIdx.x * blockDim.x + threadIdx.x;
    if (t < M) atomicAdd(&cnt[idx[t]], 1);
}

// ---- 3-phase exclusive scan (used for edge-CSR over N) ----
__global__ __launch_bounds__(256) void k_scan_part(
    const int* __restrict__ cnt, int* __restrict__ bsum, int M) {
    __shared__ int sm[4];
    int tid = threadIdx.x;
    int i = blockIdx.x * 256 + tid;
    int v = (i < M) ? cnt[i] : 0;
    for (int off = 32; off > 0; off >>= 1) v += __shfl_xor(v, off, 64);
    if ((tid & 63) == 0) sm[tid >> 6] = v;
    __syncthreads();
    if (tid == 0) bsum[blockIdx.x] = sm[0] + sm[1] + sm[2] + sm[3];
}

__global__ __launch_bounds__(1024) void k_scan_mid(int* __restrict__ bsum, int nb) {
    __shared__ int sm[1024];
    int tid = threadIdx.x;
    int v = (tid < nb) ? bsum[tid] : 0;
    sm[tid] = v;
    __syncthreads();
    for (int off = 1; off < 1024; off <<= 1) {
        int u = (tid >= off) ? sm[tid - off] : 0;
        __syncthreads();
        sm[tid] += u;
        __syncthreads();
    }
    if (tid < nb) bsum[tid] = sm[tid] - v;
}

__global__ __launch_bounds__(256) void k_scan_final(
    const int* __restrict__ cnt, const int* __restrict__ bsum,
    int* __restrict__ rowp, int M, int total) {
    __shared__ int sm[256];
    int tid = threadIdx.x;
    int i = blockIdx.x * 256 + tid;
    int v = (i < M) ? cnt[i] : 0;
    sm[tid] = v;
    __syncthreads();
    for (int off = 1; off < 256; off <<= 1) {
        int u = (tid >= off) ? sm[tid - off] : 0;
        __syncthreads();
        sm[tid] += u;
        __syncthreads();
    }
    if (i < M) rowp[i] = bsum[blockIdx.x] + sm[tid] - v;
    if (i == 0) rowp[M] = total;
}

// ---- two-level bucket sort of triplets by t_dst ----
// bucket b holds edges [b*512, b*512+512)

__global__ __launch_bounds__(512) void k_bhist(
    const int* __restrict__ td, int* __restrict__ gbcnt, int T, int NB) {
    __shared__ int h[NBMAX];
    int tid = threadIdx.x;
    for (int i = tid; i < NBMAX; i += 512) h[i] = 0;
    __syncthreads();
    int t0 = blockIdx.x * 4096;
    #pragma unroll
    for (int i = 0; i < 8; ++i) {
        int t = t0 + tid + i * 512;
        if (t < T) atomicAdd(&h[td[t] >> BSH], 1);
    }
    __syncthreads();
    for (int b = tid; b < NB; b += 512)
        if (h[b]) atomicAdd(&gbcnt[b], h[b]);
}

__global__ __launch_bounds__(512) void k_bscan(
    const int* __restrict__ gbcnt, int* __restrict__ bbase, int NB, int total) {
    __shared__ int sm[512];
    int tid = threadIdx.x;
    int v = (tid < NB) ? gbcnt[tid] : 0;
    sm[tid] = v;
    __syncthreads();
    for (int off = 1; off < 512; off <<= 1) {
        int u = (tid >= off) ? sm[tid - off] : 0;
        __syncthreads();
        sm[tid] += u;
        __syncthreads();
    }
    if (tid < NB) bbase[tid] = sm[tid] - v;
    if (tid == 0) bbase[NB] = total;
}

// passA: bin 4096 triplets into LDS by bucket, flush runs coalesced.
__global__ __launch_bounds__(512) void k_passA(
    const int* __restrict__ ts, const int* __restrict__ td,
    const float* __restrict__ rn, const int* __restrict__ bbase,
    int* __restrict__ bcur, int2* __restrict__ ipair, float* __restrict__ idv,
    int T, int NB) {
    __shared__ int   std_[4096];
    __shared__ int   ssrc[4096];
    __shared__ float sdv[4096];
    __shared__ int lbcnt[NBMAX], lbase[NBMAX], lpos[NBMAX], lgst[NBMAX],
                   lbb[NBMAX];
    __shared__ int ssc[512];
    int tid = threadIdx.x;
    int t0 = blockIdx.x * 4096;
    int total = min(4096, T - t0);
    for (int i = tid; i < NBMAX; i += 512) lbcnt[i] = 0;
    for (int i = tid; i < NB; i += 512) lbb[i] = bbase[i];
    __syncthreads();
    int   mtd[8], msrc[8];
    float md[8];
    #pragma unroll
    for (int i = 0; i < 8; ++i) {
        int idx = tid + i * 512;
        mtd[i] = -1;
        if (idx < total) {
            int t = t0 + idx;
            int a = ts[t], b = td[t];
            float d = rn[a * 3 + 0] * rn[b * 3 + 0]
                    + rn[a * 3 + 1] * rn[b * 3 + 1]
                    + rn[a * 3 + 2] * rn[b * 3 + 2];
            d = fminf(1.0f, fmaxf(-1.0f, d));
            mtd[i] = b; msrc[i] = a; md[i] = d;
            atomicAdd(&lbcnt[b >> BSH], 1);
        }
    }
    __syncthreads();
    // scan block-local bucket counts (NB <= 320 <= 512)
    int v = (tid < NB) ? lbcnt[tid] : 0;
    ssc[tid] = v;
    __syncthreads();
    for (int off = 1; off < 512; off <<= 1) {
        int u = (tid >= off) ? ssc[tid - off] : 0;
        __syncthreads();
        ssc[tid] += u;
        __syncthreads();
    }
    if (tid < NB) {
        int ex = ssc[tid] - v;
        lbase[tid] = ex;
        lpos[tid] = ex;
    }
    __syncthreads();
    // place into LDS staging grouped by bucket
    #pragma unroll
    for (int i = 0; i < 8; ++i) {
        if (mtd[i] >= 0) {
            int bin = mtd[i] >> BSH;
            int p = atomicAdd(&lpos[bin], 1);
            std_[p] = mtd[i]; ssrc[p] = msrc[i]; sdv[p] = md[i];
        }
    }
    __syncthreads();
    // reserve global runs: one atomic per (block, bucket)
    for (int b = tid; b < NB; b += 512)
        if (lbcnt[b]) lgst[b] = atomicAdd(&bcur[b], lbcnt[b]);
    __syncthreads();
    // coalesced flush of runs
    for (int j = tid; j < total; j += 512) {
        int bin = std_[j] >> BSH;
        int dest = lbb[bin] + lgst[bin] + (j - lbase[bin]);
        ipair[dest] = make_int2(std_[j], ssrc[j]);
        idv[dest] = sdv[j];
    }
}

// passB: one block per bucket; in-LDS edge hist + scan -> rowp (coalesced)
// and final packed placement flushed coalesced.
__global__ __launch_bounds__(512) void k_passB(
    const int2* __restrict__ ipair, const float* __restrict__ idv,
    const int* __restrict__ bbase, int2* __restrict__ packed,
    int* __restrict__ rowp, int E, int T) {
    __shared__ int2 spk[CAPB];
    __shared__ int hcnt[512], lcur[512], ssc[512];
    int tid = threadIdx.x;
    int b = blockIdx.x;
    int ibeg = bbase[b], iend = bbase[b + 1];
    int nb = iend - ibeg;
    int e0 = b << BSH;
    hcnt[tid] = 0;
    __syncthreads();
    for (int j = ibeg + tid; j < iend; j += 512)
        atomicAdd(&hcnt[ipair[j].x - e0], 1);
    __syncthreads();
    int v = hcnt[tid];
    ssc[tid] = v;
    __syncthreads();
    for (int off = 1; off < 512; off <<= 1) {
        int u = (tid >= off) ? ssc[tid - off] : 0;
        __syncthreads();
        ssc[tid] += u;
        __syncthreads();
    }
    int excl = ssc[tid] - v;
    lcur[tid] = excl;
    int e = e0 + tid;
    if (e < E) rowp[e] = ibeg + excl;
    if (b == 0 && tid == 0) rowp[E] = T;
    __syncthreads();
    bool staged = (nb <= CAPB);
    for (int j = ibeg + tid; j < iend; j += 512) {
        int2 pr = ipair[j];
        int pos = atomicAdd(&lcur[pr.x - e0], 1);
        int2 out = make_int2(pr.y, __float_as_int(idv[j]));
        if (staged) spk[pos] = out;
        else packed[ibeg + pos] = out;
    }
    __syncthreads();
    if (staged)
        for (int j = tid; j < nb; j += 512) packed[ibeg + j] = spk[j];
}

__global__ void k_escatter(const int* __restrict__ gd, const int* __restrict__ erowp,
                           int* __restrict__ cursor, int* __restrict__ eord, int E) {
    int e = blockIdx.x * blockDim.x + threadIdx.x;
    if (e >= E) return;
    int n = gd[e];
    int pos = erowp[n] + atomicAdd(&cursor[n], 1);
    eord[pos] = e;
}

// ---- degree bucket sort of edges (by triplet-segment length) ----
__global__ __launch_bounds__(256) void k_deghist(
    const int* __restrict__ rowp, int* __restrict__ dcnt, int E) {
    __shared__ int h[256];
    int tid = threadIdx.x;
    h[tid] = 0;
    __syncthreads();
    int e = blockIdx.x * 256 + tid;
    if (e < E) {
        int d = rowp[e + 1] - rowp[e];
        if (d > 255) d = 255;
        atomicAdd(&h[d], 1);
    }
    __syncthreads();
    if (h[tid]) atomicAdd(&dcnt[tid], h[tid]);
}

__global__ __launch_bounds__(256) void k_degscatter(
    const int* __restrict__ rowp, const int* __restrict__ doff,
    int* __restrict__ dcur, int* __restrict__ eperm, int E) {
    __shared__ int lcnt[256];
    __shared__ int base[256];
    int tid = threadIdx.x;
    lcnt[tid] = 0;
    __syncthreads();
    int e = blockIdx.x * 256 + tid;
    int d = 0, rk = 0;
    if (e < E) {
        d = rowp[e + 1] - rowp[e];
        if (d > 255) d = 255;
        rk = atomicAdd(&lcnt[d], 1);
    }
    __syncthreads();
    if (lcnt[tid]) base[tid] = atomicAdd(&dcur[tid], lcnt[tid]);
    __syncthreads();
    // DESCENDING degree order (LPT): longest-running waves dispatch first,
    // short waves backfill the tail (R24: 57us -> balances the drain).
    if (e < E) eperm[E - 1 - (doff[d] + base[d] + rk)] = e;
}

// 32x32 tiled transpose + cast: src fp32 [K][Nn] -> dst bf16 [Nn][K].
__global__ __launch_bounds__(256) void k_castT(
    const float* __restrict__ src, bf16_t* __restrict__ dst, int K, int Nn) {
    __shared__ float tile[32][33];
    int k0 = blockIdx.x * 32, n0 = blockIdx.y * 32;
    int tx = threadIdx.x & 31, ty = threadIdx.x >> 5;
    #pragma unroll
    for (int i = 0; i < 4; ++i) {
        int row = ty + i * 8;
        tile[row][tx] = src[(size_t)(k0 + row) * Nn + n0 + tx];
    }
    __syncthreads();
    #pragma unroll
    for (int i = 0; i < 4; ++i) {
        int row = ty + i * 8;
        dst[(size_t)(n0 + row) * K + k0 + tx] = f2bf(tile[tx][row]);
    }
}

// MFMA node_proj: xs = x@Wsrc + bs, xd = x@Wdst + bd (fp32 out).
// R25: Wst/Wdt staged into LDS (32KB each, padded rows); B frags via
// ds_read_b128 -> compiler pipelines (fixes VGPR-32 load-use serialization).
__global__ __launch_bounds__(256) void k_node_proj(
    const bf16_t* __restrict__ xb,
    const bf16_t* __restrict__ Wst, const float* __restrict__ bs,
    const bf16_t* __restrict__ Wdt, const float* __restrict__ bd,
    float* __restrict__ xs, float* __restrict__ xd, int N) {
    __shared__ bf16_t wsl[64 * WPAD];
    __shared__ bf16_t wdl[64 * WPAD];
    int tid = threadIdx.x;
    for (int i = tid; i < 2048; i += 256) {
        int row = i >> 5, inw = i & 31;
        *(uint4*)&wsl[row * WPAD + inw * 8] =
            *(const uint4*)&Wst[(size_t)row * DMODEL + inw * 8];
        *(uint4*)&wdl[row * WPAD + inw * 8] =
            *(const uint4*)&Wdt[(size_t)row * DMODEL + inw * 8];
    }
    __syncthreads();
    int w = tid >> 6, lane = tid & 63;
    int col = lane & 15, quad = lane >> 4;
    int m0 = blockIdx.x * 64 + w * 16;
    f4 as[4] = {{0.f,0.f,0.f,0.f},{0.f,0.f,0.f,0.f},
                {0.f,0.f,0.f,0.f},{0.f,0.f,0.f,0.f}};
    f4 ad[4] = {{0.f,0.f,0.f,0.f},{0.f,0.f,0.f,0.f},
                {0.f,0.f,0.f,0.f},{0.f,0.f,0.f,0.f}};
    #pragma unroll
    for (int k0 = 0; k0 < DMODEL; k0 += 32) {
        s8v a = *(const s8v*)&xb[(size_t)(m0 + col) * DMODEL + k0 + quad * 8];
        #pragma unroll
        for (int t = 0; t < 4; ++t) {
            s8v b1v = *(const s8v*)&wsl[(t * 16 + col) * WPAD + k0 + quad * 8];
            as[t] = __builtin_amdgcn_mfma_f32_16x16x32_bf16(a, b1v, as[t], 0, 0, 0);
            s8v b2v = *(const s8v*)&wdl[(t * 16 + col) * WPAD + k0 + quad * 8];
            ad[t] = __builtin_amdgcn_mfma_f32_16x16x32_bf16(a, b2v, ad[t], 0, 0, 0);
        }
    }
    #pragma unroll
    for (int t = 0; t < 4; ++t) {
        int c = t * 16 + col;
        float bsv = bs[c], bdv = bd[c];
        #pragma unroll
        for (int r = 0; r < 4; ++r) {
            int m = m0 + quad * 4 + r;
            if (m < N) {
                xs[(size_t)m * DM + c] = as[t][r] + bsv;
                xd[(size_t)m * DM + c] = ad[t][r] + bdv;
            }
        }
    }
}

// MFMA k_xij: xij[e][c] = (RBF(bl[e]) @ Wedge)[c] + xs[gs[e]][c] + xd[gd[e]][c] + be[c]
// R25: Wedgt staged into LDS (32KB, padded rows).
__global__ __launch_bounds__(256) void k_xij(
    const float* __restrict__ bl, const bf16_t* __restrict__ Wedgt,
    const float* __restrict__ be,
    const float* __restrict__ xs, const float* __restrict__ xd,
    const int* __restrict__ gs, const int* __restrict__ gd,
    bf16_t* __restrict__ xij, int E) {
    __shared__ bf16_t wel[64 * WPAD];
    int tid = threadIdx.x;
    for (int i = tid; i < 2048; i += 256) {
        int row = i >> 5, inw = i & 31;
        *(uint4*)&wel[row * WPAD + inw * 8] =
            *(const uint4*)&Wedgt[(size_t)row * DMODEL + inw * 8];
    }
    __syncthreads();
    int w = tid >> 6, lane = tid & 63;
    int col = lane & 15, quad = lane >> 4;
    int m0 = blockIdx.x * 64 + w * 16;
    const float step = 8.0f / 255.0f;
    const float gamma = (255.0f / 8.0f) * (255.0f / 8.0f);
    int me = m0 + col;
    float blv = (me < E) ? bl[me] : 0.f;
    f4 acc[4] = {{0.f,0.f,0.f,0.f},{0.f,0.f,0.f,0.f},
                 {0.f,0.f,0.f,0.f},{0.f,0.f,0.f,0.f}};
    #pragma unroll
    for (int k0 = 0; k0 < DMODEL; k0 += 32) {
        s8v a;
        #pragma unroll
        for (int j = 0; j < 8; ++j) {
            float c = (float)(k0 + quad * 8 + j) * step;
            float dd = blv - c;
            a[j] = (short)f2bf(__expf(-gamma * dd * dd));
        }
        #pragma unroll
        for (int t = 0; t < 4; ++t) {
            s8v b = *(const s8v*)&wel[(t * 16 + col) * WPAD + k0 + quad * 8];
            acc[t] = __builtin_amdgcn_mfma_f32_16x16x32_bf16(a, b, acc[t], 0, 0, 0);
        }
    }
    #pragma unroll
    for (int r = 0; r < 4; ++r) {
        int e = m0 + quad * 4 + r;
        if (e >= E) continue;
        int s = gs[e], d2 = gd[e];
        #pragma unroll
        for (int t = 0; t < 4; ++t) {
            int c = t * 16 + col;
            float v = acc[t][r] + xs[(size_t)s * DM + c] + xd[(size_t)d2 * DM + c] + be[c];
            xij[(size_t)e * DM + c] = f2bf(v);
        }
    }
}

// Fused logit+softmax+attend: 4 lanes per edge (degree-sorted via eperm),
// 16 channels per lane. Chebyshev T_k(d) for cos(k*theta); 2-shfl reduce.
__global__ __launch_bounds__(256) void k_edge_attn(
    const bf16_t* __restrict__ xij, const int2* __restrict__ packed,
    const int* __restrict__ rowp, const float* __restrict__ attn_l,
    const int* __restrict__ eperm, bf16_t* __restrict__ msg, int E) {
    int gtid = blockIdx.x * 256 + threadIdx.x;
    int ei = gtid >> 2;
    if (ei >= E) return;
    int q = gtid & 3;                  // channel block [16q, 16q+16)
    int e = eperm[ei];
    int beg = rowp[e], end = rowp[e + 1];

    float av[16];
    #pragma unroll
    for (int c = 0; c < 16; ++c) av[c] = attn_l[q * 16 + c];

    // my 16 channels of this edge's xij row (32B)
    uint4 xe0, xe1;
    {
        const uint4* xer = (const uint4*)&xij[(size_t)e * DM + q * 16];
        xe0 = xer[0]; xe1 = xer[1];
    }
    float acc[16];
    #pragma unroll
    for (int c = 0; c < 16; ++c) acc[c] = 0.f;
    float den = 0.f;

    if (beg < end) {
        // depth-1 pipeline priming
        int2 pk0 = packed[beg];
        int2 pk1 = (beg + 1 < end) ? packed[beg + 1] : pk0;
        const uint4* s0 = (const uint4*)&xij[(size_t)pk0.x * DM + q * 16];
        uint4 nsa = s0[0], nsb = s0[1];
        for (int p = beg; p < end; ++p) {
            float d = __int_as_float(pk0.y);
            uint4 xa = nsa, xb = nsb;
            if (p + 1 < end) {
                const uint4* sn = (const uint4*)&xij[(size_t)pk1.x * DM + q * 16];
                nsa = sn[0]; nsb = sn[1];
                pk0 = pk1;
                if (p + 2 < end) pk1 = packed[p + 2];
            }
            float d2 = d + d;
            // ladder: seeds T_{16q}, T_{16q+1} via 2TmTn = T_{m+n} + T_{|m-n|}
            float t2  = fmaf(d2, d, -1.f);
            float t3  = fmaf(d2, t2, -d);
            float t4  = fmaf(t2 + t2, t2, -1.f);
            float t7  = fmaf(t4 + t4, t3, -d);
            float t8  = fmaf(t4 + t4, t4, -1.f);
            float t15 = fmaf(t8 + t8, t7, -d);
            float t16 = fmaf(t8 + t8, t8, -1.f);
            float t17 = fmaf(t16 + t16, d, -t15);
            float t31 = fmaf(t16 + t16, t15, -d);
            float t32 = fmaf(t16 + t16, t16, -1.f);
            float t33 = fmaf(t32 + t32, d, -t31);
            float t48 = fmaf(t32 + t32, t16, -t16);
            float t49 = fmaf(t32 + t32, t17, -t15);
            float za, zb;                        // T_{16q}, T_{16q+1}
            if (q == 0)      { za = 1.f;  zb = d;   }
            else if (q == 1) { za = t16;  zb = t17; }
            else if (q == 2) { za = t32;  zb = t33; }
            else             { za = t48;  zb = t49; }
            float logit = 0.f;
            #define CH2(uw, ew, c)                                            \
            {                                                                 \
                float u0 = za + bf_lo(uw) + bf_lo(ew);                        \
                float zn = fmaf(d2, zb, -za); za = zb; zb = zn;               \
                float u1 = za + bf_hi(uw) + bf_hi(ew);                        \
                zn = fmaf(d2, zb, -za); za = zb; zb = zn;                     \
                logit = fmaf(silu_f(u0), av[c], logit);                       \
                logit = fmaf(silu_f(u1), av[c + 1], logit);                   \
            }
            CH2(xa.x, xe0.x, 0);
            CH2(xa.y, xe0.y, 2);
            CH2(xa.z, xe0.z, 4);
            CH2(xa.w, xe0.w, 6);
            CH2(xb.x, xe1.x, 8);
            CH2(xb.y, xe1.y, 10);
            CH2(xb.z, xe1.z, 12);
            CH2(xb.w, xe1.w, 14);
            #undef CH2
            // sum logit across the 4-lane group
            logit += __shfl_xor(logit, 1, 64);
            logit += __shfl_xor(logit, 2, 64);
            float wg = __expf(logit);
            den += wg;
            acc[0]  = fmaf(wg, bf_lo(xa.x), acc[0]);
            acc[1]  = fmaf(wg, bf_hi(xa.x), acc[1]);
            acc[2]  = fmaf(wg, bf_lo(xa.y), acc[2]);
            acc[3]  = fmaf(wg, bf_hi(xa.y), acc[3]);
            acc[4]  = fmaf(wg, bf_lo(xa.z), acc[4]);
            acc[5]  = fmaf(wg, bf_hi(xa.z), acc[5]);
            acc[6]  = fmaf(wg, bf_lo(xa.w), acc[6]);
            acc[7]  = fmaf(wg, bf_hi(xa.w), acc[7]);
            acc[8]  = fmaf(wg, bf_lo(xb.x), acc[8]);
            acc[9]  = fmaf(wg, bf_hi(xb.x), acc[9]);
            acc[10] = fmaf(wg, bf_lo(xb.y), acc[10]);
            acc[11] = fmaf(wg, bf_hi(xb.y), acc[11]);
            acc[12] = fmaf(wg, bf_lo(xb.z), acc[12]);
            acc[13] = fmaf(wg, bf_hi(xb.z), acc[13]);
            acc[14] = fmaf(wg, bf_lo(xb.w), acc[14]);
            acc[15] = fmaf(wg, bf_hi(xb.w), acc[15]);
        }
    }
    float inv = (den > 0.f) ? 1.f / den : 0.f;
    uint4 o0, o1;
    o0.x = (unsigned int)f2bf(acc[0] * inv)  | ((unsigned int)f2bf(acc[1] * inv) << 16);
    o0.y = (unsigned int)f2bf(acc[2] * inv)  | ((unsigned int)f2bf(acc[3] * inv) << 16);
    o0.z = (unsigned int)f2bf(acc[4] * inv)  | ((unsigned int)f2bf(acc[5] * inv) << 16);
    o0.w = (unsigned int)f2bf(acc[6] * inv)  | ((unsigned int)f2bf(acc[7] * inv) << 16);
    o1.x = (unsigned int)f2bf(acc[8] * inv)  | ((unsigned int)f2bf(acc[9] * inv) << 16);
    o1.y = (unsigned int)f2bf(acc[10] * inv) | ((unsigned int)f2bf(acc[11] * inv) << 16);
    o1.z = (unsigned int)f2bf(acc[12] * inv) | ((unsigned int)f2bf(acc[13] * inv) << 16);
    o1.w = (unsigned int)f2bf(acc[14] * inv) | ((unsigned int)f2bf(acc[15] * inv) << 16);
    uint4* op = (uint4*)&msg[(size_t)e * DM + q * 16];
    op[0] = o0;
    op[1] = o1;
}

// thread per (node, channel-quad): sum bf16 msg -> bf16 ft.
__global__ __launch_bounds__(256) void k_aggregate(
    const bf16_t* __restrict__ msg, const int* __restrict__ erowp,
    const int* __restrict__ eord, bf16_t* __restrict__ ft, int N) {
    int gtid = blockIdx.x * 256 + threadIdx.x;
    int n = gtid >> 4;
    if (n >= N) return;
    int quad = gtid & 15;
    int beg = erowp[n], end = erowp[n + 1];
    float a0 = 0.f, a1 = 0.f, a2 = 0.f, a3 = 0.f;
    for (int j = beg; j < end; ++j) {
        uint2 uv = *(const uint2*)&msg[(size_t)eord[j] * DM + quad * 4];
        a0 += bf_lo(uv.x); a1 += bf_hi(uv.x);
        a2 += bf_lo(uv.y); a3 += bf_hi(uv.y);
    }
    ushort4 o = {f2bf(a0), f2bf(a1), f2bf(a2), f2bf(a3)};
    *(ushort4*)&ft[(size_t)n * DM + quad * 4] = o;
}

// Fused FFN: x = silu(ft@W1 + b1) @ W2 + b2; h never leaves the CU.
// Grid (N/64, 4): blockIdx.y owns 64 output cols. Block = 64 rows, 4 waves.
// Weights stream through double-buffered LDS (pad-72 rows). R23.
__global__ __launch_bounds__(256) void k_ffn_fused(
    const bf16_t* __restrict__ ft, const bf16_t* __restrict__ W1t,
    const float* __restrict__ b1, const bf16_t* __restrict__ W2t,
    const float* __restrict__ b2, bf16_t* __restrict__ x, int N) {
    __shared__ bf16_t w1s[2][64 * 72];
    __shared__ bf16_t w2s[2][64 * 72];
    __shared__ bf16_t hld[4][16 * 72];
    __shared__ float b1s[HDIM];
    int tid = threadIdx.x;
    int w = tid >> 6, lane = tid & 63;
    int col = lane & 15, quad = lane >> 4;
    int m0 = blockIdx.x * 64 + w * 16;
    int c0 = blockIdx.y * 64;                 // this block's output columns
    bf16_t* myl = hld[w];

    // bias table -> LDS once
    #pragma unroll
    for (int j = 0; j < 4; ++j) b1s[tid + j * 256] = b1[tid + j * 256];

    // ft A-fragments for this wave's 16 rows (k = 0..63), held all kernel
    s8v fa0 = *(const s8v*)&ft[(size_t)(m0 + col) * DM + quad * 8];
    s8v fa1 = *(const s8v*)&ft[(size_t)(m0 + col) * DM + 32 + quad * 8];

    // staging geometry: piece idx = r*256+tid -> row = idx>>3, kblk = idx&7
    int srow0 = tid >> 3;            // r=0 rows 0..31
    int srow1 = 32 + srow0;          // r=1 rows 32..63
    int skb = tid & 7;

    f4 acc[4] = {{0.f,0.f,0.f,0.f},{0.f,0.f,0.f,0.f},
                 {0.f,0.f,0.f,0.f},{0.f,0.f,0.f,0.f}};

    // ---- prologue: stage chunk 0 into buffer 0 ----
    {
        uint4 a0 = *(const uint4*)&W1t[(size_t)srow0 * DM + skb * 8];
        uint4 a1 = *(const uint4*)&W1t[(size_t)srow1 * DM + skb * 8];
        uint4 c0v = *(const uint4*)&W2t[(size_t)(c0 + srow0) * HDIM + skb * 8];
        uint4 c1v = *(const uint4*)&W2t[(size_t)(c0 + srow1) * HDIM + skb * 8];
        *(uint4*)&w1s[0][srow0 * 72 + skb * 8] = a0;
        *(uint4*)&w1s[0][srow1 * 72 + skb * 8] = a1;
        *(uint4*)&w2s[0][srow0 * 72 + skb * 8] = c0v;
        *(uint4*)&w2s[0][srow1 * 72 + skb * 8] = c1v;
    }
    __syncthreads();

    #pragma unroll 1
    for (int kc = 0; kc < 16; ++kc) {         // h-col chunks of 64
        int cb = kc & 1, nb = cb ^ 1;
        int ch0 = kc * 64;
        int chn = (kc < 15) ? ch0 + 64 : ch0;  // clamped (load redundant on last)
        // issue next-chunk global loads into regs (no use until after barrier)
        uint4 na0 = *(const uint4*)&W1t[(size_t)(chn + srow0) * DM + skb * 8];
        uint4 na1 = *(const uint4*)&W1t[(size_t)(chn + srow1) * DM + skb * 8];
        uint4 nc0 = *(const uint4*)&W2t[(size_t)(c0 + srow0) * HDIM + chn + skb * 8];
        uint4 nc1 = *(const uint4*)&W2t[(size_t)(c0 + srow1) * HDIM + chn + skb * 8];
        // ---- compute current chunk entirely from LDS ----
        #pragma unroll
        for (int th = 0; th < 4; ++th) {
            s8v wb0 = *(const s8v*)&w1s[cb][(th * 16 + col) * 72 + quad * 8];
            s8v wb1 = *(const s8v*)&w1s[cb][(th * 16 + col) * 72 + 32 + quad * 8];
            f4 hv = {0.f, 0.f, 0.f, 0.f};
            hv = __builtin_amdgcn_mfma_f32_16x16x32_bf16(fa0, wb0, hv, 0, 0, 0);
            hv = __builtin_amdgcn_mfma_f32_16x16x32_bf16(fa1, wb1, hv, 0, 0, 0);
            float bb = b1s[ch0 + th * 16 + col];
            #pragma unroll
            for (int r = 0; r < 4; ++r)
                myl[(quad * 4 + r) * 72 + th * 16 + col] =
                    f2bf(silu_f(hv[r] + bb));
        }
        // A-fragments of h (wave-private tile; compiler emits lgkmcnt waits)
        s8v ha0 = *(const s8v*)&myl[col * 72 + quad * 8];
        s8v ha1 = *(const s8v*)&myl[col * 72 + 32 + quad * 8];
        #pragma unroll
        for (int t2 = 0; t2 < 4; ++t2) {
            s8v vb0 = *(const s8v*)&w2s[cb][(t2 * 16 + col) * 72 + quad * 8];
            s8v vb1 = *(const s8v*)&w2s[cb][(t2 * 16 + col) * 72 + 32 + quad * 8];
            acc[t2] = __builtin_amdgcn_mfma_f32_16x16x32_bf16(ha0, vb0, acc[t2], 0, 0, 0);
            acc[t2] = __builtin_amdgcn_mfma_f32_16x16x32_bf16(ha1, vb1, acc[t2], 0, 0, 0);
        }
        __syncthreads();                       // all waves done reading buf nb
        if (kc < 15) {
            *(uint4*)&w1s[nb][srow0 * 72 + skb * 8] = na0;
            *(uint4*)&w1s[nb][srow1 * 72 + skb * 8] = na1;
            *(uint4*)&w2s[nb][srow0 * 72 + skb * 8] = nc0;
            *(uint4*)&w2s[nb][srow1 * 72 + skb * 8] = nc1;
        }
        __syncthreads();                       // buf nb ready for next iter
    }
    #pragma unroll
    for (int t2 = 0; t2 < 4; ++t2) {
        int c = c0 + t2 * 16 + col;
        float bb = b2[c];
        #pragma unroll
        for (int r = 0; r < 4; ++r) {
            int m = m0 + quad * 4 + r;
            if (m < N) x[(size_t)m * DMODEL + c] = f2bf(acc[t2][r] + bb);
        }
    }
}

// grid-stride dot over bf16 x, one atomic per block.
__global__ __launch_bounds__(256) void k_out_reduce(
    const bf16_t* __restrict__ x, const float* __restrict__ Wfc,
    float* __restrict__ acc, int NT) {
    __shared__ float sm[4];
    int tid = threadIdx.x;
    float v = 0.f;
    int np = NT / 2;
    const unsigned int* xp = (const unsigned int*)x;
    for (int i = blockIdx.x * blockDim.x + tid; i < np; i += gridDim.x * blockDim.x) {
        unsigned int u = xp[i];
        int c = (2 * i) & (DMODEL - 1);
        v = fmaf(bf_lo(u), Wfc[c], v);
        v = fmaf(bf_hi(u), Wfc[c + 1], v);
    }
    for (int off = 32; off > 0; off >>= 1) v += __shfl_xor(v, off, 64);
    if ((tid & 63) == 0) sm[tid >> 6] = v;
    __syncthreads();
    if (tid == 0) {
        float s = sm[0] + sm[1] + sm[2] + sm[3];
        atomicAdd(acc, s);
    }
}

__global__ void k_out_final(const float* __restrict__ acc, const float* __restrict__ bfc,
                            float* __restrict__ out, float invN) {
    out[0] = acc[0] * invN + bfc[0];
}

extern "C" void kernel_launch(void* const* d_in, const int* in_sizes, int n_in,
                              void* d_out, int out_size, void* d_ws, size_t ws_size,
                              hipStream_t stream) {
    const int*   an    = (const int*)d_in[0];
    const int*   gs    = (const int*)d_in[1];
    const int*   gd    = (const int*)d_in[2];
    const int*   ts    = (const int*)d_in[3];
    const int*   td    = (const int*)d_in[4];
    const float* r     = (const float*)d_in[5];
    const float* emb   = (const float*)d_in[6];
    const float* Wsrc  = (const float*)d_in[7];
    const float* bsrc  = (const float*)d_in[8];
    const float* Wdst  = (const float*)d_in[9];
    const float* bdst  = (const float*)d_in[10];
    const float* Wedge = (const float*)d_in[11];
    const float* bedge = (const float*)d_in[12];
    const float* attn  = (const float*)d_in[13];
    const float* W1    = (const float*)d_in[14];
    const float* b1    = (const float*)d_in[15];
    const float* W2    = (const float*)d_in[16];
    const float* b2    = (const float*)d_in[17];
    const float* Wfc   = (const float*)d_in[18];
    const float* bfc   = (const float*)d_in[19];

    const int N = in_sizes[0];
    const int E = in_sizes[1];
    const int T = in_sizes[3];
    const int NB = (E + 511) >> BSH;          // triplet-sort buckets

    char* w = (char*)d_ws;
    size_t off = 0;
    auto alloc = [&](size_t bytes) {
        void* p = w + off;
        off += (bytes + 255) & ~(size_t)255;
        return p;
    };
    bf16_t* xb     = (bf16_t*)alloc((size_t)(N + 64) * DMODEL * 2);
    float*  rn     = (float*) alloc((size_t)E * 3 * 4);
    float*  bl     = (float*) alloc(((size_t)E + 64) * 4);
    int*    rowp   = (int*)   alloc(((size_t)E + 1) * 4);
    int*    bsum   = (int*)   alloc(4096);
    int2*   packed = (int2*)  alloc((size_t)T * 8);
    int2*   ipair  = (int2*)  alloc((size_t)T * 8);
    float*  idv    = (float*) alloc((size_t)T * 4);
    int*    gbcnt  = (int*)   alloc(NBMAX * 4);
    int*    bbase  = (int*)   alloc((NBMAX + 1) * 4);
    int*    bcur   = (int*)   alloc(NBMAX * 4);
    int*    ecnt   = (int*)   alloc((size_t)N * 4);
    int*    erowp  = (int*)   alloc(((size_t)N + 1) * 4);
    int*    eord   = (int*)   alloc((size_t)E * 4);
    int*    eperm  = (int*)   alloc((size_t)E * 4);
    int*    dcnt   = (int*)   alloc(1024);
    int*    dcur   = (int*)   alloc(1024);
    float*  xs     = (float*) alloc((size_t)N * DM * 4);
    float*  xd     = (float*) alloc((size_t)N * DM * 4);
    bf16_t* xij    = (bf16_t*)alloc((size_t)E * DM * 2);
    bf16_t* msg    = (bf16_t*)alloc((size_t)E * DM * 2);
    bf16_t* ft     = (bf16_t*)alloc((size_t)(N + 64) * DM * 2);
    bf16_t* W1t    = (bf16_t*)alloc((size_t)3 * HDIM * DM * 2);
    bf16_t* W2t    = (bf16_t*)alloc((size_t)3 * DMODEL * HDIM * 2);
    bf16_t* Wedgt  = (bf16_t*)alloc((size_t)3 * DM * DMODEL * 2);
    bf16_t* Wst    = (bf16_t*)alloc((size_t)3 * DM * DMODEL * 2);
    bf16_t* Wdt    = (bf16_t*)alloc((size_t)3 * DM * DMODEL * 2);
    float*  accs   = (float*) alloc(64);
    (void)ws_size; (void)n_in; (void)out_size;

    const int nbScanN = (N + 255) / 256;
    const int nbT = (T + 4095) / 4096;

    // ---- setup (layer-invariant) ----
    k_embed<<<N, 256, 0, stream>>>(an, emb, xb);
    k_edge_geom<<<(E + 255) / 256, 256, 0, stream>>>(r, bl, rn, E);
    for (int l = 0; l < 3; ++l) {
        k_castT<<<dim3(DM / 32, HDIM / 32), 256, 0, stream>>>(
            W1 + (size_t)l * DM * HDIM, W1t + (size_t)l * HDIM * DM, DM, HDIM);
        k_castT<<<dim3(HDIM / 32, DMODEL / 32), 256, 0, stream>>>(
            W2 + (size_t)l * HDIM * DMODEL, W2t + (size_t)l * DMODEL * HDIM,
            HDIM, DMODEL);
        k_castT<<<dim3(DMODEL / 32, DM / 32), 256, 0, stream>>>(
            Wedge + (size_t)l * DMODEL * DM, Wedgt + (size_t)l * DM * DMODEL,
            DMODEL, DM);
        k_castT<<<dim3(DMODEL / 32, DM / 32), 256, 0, stream>>>(
            Wsrc + (size_t)l * DMODEL * DM, Wst + (size_t)l * DM * DMODEL,
            DMODEL, DM);
        k_castT<<<dim3(DMODEL / 32, DM / 32), 256, 0, stream>>>(
            Wdst + (size_t)l * DMODEL * DM, Wdt + (size_t)l * DM * DMODEL,
            DMODEL, DM);
    }
    // triplet CSR by t_dst: two-level bucket sort, all writes coalesced
    hipMemsetAsync(gbcnt, 0, NBMAX * 4, stream);
    hipMemsetAsync(bcur, 0, NBMAX * 4, stream);
    k_bhist<<<nbT, 512, 0, stream>>>(td, gbcnt, T, NB);
    k_bscan<<<1, 512, 0, stream>>>(gbcnt, bbase, NB, T);
    k_passA<<<nbT, 512, 0, stream>>>(ts, td, rn, bbase, bcur, ipair, idv, T, NB);
    k_passB<<<NB, 512, 0, stream>>>(ipair, idv, bbase, packed, rowp, E, T);
    // degree-sorted edge permutation (for k_edge_attn load balance)
    hipMemsetAsync(dcnt, 0, 1024, stream);
    hipMemsetAsync(dcur, 0, 1024, stream);
    k_deghist<<<(E + 255) / 256, 256, 0, stream>>>(rowp, dcnt, E);
    k_scan_mid<<<1, 1024, 0, stream>>>(dcnt, 256);
    k_degscatter<<<(E + 255) / 256, 256, 0, stream>>>(rowp, dcnt, dcur, eperm, E);
    // edge CSR by gd
    hipMemsetAsync(ecnt, 0, (size_t)N * 4, stream);
    k_hist<<<(E + 255) / 256, 256, 0, stream>>>(gd, ecnt, E);
    k_scan_part<<<nbScanN, 256, 0, stream>>>(ecnt, bsum, N);
    k_scan_mid<<<1, 1024, 0, stream>>>(bsum, nbScanN);
    k_scan_final<<<nbScanN, 256, 0, stream>>>(ecnt, bsum, erowp, N, E);
    hipMemsetAsync(ecnt, 0, (size_t)N * 4, stream);
    k_escatter<<<(E + 255) / 256, 256, 0, stream>>>(gd, erowp, ecnt, eord, E);

    // ---- layers ----
    for (int l = 0; l < 3; ++l) {
        k_node_proj<<<(N + 63) / 64, 256, 0, stream>>>(
            xb, Wst + (size_t)l * DM * DMODEL, bsrc + l * DM,
            Wdt + (size_t)l * DM * DMODEL, bdst + l * DM, xs, xd, N);
        k_xij<<<(E + 63) / 64, 256, 0, stream>>>(
            bl, Wedgt + (size_t)l * DM * DMODEL, bedge + l * DM,
            xs, xd, gs, gd, xij, E);
        k_edge_attn<<<(E * 4 + 255) / 256, 256, 0, stream>>>(
            xij, packed, rowp, attn + l * DM, eperm, msg, E);
        k_aggregate<<<(N * 16 + 255) / 256, 256, 0, stream>>>(
            msg, erowp, eord, ft, N);
        k_ffn_fused<<<dim3((N + 63) / 64, 4), 256, 0, stream>>>(
            ft, W1t + (size_t)l * HDIM * DM, b1 + l * HDIM,
            W2t + (size_t)l * DMODEL * HDIM, b2 + l * DMODEL, xb, N);
    }

    // ---- output head ----
    hipMemsetAsync(accs, 0, 4, stream);
    k_out_reduce<<<120, 256, 0, stream>>>(xb, Wfc, accs, N * DMODEL);
    k_out_final<<<1, 1, 0, stream>>>(accs, bfc, (float*)d_out, 1.0f / (float)N);
}

// Round 11
// 635.274 us; speedup vs baseline: 1.4758x; 1.0119x over previous
//
#include <hip/hip_runtime.h>
#include <math.h>

// M3GNet-like GNN forward. N=10000 nodes, E=160000 edges, T=1200000 triplets,
// D=256, DM=64, H=1024, L=3, output = scalar mean energy (fp32).
//
// R26: two changes.
//  (a) k_edge_attn: s_setprio(1) on high-degree waves (degree is wave-
//      uniform after the sort). Light waves flood the SIMDs and time-share
//      issue with the deg~30 waves that set the makespan (occ 34%, VALU
//      72%, 45us vs ~38us random-BW floor). Priority lets heavy waves
//      stream at full issue rate. Zero numerics risk.
//  (b) xs/xd fp32 -> bf16. k_xij's epilogue gathers E x 512B = 82MB random
//      from a 10MB working set (> per-XCD L2) -- the biggest hidden cost
//      (~30us x3). bf16 halves it. Rounding (<=2^-9 rel) lands inside
//      xij's own bf16 quantization.

#define DM 64
#define DMODEL 256
#define HDIM 1024
#define WPAD 264

#define BSH 9            // log2(edges per bucket)
#define NBMAX 320        // max buckets (E <= 163840)
#define CAPB 4608        // passB LDS staging capacity (bucket ~3840+-62)

typedef unsigned short bf16_t;
typedef __attribute__((ext_vector_type(8))) short s8v;    // 8 bf16 (4 VGPRs)
typedef __attribute__((ext_vector_type(4))) float f4;     // MFMA acc

__device__ __forceinline__ bf16_t f2bf(float f) {
    unsigned int u = __float_as_uint(f);
    return (bf16_t)((u + 0x7FFFu + ((u >> 16) & 1u)) >> 16);   // RNE
}
__device__ __forceinline__ float bf_lo(unsigned int u) {
    return __uint_as_float(u << 16);
}
__device__ __forceinline__ float bf_hi(unsigned int u) {
    return __uint_as_float(u & 0xFFFF0000u);
}
__device__ __forceinline__ float bf2f(bf16_t v) {
    return __uint_as_float((unsigned int)v << 16);
}
__device__ __forceinline__ float silu_f(float u) {
    return u * __builtin_amdgcn_rcpf(1.f + __expf(-u));
}

__global__ void k_embed(const int* __restrict__ an, const float* __restrict__ emb,
                        bf16_t* __restrict__ x) {
    int n = blockIdx.x;
    int d = threadIdx.x;
    x[n * DMODEL + d] = f2bf(emb[an[n] * DMODEL + d]);
}

__global__ void k_edge_geom(const float* __restrict__ r, float* __restrict__ bl,
                            float* __restrict__ rn, int E) {
    int e = blockIdx.x * blockDim.x + threadIdx.x;
    if (e >= E) return;
    float a = r[e * 3 + 0], b = r[e * 3 + 1], c = r[e * 3 + 2];
    float l = sqrtf(a * a + b * b + c * c);
    bl[e] = l;
    float inv = 1.0f / l;
    rn[e * 3 + 0] = a * inv;
    rn[e * 3 + 1] = b * inv;
    rn[e * 3 + 2] = c * inv;
}

__global__ void k_hist(const int* __restrict__ idx, int* __restrict__ cnt, int M) {
    int t = blockIdx.x * blockDim.x + threadIdx.x;
    if (t < M) atomicAdd(&cnt[idx[t]], 1);
}

// ---- 3-phase exclusive scan (used for edge-CSR over N) ----
__global__ __launch_bounds__(256) void k_scan_part(
    const int* __restrict__ cnt, int* __restrict__ bsum, int M) {
    __shared__ int sm[4];
    int tid = threadIdx.x;
    int i = blockIdx.x * 256 + tid;
    int v = (i < M) ? cnt[i] : 0;
    for (int off = 32; off > 0; off >>= 1) v += __shfl_xor(v, off, 64);
    if ((tid & 63) == 0) sm[tid >> 6] = v;
    __syncthreads();
    if (tid == 0) bsum[blockIdx.x] = sm[0] + sm[1] + sm[2] + sm[3];
}

__global__ __launch_bounds__(1024) void k_scan_mid(int* __restrict__ bsum, int nb) {
    __shared__ int sm[1024];
    int tid = threadIdx.x;
    int v = (tid < nb) ? bsum[tid] : 0;
    sm[tid] = v;
    __syncthreads();
    for (int off = 1; off < 1024; off <<= 1) {
        int u = (tid >= off) ? sm[tid - off] : 0;
        __syncthreads();
        sm[tid] += u;
        __syncthreads();
    }
    if (tid < nb) bsum[tid] = sm[tid] - v;
}

__global__ __launch_bounds__(256) void k_scan_final(
    const int* __restrict__ cnt, const int* __restrict__ bsum,
    int* __restrict__ rowp, int M, int total) {
    __shared__ int sm[256];
    int tid = threadIdx.x;
    int i = blockIdx.x * 256 + tid;
    int v = (i < M) ? cnt[i] : 0;
    sm[tid] = v;
    __syncthreads();
    for (int off = 1; off < 256; off <<= 1) {
        int u = (tid >= off) ? sm[tid - off] : 0;
        __syncthreads();
        sm[tid] += u;
        __syncthreads();
    }
    if (i < M) rowp[i] = bsum[blockIdx.x] + sm[tid] - v;
    if (i == 0) rowp[M] = total;
}

// ---- two-level bucket sort of triplets by t_dst ----
// bucket b holds edges [b*512, b*512+512)

__global__ __launch_bounds__(512) void k_bhist(
    const int* __restrict__ td, int* __restrict__ gbcnt, int T, int NB) {
    __shared__ int h[NBMAX];
    int tid = threadIdx.x;
    for (int i = tid; i < NBMAX; i += 512) h[i] = 0;
    __syncthreads();
    int t0 = blockIdx.x * 4096;
    #pragma unroll
    for (int i = 0; i < 8; ++i) {
        int t = t0 + tid + i * 512;
        if (t < T) atomicAdd(&h[td[t] >> BSH], 1);
    }
    __syncthreads();
    for (int b = tid; b < NB; b += 512)
        if (h[b]) atomicAdd(&gbcnt[b], h[b]);
}

__global__ __launch_bounds__(512) void k_bscan(
    const int* __restrict__ gbcnt, int* __restrict__ bbase, int NB, int total) {
    __shared__ int sm[512];
    int tid = threadIdx.x;
    int v = (tid < NB) ? gbcnt[tid] : 0;
    sm[tid] = v;
    __syncthreads();
    for (int off = 1; off < 512; off <<= 1) {
        int u = (tid >= off) ? sm[tid - off] : 0;
        __syncthreads();
        sm[tid] += u;
        __syncthreads();
    }
    if (tid < NB) bbase[tid] = sm[tid] - v;
    if (tid == 0) bbase[NB] = total;
}

// passA: bin 4096 triplets into LDS by bucket, flush runs coalesced.
__global__ __launch_bounds__(512) void k_passA(
    const int* __restrict__ ts, const int* __restrict__ td,
    const float* __restrict__ rn, const int* __restrict__ bbase,
    int* __restrict__ bcur, int2* __restrict__ ipair, float* __restrict__ idv,
    int T, int NB) {
    __shared__ int   std_[4096];
    __shared__ int   ssrc[4096];
    __shared__ float sdv[4096];
    __shared__ int lbcnt[NBMAX], lbase[NBMAX], lpos[NBMAX], lgst[NBMAX],
                   lbb[NBMAX];
    __shared__ int ssc[512];
    int tid = threadIdx.x;
    int t0 = blockIdx.x * 4096;
    int total = min(4096, T - t0);
    for (int i = tid; i < NBMAX; i += 512) lbcnt[i] = 0;
    for (int i = tid; i < NB; i += 512) lbb[i] = bbase[i];
    __syncthreads();
    int   mtd[8], msrc[8];
    float md[8];
    #pragma unroll
    for (int i = 0; i < 8; ++i) {
        int idx = tid + i * 512;
        mtd[i] = -1;
        if (idx < total) {
            int t = t0 + idx;
            int a = ts[t], b = td[t];
            float d = rn[a * 3 + 0] * rn[b * 3 + 0]
                    + rn[a * 3 + 1] * rn[b * 3 + 1]
                    + rn[a * 3 + 2] * rn[b * 3 + 2];
            d = fminf(1.0f, fmaxf(-1.0f, d));
            mtd[i] = b; msrc[i] = a; md[i] = d;
            atomicAdd(&lbcnt[b >> BSH], 1);
        }
    }
    __syncthreads();
    // scan block-local bucket counts (NB <= 320 <= 512)
    int v = (tid < NB) ? lbcnt[tid] : 0;
    ssc[tid] = v;
    __syncthreads();
    for (int off = 1; off < 512; off <<= 1) {
        int u = (tid >= off) ? ssc[tid - off] : 0;
        __syncthreads();
        ssc[tid] += u;
        __syncthreads();
    }
    if (tid < NB) {
        int ex = ssc[tid] - v;
        lbase[tid] = ex;
        lpos[tid] = ex;
    }
    __syncthreads();
    // place into LDS staging grouped by bucket
    #pragma unroll
    for (int i = 0; i < 8; ++i) {
        if (mtd[i] >= 0) {
            int bin = mtd[i] >> BSH;
            int p = atomicAdd(&lpos[bin], 1);
            std_[p] = mtd[i]; ssrc[p] = msrc[i]; sdv[p] = md[i];
        }
    }
    __syncthreads();
    // reserve global runs: one atomic per (block, bucket)
    for (int b = tid; b < NB; b += 512)
        if (lbcnt[b]) lgst[b] = atomicAdd(&bcur[b], lbcnt[b]);
    __syncthreads();
    // coalesced flush of runs
    for (int j = tid; j < total; j += 512) {
        int bin = std_[j] >> BSH;
        int dest = lbb[bin] + lgst[bin] + (j - lbase[bin]);
        ipair[dest] = make_int2(std_[j], ssrc[j]);
        idv[dest] = sdv[j];
    }
}

// passB: one block per bucket; in-LDS edge hist + scan -> rowp (coalesced)
// and final packed placement flushed coalesced.
__global__ __launch_bounds__(512) void k_passB(
    const int2* __restrict__ ipair, const float* __restrict__ idv,
    const int* __restrict__ bbase, int2* __restrict__ packed,
    int* __restrict__ rowp, int E, int T) {
    __shared__ int2 spk[CAPB];
    __shared__ int hcnt[512], lcur[512], ssc[512];
    int tid = threadIdx.x;
    int b = blockIdx.x;
    int ibeg = bbase[b], iend = bbase[b + 1];
    int nb = iend - ibeg;
    int e0 = b << BSH;
    hcnt[tid] = 0;
    __syncthreads();
    for (int j = ibeg + tid; j < iend; j += 512)
        atomicAdd(&hcnt[ipair[j].x - e0], 1);
    __syncthreads();
    int v = hcnt[tid];
    ssc[tid] = v;
    __syncthreads();
    for (int off = 1; off < 512; off <<= 1) {
        int u = (tid >= off) ? ssc[tid - off] : 0;
        __syncthreads();
        ssc[tid] += u;
        __syncthreads();
    }
    int excl = ssc[tid] - v;
    lcur[tid] = excl;
    int e = e0 + tid;
    if (e < E) rowp[e] = ibeg + excl;
    if (b == 0 && tid == 0) rowp[E] = T;
    __syncthreads();
    bool staged = (nb <= CAPB);
    for (int j = ibeg + tid; j < iend; j += 512) {
        int2 pr = ipair[j];
        int pos = atomicAdd(&lcur[pr.x - e0], 1);
        int2 out = make_int2(pr.y, __float_as_int(idv[j]));
        if (staged) spk[pos] = out;
        else packed[ibeg + pos] = out;
    }
    __syncthreads();
    if (staged)
        for (int j = tid; j < nb; j += 512) packed[ibeg + j] = spk[j];
}

__global__ void k_escatter(const int* __restrict__ gd, const int* __restrict__ erowp,
                           int* __restrict__ cursor, int* __restrict__ eord, int E) {
    int e = blockIdx.x * blockDim.x + threadIdx.x;
    if (e >= E) return;
    int n = gd[e];
    int pos = erowp[n] + atomicAdd(&cursor[n], 1);
    eord[pos] = e;
}

// ---- degree bucket sort of edges (by triplet-segment length) ----
__global__ __launch_bounds__(256) void k_deghist(
    const int* __restrict__ rowp, int* __restrict__ dcnt, int E) {
    __shared__ int h[256];
    int tid = threadIdx.x;
    h[tid] = 0;
    __syncthreads();
    int e = blockIdx.x * 256 + tid;
    if (e < E) {
        int d = rowp[e + 1] - rowp[e];
        if (d > 255) d = 255;
        atomicAdd(&h[d], 1);
    }
    __syncthreads();
    if (h[tid]) atomicAdd(&dcnt[tid], h[tid]);
}

__global__ __launch_bounds__(256) void k_degscatter(
    const int* __restrict__ rowp, const int* __restrict__ doff,
    int* __restrict__ dcur, int* __restrict__ eperm, int E) {
    __shared__ int lcnt[256];
    __shared__ int base[256];
    int tid = threadIdx.x;
    lcnt[tid] = 0;
    __syncthreads();
    int e = blockIdx.x * 256 + tid;
    int d = 0, rk = 0;
    if (e < E) {
        d = rowp[e + 1] - rowp[e];
        if (d > 255) d = 255;
        rk = atomicAdd(&lcnt[d], 1);
    }
    __syncthreads();
    if (lcnt[tid]) base[tid] = atomicAdd(&dcur[tid], lcnt[tid]);
    __syncthreads();
    // DESCENDING degree order (LPT): longest-running waves dispatch first,
    // short waves backfill the tail (R24: 57us -> balances the drain).
    if (e < E) eperm[E - 1 - (doff[d] + base[d] + rk)] = e;
}

// 32x32 tiled transpose + cast: src fp32 [K][Nn] -> dst bf16 [Nn][K].
__global__ __launch_bounds__(256) void k_castT(
    const float* __restrict__ src, bf16_t* __restrict__ dst, int K, int Nn) {
    __shared__ float tile[32][33];
    int k0 = blockIdx.x * 32, n0 = blockIdx.y * 32;
    int tx = threadIdx.x & 31, ty = threadIdx.x >> 5;
    #pragma unroll
    for (int i = 0; i < 4; ++i) {
        int row = ty + i * 8;
        tile[row][tx] = src[(size_t)(k0 + row) * Nn + n0 + tx];
    }
    __syncthreads();
    #pragma unroll
    for (int i = 0; i < 4; ++i) {
        int row = ty + i * 8;
        dst[(size_t)(n0 + row) * K + k0 + tx] = f2bf(tile[tx][row]);
    }
}

// MFMA node_proj: xs = x@Wsrc + bs, xd = x@Wdst + bd (bf16 out, R26).
// R25: Wst/Wdt staged into LDS (32KB each, padded rows).
__global__ __launch_bounds__(256) void k_node_proj(
    const bf16_t* __restrict__ xb,
    const bf16_t* __restrict__ Wst, const float* __restrict__ bs,
    const bf16_t* __restrict__ Wdt, const float* __restrict__ bd,
    bf16_t* __restrict__ xs, bf16_t* __restrict__ xd, int N) {
    __shared__ bf16_t wsl[64 * WPAD];
    __shared__ bf16_t wdl[64 * WPAD];
    int tid = threadIdx.x;
    for (int i = tid; i < 2048; i += 256) {
        int row = i >> 5, inw = i & 31;
        *(uint4*)&wsl[row * WPAD + inw * 8] =
            *(const uint4*)&Wst[(size_t)row * DMODEL + inw * 8];
        *(uint4*)&wdl[row * WPAD + inw * 8] =
            *(const uint4*)&Wdt[(size_t)row * DMODEL + inw * 8];
    }
    __syncthreads();
    int w = tid >> 6, lane = tid & 63;
    int col = lane & 15, quad = lane >> 4;
    int m0 = blockIdx.x * 64 + w * 16;
    f4 as[4] = {{0.f,0.f,0.f,0.f},{0.f,0.f,0.f,0.f},
                {0.f,0.f,0.f,0.f},{0.f,0.f,0.f,0.f}};
    f4 ad[4] = {{0.f,0.f,0.f,0.f},{0.f,0.f,0.f,0.f},
                {0.f,0.f,0.f,0.f},{0.f,0.f,0.f,0.f}};
    #pragma unroll
    for (int k0 = 0; k0 < DMODEL; k0 += 32) {
        s8v a = *(const s8v*)&xb[(size_t)(m0 + col) * DMODEL + k0 + quad * 8];
        #pragma unroll
        for (int t = 0; t < 4; ++t) {
            s8v b1v = *(const s8v*)&wsl[(t * 16 + col) * WPAD + k0 + quad * 8];
            as[t] = __builtin_amdgcn_mfma_f32_16x16x32_bf16(a, b1v, as[t], 0, 0, 0);
            s8v b2v = *(const s8v*)&wdl[(t * 16 + col) * WPAD + k0 + quad * 8];
            ad[t] = __builtin_amdgcn_mfma_f32_16x16x32_bf16(a, b2v, ad[t], 0, 0, 0);
        }
    }
    #pragma unroll
    for (int t = 0; t < 4; ++t) {
        int c = t * 16 + col;
        float bsv = bs[c], bdv = bd[c];
        #pragma unroll
        for (int r = 0; r < 4; ++r) {
            int m = m0 + quad * 4 + r;
            if (m < N) {
                xs[(size_t)m * DM + c] = f2bf(as[t][r] + bsv);
                xd[(size_t)m * DM + c] = f2bf(ad[t][r] + bdv);
            }
        }
    }
}

// MFMA k_xij: xij[e][c] = (RBF(bl[e]) @ Wedge)[c] + xs[gs[e]][c] + xd[gd[e]][c] + be[c]
// R25: Wedgt staged into LDS. R26: xs/xd are bf16 (halves the 82MB gather).
__global__ __launch_bounds__(256) void k_xij(
    const float* __restrict__ bl, const bf16_t* __restrict__ Wedgt,
    const float* __restrict__ be,
    const bf16_t* __restrict__ xs, const bf16_t* __restrict__ xd,
    const int* __restrict__ gs, const int* __restrict__ gd,
    bf16_t* __restrict__ xij, int E) {
    __shared__ bf16_t wel[64 * WPAD];
    int tid = threadIdx.x;
    for (int i = tid; i < 2048; i += 256) {
        int row = i >> 5, inw = i & 31;
        *(uint4*)&wel[row * WPAD + inw * 8] =
            *(const uint4*)&Wedgt[(size_t)row * DMODEL + inw * 8];
    }
    __syncthreads();
    int w = tid >> 6, lane = tid & 63;
    int col = lane & 15, quad = lane >> 4;
    int m0 = blockIdx.x * 64 + w * 16;
    const float step = 8.0f / 255.0f;
    const float gamma = (255.0f / 8.0f) * (255.0f / 8.0f);
    int me = m0 + col;
    float blv = (me < E) ? bl[me] : 0.f;
    f4 acc[4] = {{0.f,0.f,0.f,0.f},{0.f,0.f,0.f,0.f},
                 {0.f,0.f,0.f,0.f},{0.f,0.f,0.f,0.f}};
    #pragma unroll
    for (int k0 = 0; k0 < DMODEL; k0 += 32) {
        s8v a;
        #pragma unroll
        for (int j = 0; j < 8; ++j) {
            float c = (float)(k0 + quad * 8 + j) * step;
            float dd = blv - c;
            a[j] = (short)f2bf(__expf(-gamma * dd * dd));
        }
        #pragma unroll
        for (int t = 0; t < 4; ++t) {
            s8v b = *(const s8v*)&wel[(t * 16 + col) * WPAD + k0 + quad * 8];
            acc[t] = __builtin_amdgcn_mfma_f32_16x16x32_bf16(a, b, acc[t], 0, 0, 0);
        }
    }
    #pragma unroll
    for (int r = 0; r < 4; ++r) {
        int e = m0 + quad * 4 + r;
        if (e >= E) continue;
        int s = gs[e], d2 = gd[e];
        #pragma unroll
        for (int t = 0; t < 4; ++t) {
            int c = t * 16 + col;
            float v = acc[t][r] + bf2f(xs[(size_t)s * DM + c])
                    + bf2f(xd[(size_t)d2 * DM + c]) + be[c];
            xij[(size_t)e * DM + c] = f2bf(v);
        }
    }
}

// Fused logit+softmax+attend: 4 lanes per edge (degree-sorted via eperm),
// 16 channels per lane. Chebyshev T_k(d) for cos(k*theta); 2-shfl reduce.
// R26: heavy (high-degree) waves run at s_setprio(1) so they stream at full
// issue rate while the flood of light waves yields -- they set the makespan.
__global__ __launch_bounds__(256) void k_edge_attn(
    const bf16_t* __restrict__ xij, const int2* __restrict__ packed,
    const int* __restrict__ rowp, const float* __restrict__ attn_l,
    const int* __restrict__ eperm, bf16_t* __restrict__ msg, int E) {
    int gtid = blockIdx.x * 256 + threadIdx.x;
    int ei = gtid >> 2;
    if (ei >= E) return;
    int q = gtid & 3;                  // channel block [16q, 16q+16)
    int e = eperm[ei];
    int beg = rowp[e], end = rowp[e + 1];

    float av[16];
    #pragma unroll
    for (int c = 0; c < 16; ++c) av[c] = attn_l[q * 16 + c];

    // my 16 channels of this edge's xij row (32B)
    uint4 xe0, xe1;
    {
        const uint4* xer = (const uint4*)&xij[(size_t)e * DM + q * 16];
        xe0 = xer[0]; xe1 = xer[1];
    }
    float acc[16];
    #pragma unroll
    for (int c = 0; c < 16; ++c) acc[c] = 0.f;
    float den = 0.f;

    // degree is wave-uniform (degree-sorted); boost heavy waves
    int degw = __builtin_amdgcn_readfirstlane(end - beg);
    if (degw > 9) __builtin_amdgcn_s_setprio(1);

    if (beg < end) {
        // depth-1 pipeline priming
        int2 pk0 = packed[beg];
        int2 pk1 = (beg + 1 < end) ? packed[beg + 1] : pk0;
        const uint4* s0 = (const uint4*)&xij[(size_t)pk0.x * DM + q * 16];
        uint4 nsa = s0[0], nsb = s0[1];
        for (int p = beg; p < end; ++p) {
            float d = __int_as_float(pk0.y);
            uint4 xa = nsa, xb = nsb;
            if (p + 1 < end) {
                const uint4* sn = (const uint4*)&xij[(size_t)pk1.x * DM + q * 16];
                nsa = sn[0]; nsb = sn[1];
                pk0 = pk1;
                if (p + 2 < end) pk1 = packed[p + 2];
            }
            float d2 = d + d;
            // ladder: seeds T_{16q}, T_{16q+1} via 2TmTn = T_{m+n} + T_{|m-n|}
            float t2  = fmaf(d2, d, -1.f);
            float t3  = fmaf(d2, t2, -d);
            float t4  = fmaf(t2 + t2, t2, -1.f);
            float t7  = fmaf(t4 + t4, t3, -d);
            float t8  = fmaf(t4 + t4, t4, -1.f);
            float t15 = fmaf(t8 + t8, t7, -d);
            float t16 = fmaf(t8 + t8, t8, -1.f);
            float t17 = fmaf(t16 + t16, d, -t15);
            float t31 = fmaf(t16 + t16, t15, -d);
            float t32 = fmaf(t16 + t16, t16, -1.f);
            float t33 = fmaf(t32 + t32, d, -t31);
            float t48 = fmaf(t32 + t32, t16, -t16);
            float t49 = fmaf(t32 + t32, t17, -t15);
            float za, zb;                        // T_{16q}, T_{16q+1}
            if (q == 0)      { za = 1.f;  zb = d;   }
            else if (q == 1) { za = t16;  zb = t17; }
            else if (q == 2) { za = t32;  zb = t33; }
            else             { za = t48;  zb = t49; }
            float logit = 0.f;
            #define CH2(uw, ew, c)                                            \
            {                                                                 \
                float u0 = za + bf_lo(uw) + bf_lo(ew);                        \
                float zn = fmaf(d2, zb, -za); za = zb; zb = zn;               \
                float u1 = za + bf_hi(uw) + bf_hi(ew);                        \
                zn = fmaf(d2, zb, -za); za = zb; zb = zn;                     \
                logit = fmaf(silu_f(u0), av[c], logit);                       \
                logit = fmaf(silu_f(u1), av[c + 1], logit);                   \
            }
            CH2(xa.x, xe0.x, 0);
            CH2(xa.y, xe0.y, 2);
            CH2(xa.z, xe0.z, 4);
            CH2(xa.w, xe0.w, 6);
            CH2(xb.x, xe1.x, 8);
            CH2(xb.y, xe1.y, 10);
            CH2(xb.z, xe1.z, 12);
            CH2(xb.w, xe1.w, 14);
            #undef CH2
            // sum logit across the 4-lane group
            logit += __shfl_xor(logit, 1, 64);
            logit += __shfl_xor(logit, 2, 64);
            float wg = __expf(logit);
            den += wg;
            acc[0]  = fmaf(wg, bf_lo(xa.x), acc[0]);
            acc[1]  = fmaf(wg, bf_hi(xa.x), acc[1]);
            acc[2]  = fmaf(wg, bf_lo(xa.y), acc[2]);
            acc[3]  = fmaf(wg, bf_hi(xa.y), acc[3]);
            acc[4]  = fmaf(wg, bf_lo(xa.z), acc[4]);
            acc[5]  = fmaf(wg, bf_hi(xa.z), acc[5]);
            acc[6]  = fmaf(wg, bf_lo(xa.w), acc[6]);
            acc[7]  = fmaf(wg, bf_hi(xa.w), acc[7]);
            acc[8]  = fmaf(wg, bf_lo(xb.x), acc[8]);
            acc[9]  = fmaf(wg, bf_hi(xb.x), acc[9]);
            acc[10] = fmaf(wg, bf_lo(xb.y), acc[10]);
            acc[11] = fmaf(wg, bf_hi(xb.y), acc[11]);
            acc[12] = fmaf(wg, bf_lo(xb.z), acc[12]);
            acc[13] = fmaf(wg, bf_hi(xb.z), acc[13]);
            acc[14] = fmaf(wg, bf_lo(xb.w), acc[14]);
            acc[15] = fmaf(wg, bf_hi(xb.w), acc[15]);
        }
    }
    __builtin_amdgcn_s_setprio(0);
    float inv = (den > 0.f) ? 1.f / den : 0.f;
    uint4 o0, o1;
    o0.x = (unsigned int)f2bf(acc[0] * inv)  | ((unsigned int)f2bf(acc[1] * inv) << 16);
    o0.y = (unsigned int)f2bf(acc[2] * inv)  | ((unsigned int)f2bf(acc[3] * inv) << 16);
    o0.z = (unsigned int)f2bf(acc[4] * inv)  | ((unsigned int)f2bf(acc[5] * inv) << 16);
    o0.w = (unsigned int)f2bf(acc[6] * inv)  | ((unsigned int)f2bf(acc[7] * inv) << 16);
    o1.x = (unsigned int)f2bf(acc[8] * inv)  | ((unsigned int)f2bf(acc[9] * inv) << 16);
    o1.y = (unsigned int)f2bf(acc[10] * inv) | ((unsigned int)f2bf(acc[11] * inv) << 16);
    o1.z = (unsigned int)f2bf(acc[12] * inv) | ((unsigned int)f2bf(acc[13] * inv) << 16);
    o1.w = (unsigned int)f2bf(acc[14] * inv) | ((unsigned int)f2bf(acc[15] * inv) << 16);
    uint4* op = (uint4*)&msg[(size_t)e * DM + q * 16];
    op[0] = o0;
    op[1] = o1;
}

// thread per (node, channel-quad): sum bf16 msg -> bf16 ft.
__global__ __launch_bounds__(256) void k_aggregate(
    const bf16_t* __restrict__ msg, const int* __restrict__ erowp,
    const int* __restrict__ eord, bf16_t* __restrict__ ft, int N) {
    int gtid = blockIdx.x * 256 + threadIdx.x;
    int n = gtid >> 4;
    if (n >= N) return;
    int quad = gtid & 15;
    int beg = erowp[n], end = erowp[n + 1];
    float a0 = 0.f, a1 = 0.f, a2 = 0.f, a3 = 0.f;
    for (int j = beg; j < end; ++j) {
        uint2 uv = *(const uint2*)&msg[(size_t)eord[j] * DM + quad * 4];
        a0 += bf_lo(uv.x); a1 += bf_hi(uv.x);
        a2 += bf_lo(uv.y); a3 += bf_hi(uv.y);
    }
    ushort4 o = {f2bf(a0), f2bf(a1), f2bf(a2), f2bf(a3)};
    *(ushort4*)&ft[(size_t)n * DM + quad * 4] = o;
}

// Fused FFN: x = silu(ft@W1 + b1) @ W2 + b2; h never leaves the CU.
// Grid (N/64, 4): blockIdx.y owns 64 output cols. Block = 64 rows, 4 waves.
// Weights stream through double-buffered LDS (pad-72 rows). R23.
__global__ __launch_bounds__(256) void k_ffn_fused(
    const bf16_t* __restrict__ ft, const bf16_t* __restrict__ W1t,
    const float* __restrict__ b1, const bf16_t* __restrict__ W2t,
    const float* __restrict__ b2, bf16_t* __restrict__ x, int N) {
    __shared__ bf16_t w1s[2][64 * 72];
    __shared__ bf16_t w2s[2][64 * 72];
    __shared__ bf16_t hld[4][16 * 72];
    __shared__ float b1s[HDIM];
    int tid = threadIdx.x;
    int w = tid >> 6, lane = tid & 63;
    int col = lane & 15, quad = lane >> 4;
    int m0 = blockIdx.x * 64 + w * 16;
    int c0 = blockIdx.y * 64;                 // this block's output columns
    bf16_t* myl = hld[w];

    // bias table -> LDS once
    #pragma unroll
    for (int j = 0; j < 4; ++j) b1s[tid + j * 256] = b1[tid + j * 256];

    // ft A-fragments for this wave's 16 rows (k = 0..63), held all kernel
    s8v fa0 = *(const s8v*)&ft[(size_t)(m0 + col) * DM + quad * 8];
    s8v fa1 = *(const s8v*)&ft[(size_t)(m0 + col) * DM + 32 + quad * 8];

    // staging geometry: piece idx = r*256+tid -> row = idx>>3, kblk = idx&7
    int srow0 = tid >> 3;            // r=0 rows 0..31
    int srow1 = 32 + srow0;          // r=1 rows 32..63
    int skb = tid & 7;

    f4 acc[4] = {{0.f,0.f,0.f,0.f},{0.f,0.f,0.f,0.f},
                 {0.f,0.f,0.f,0.f},{0.f,0.f,0.f,0.f}};

    // ---- prologue: stage chunk 0 into buffer 0 ----
    {
        uint4 a0 = *(const uint4*)&W1t[(size_t)srow0 * DM + skb * 8];
        uint4 a1 = *(const uint4*)&W1t[(size_t)srow1 * DM + skb * 8];
        uint4 c0v = *(const uint4*)&W2t[(size_t)(c0 + srow0) * HDIM + skb * 8];
        uint4 c1v = *(const uint4*)&W2t[(size_t)(c0 + srow1) * HDIM + skb * 8];
        *(uint4*)&w1s[0][srow0 * 72 + skb * 8] = a0;
        *(uint4*)&w1s[0][srow1 * 72 + skb * 8] = a1;
        *(uint4*)&w2s[0][srow0 * 72 + skb * 8] = c0v;
        *(uint4*)&w2s[0][srow1 * 72 + skb * 8] = c1v;
    }
    __syncthreads();

    #pragma unroll 1
    for (int kc = 0; kc < 16; ++kc) {         // h-col chunks of 64
        int cb = kc & 1, nb = cb ^ 1;
        int ch0 = kc * 64;
        int chn = (kc < 15) ? ch0 + 64 : ch0;  // clamped (load redundant on last)
        // issue next-chunk global loads into regs (no use until after barrier)
        uint4 na0 = *(const uint4*)&W1t[(size_t)(chn + srow0) * DM + skb * 8];
        uint4 na1 = *(const uint4*)&W1t[(size_t)(chn + srow1) * DM + skb * 8];
        uint4 nc0 = *(const uint4*)&W2t[(size_t)(c0 + srow0) * HDIM + chn + skb * 8];
        uint4 nc1 = *(const uint4*)&W2t[(size_t)(c0 + srow1) * HDIM + chn + skb * 8];
        // ---- compute current chunk entirely from LDS ----
        #pragma unroll
        for (int th = 0; th < 4; ++th) {
            s8v wb0 = *(const s8v*)&w1s[cb][(th * 16 + col) * 72 + quad * 8];
            s8v wb1 = *(const s8v*)&w1s[cb][(th * 16 + col) * 72 + 32 + quad * 8];
            f4 hv = {0.f, 0.f, 0.f, 0.f};
            hv = __builtin_amdgcn_mfma_f32_16x16x32_bf16(fa0, wb0, hv, 0, 0, 0);
            hv = __builtin_amdgcn_mfma_f32_16x16x32_bf16(fa1, wb1, hv, 0, 0, 0);
            float bb = b1s[ch0 + th * 16 + col];
            #pragma unroll
            for (int r = 0; r < 4; ++r)
                myl[(quad * 4 + r) * 72 + th * 16 + col] =
                    f2bf(silu_f(hv[r] + bb));
        }
        // A-fragments of h (wave-private tile; compiler emits lgkmcnt waits)
        s8v ha0 = *(const s8v*)&myl[col * 72 + quad * 8];
        s8v ha1 = *(const s8v*)&myl[col * 72 + 32 + quad * 8];
        #pragma unroll
        for (int t2 = 0; t2 < 4; ++t2) {
            s8v vb0 = *(const s8v*)&w2s[cb][(t2 * 16 + col) * 72 + quad * 8];
            s8v vb1 = *(const s8v*)&w2s[cb][(t2 * 16 + col) * 72 + 32 + quad * 8];
            acc[t2] = __builtin_amdgcn_mfma_f32_16x16x32_bf16(ha0, vb0, acc[t2], 0, 0, 0);
            acc[t2] = __builtin_amdgcn_mfma_f32_16x16x32_bf16(ha1, vb1, acc[t2], 0, 0, 0);
        }
        __syncthreads();                       // all waves done reading buf nb
        if (kc < 15) {
            *(uint4*)&w1s[nb][srow0 * 72 + skb * 8] = na0;
            *(uint4*)&w1s[nb][srow1 * 72 + skb * 8] = na1;
            *(uint4*)&w2s[nb][srow0 * 72 + skb * 8] = nc0;
            *(uint4*)&w2s[nb][srow1 * 72 + skb * 8] = nc1;
        }
        __syncthreads();                       // buf nb ready for next iter
    }
    #pragma unroll
    for (int t2 = 0; t2 < 4; ++t2) {
        int c = c0 + t2 * 16 + col;
        float bb = b2[c];
        #pragma unroll
        for (int r = 0; r < 4; ++r) {
            int m = m0 + quad * 4 + r;
            if (m < N) x[(size_t)m * DMODEL + c] = f2bf(acc[t2][r] + bb);
        }
    }
}

// grid-stride dot over bf16 x, one atomic per block.
__global__ __launch_bounds__(256) void k_out_reduce(
    const bf16_t* __restrict__ x, const float* __restrict__ Wfc,
    float* __restrict__ acc, int NT) {
    __shared__ float sm[4];
    int tid = threadIdx.x;
    float v = 0.f;
    int np = NT / 2;
    const unsigned int* xp = (const unsigned int*)x;
    for (int i = blockIdx.x * blockDim.x + tid; i < np; i += gridDim.x * blockDim.x) {
        unsigned int u = xp[i];
        int c = (2 * i) & (DMODEL - 1);
        v = fmaf(bf_lo(u), Wfc[c], v);
        v = fmaf(bf_hi(u), Wfc[c + 1], v);
    }
    for (int off = 32; off > 0; off >>= 1) v += __shfl_xor(v, off, 64);
    if ((tid & 63) == 0) sm[tid >> 6] = v;
    __syncthreads();
    if (tid == 0) {
        float s = sm[0] + sm[1] + sm[2] + sm[3];
        atomicAdd(acc, s);
    }
}

__global__ void k_out_final(const float* __restrict__ acc, const float* __restrict__ bfc,
                            float* __restrict__ out, float invN) {
    out[0] = acc[0] * invN + bfc[0];
}

extern "C" void kernel_launch(void* const* d_in, const int* in_sizes, int n_in,
                              void* d_out, int out_size, void* d_ws, size_t ws_size,
                              hipStream_t stream) {
    const int*   an    = (const int*)d_in[0];
    const int*   gs    = (const int*)d_in[1];
    const int*   gd    = (const int*)d_in[2];
    const int*   ts    = (const int*)d_in[3];
    const int*   td    = (const int*)d_in[4];
    const float* r     = (const float*)d_in[5];
    const float* emb   = (const float*)d_in[6];
    const float* Wsrc  = (const float*)d_in[7];
    const float* bsrc  = (const float*)d_in[8];
    const float* Wdst  = (const float*)d_in[9];
    const float* bdst  = (const float*)d_in[10];
    const float* Wedge = (const float*)d_in[11];
    const float* bedge = (const float*)d_in[12];
    const float* attn  = (const float*)d_in[13];
    const float* W1    = (const float*)d_in[14];
    const float* b1    = (const float*)d_in[15];
    const float* W2    = (const float*)d_in[16];
    const float* b2    = (const float*)d_in[17];
    const float* Wfc   = (const float*)d_in[18];
    const float* bfc   = (const float*)d_in[19];

    const int N = in_sizes[0];
    const int E = in_sizes[1];
    const int T = in_sizes[3];
    const int NB = (E + 511) >> BSH;          // triplet-sort buckets

    char* w = (char*)d_ws;
    size_t off = 0;
    auto alloc = [&](size_t bytes) {
        void* p = w + off;
        off += (bytes + 255) & ~(size_t)255;
        return p;
    };
    bf16_t* xb     = (bf16_t*)alloc((size_t)(N + 64) * DMODEL * 2);
    float*  rn     = (float*) alloc((size_t)E * 3 * 4);
    float*  bl     = (float*) alloc(((size_t)E + 64) * 4);
    int*    rowp   = (int*)   alloc(((size_t)E + 1) * 4);
    int*    bsum   = (int*)   alloc(4096);
    int2*   packed = (int2*)  alloc((size_t)T * 8);
    int2*   ipair  = (int2*)  alloc((size_t)T * 8);
    float*  idv    = (float*) alloc((size_t)T * 4);
    int*    gbcnt  = (int*)   alloc(NBMAX * 4);
    int*    bbase  = (int*)   alloc((NBMAX + 1) * 4);
    int*    bcur   = (int*)   alloc(NBMAX * 4);
    int*    ecnt   = (int*)   alloc((size_t)N * 4);
    int*    erowp  = (int*)   alloc(((size_t)N + 1) * 4);
    int*    eord   = (int*)   alloc((size_t)E * 4);
    int*    eperm  = (int*)   alloc((size_t)E * 4);
    int*    dcnt   = (int*)   alloc(1024);
    int*    dcur   = (int*)   alloc(1024);
    bf16_t* xs     = (bf16_t*)alloc((size_t)N * DM * 2);
    bf16_t* xd     = (bf16_t*)alloc((size_t)N * DM * 2);
    bf16_t* xij    = (bf16_t*)alloc((size_t)E * DM * 2);
    bf16_t* msg    = (bf16_t*)alloc((size_t)E * DM * 2);
    bf16_t* ft     = (bf16_t*)alloc((size_t)(N + 64) * DM * 2);
    bf16_t* W1t    = (bf16_t*)alloc((size_t)3 * HDIM * DM * 2);
    bf16_t* W2t    = (bf16_t*)alloc((size_t)3 * DMODEL * HDIM * 2);
    bf16_t* Wedgt  = (bf16_t*)alloc((size_t)3 * DM * DMODEL * 2);
    bf16_t* Wst    = (bf16_t*)alloc((size_t)3 * DM * DMODEL * 2);
    bf16_t* Wdt    = (bf16_t*)alloc((size_t)3 * DM * DMODEL * 2);
    float*  accs   = (float*) alloc(64);
    (void)ws_size; (void)n_in; (void)out_size;

    const int nbScanN = (N + 255) / 256;
    const int nbT = (T + 4095) / 4096;

    // ---- setup (layer-invariant) ----
    k_embed<<<N, 256, 0, stream>>>(an, emb, xb);
    k_edge_geom<<<(E + 255) / 256, 256, 0, stream>>>(r, bl, rn, E);
    for (int l = 0; l < 3; ++l) {
        k_castT<<<dim3(DM / 32, HDIM / 32), 256, 0, stream>>>(
            W1 + (size_t)l * DM * HDIM, W1t + (size_t)l * HDIM * DM, DM, HDIM);
        k_castT<<<dim3(HDIM / 32, DMODEL / 32), 256, 0, stream>>>(
            W2 + (size_t)l * HDIM * DMODEL, W2t + (size_t)l * DMODEL * HDIM,
            HDIM, DMODEL);
        k_castT<<<dim3(DMODEL / 32, DM / 32), 256, 0, stream>>>(
            Wedge + (size_t)l * DMODEL * DM, Wedgt + (size_t)l * DM * DMODEL,
            DMODEL, DM);
        k_castT<<<dim3(DMODEL / 32, DM / 32), 256, 0, stream>>>(
            Wsrc + (size_t)l * DMODEL * DM, Wst + (size_t)l * DM * DMODEL,
            DMODEL, DM);
        k_castT<<<dim3(DMODEL / 32, DM / 32), 256, 0, stream>>>(
            Wdst + (size_t)l * DMODEL * DM, Wdt + (size_t)l * DM * DMODEL,
            DMODEL, DM);
    }
    // triplet CSR by t_dst: two-level bucket sort, all writes coalesced
    hipMemsetAsync(gbcnt, 0, NBMAX * 4, stream);
    hipMemsetAsync(bcur, 0, NBMAX * 4, stream);
    k_bhist<<<nbT, 512, 0, stream>>>(td, gbcnt, T, NB);
    k_bscan<<<1, 512, 0, stream>>>(gbcnt, bbase, NB, T);
    k_passA<<<nbT, 512, 0, stream>>>(ts, td, rn, bbase, bcur, ipair, idv, T, NB);
    k_passB<<<NB, 512, 0, stream>>>(ipair, idv, bbase, packed, rowp, E, T);
    // degree-sorted edge permutation (for k_edge_attn load balance)
    hipMemsetAsync(dcnt, 0, 1024, stream);
    hipMemsetAsync(dcur, 0, 1024, stream);
    k_deghist<<<(E + 255) / 256, 256, 0, stream>>>(rowp, dcnt, E);
    k_scan_mid<<<1, 1024, 0, stream>>>(dcnt, 256);
    k_degscatter<<<(E + 255) / 256, 256, 0, stream>>>(rowp, dcnt, dcur, eperm, E);
    // edge CSR by gd
    hipMemsetAsync(ecnt, 0, (size_t)N * 4, stream);
    k_hist<<<(E + 255) / 256, 256, 0, stream>>>(gd, ecnt, E);
    k_scan_part<<<nbScanN, 256, 0, stream>>>(ecnt, bsum, N);
    k_scan_mid<<<1, 1024, 0, stream>>>(bsum, nbScanN);
    k_scan_final<<<nbScanN, 256, 0, stream>>>(ecnt, bsum, erowp, N, E);
    hipMemsetAsync(ecnt, 0, (size_t)N * 4, stream);
    k_escatter<<<(E + 255) / 256, 256, 0, stream>>>(gd, erowp, ecnt, eord, E);

    // ---- layers ----
    for (int l = 0; l < 3; ++l) {
        k_node_proj<<<(N + 63) / 64, 256, 0, stream>>>(
            xb, Wst + (size_t)l * DM * DMODEL, bsrc + l * DM,
            Wdt + (size_t)l * DM * DMODEL, bdst + l * DM, xs, xd, N);
        k_xij<<<(E + 63) / 64, 256, 0, stream>>>(
            bl, Wedgt + (size_t)l * DM * DMODEL, bedge + l * DM,
            xs, xd, gs, gd, xij, E);
        k_edge_attn<<<(E * 4 + 255) / 256, 256, 0, stream>>>(
            xij, packed, rowp, attn + l * DM, eperm, msg, E);
        k_aggregate<<<(N * 16 + 255) / 256, 256, 0, stream>>>(
            msg, erowp, eord, ft, N);
        k_ffn_fused<<<dim3((N + 63) / 64, 4), 256, 0, stream>>>(
            ft, W1t + (size_t)l * HDIM * DM, b1 + l * HDIM,
            W2t + (size_t)l * DMODEL * HDIM, b2 + l * DMODEL, xb, N);
    }

    // ---- output head ----
    hipMemsetAsync(accs, 0, 4, stream);
    k_out_reduce<<<120, 256, 0, stream>>>(xb, Wfc, accs, N * DMODEL);
    k_out_final<<<1, 1, 0, stream>>>(accs, bfc, (float*)d_out, 1.0f / (float)N);
}

// Round 13
// 596.052 us; speedup vs baseline: 1.5729x; 1.0658x over previous
//
#include <hip/hip_runtime.h>
#include <math.h>

// M3GNet-like GNN forward. N=10000 nodes, E=160000 edges, T=1200000 triplets,
// D=256, DM=64, H=1024, L=3, output = scalar mean energy (fp32).
//
// R27 (resubmit; previous round was an infra failure "container failed
// twice", not a kernel result): dispatch-count reduction + CSR-ordered msg.
//  Audit: measurable kernels sum ~350us of the 635 total -> ~250-300us is
//  inter-dispatch overhead on the serial stream (~45 dispatches). Changes
//  (all bit-identical):
//   - k_castT batched over the 3 layers via blockIdx.z (15 -> 5 dispatches)
//   - merged memsets (gbcnt+bcur contiguous, dcnt+dcur contiguous; second
//     ecnt clear folded into k_scan_final) (6 -> 3)
//   - k_edge_attn writes msg at epos[e] (CSR slot, from k_escatter) so
//     k_aggregate reads msg SEQUENTIALLY (was E x 128B random via eord).
//  edge_attn itself is at its floor (R26: setprio null; VALU ~33us ||
//  random-gather ~38us overlap to 46us) -- left unchanged.

#define DM 64
#define DMODEL 256
#define HDIM 1024
#define WPAD 264

#define BSH 9            // log2(edges per bucket)
#define NBMAX 320        // max buckets (E <= 163840)
#define CAPB 4608        // passB LDS staging capacity (bucket ~3840+-62)

typedef unsigned short bf16_t;
typedef __attribute__((ext_vector_type(8))) short s8v;    // 8 bf16 (4 VGPRs)
typedef __attribute__((ext_vector_type(4))) float f4;     // MFMA acc

__device__ __forceinline__ bf16_t f2bf(float f) {
    unsigned int u = __float_as_uint(f);
    return (bf16_t)((u + 0x7FFFu + ((u >> 16) & 1u)) >> 16);   // RNE
}
__device__ __forceinline__ float bf_lo(unsigned int u) {
    return __uint_as_float(u << 16);
}
__device__ __forceinline__ float bf_hi(unsigned int u) {
    return __uint_as_float(u & 0xFFFF0000u);
}
__device__ __forceinline__ float bf2f(bf16_t v) {
    return __uint_as_float((unsigned int)v << 16);
}
__device__ __forceinline__ float silu_f(float u) {
    return u * __builtin_amdgcn_rcpf(1.f + __expf(-u));
}

__global__ void k_embed(const int* __restrict__ an, const float* __restrict__ emb,
                        bf16_t* __restrict__ x) {
    int n = blockIdx.x;
    int d = threadIdx.x;
    x[n * DMODEL + d] = f2bf(emb[an[n] * DMODEL + d]);
}

__global__ void k_edge_geom(const float* __restrict__ r, float* __restrict__ bl,
                            float* __restrict__ rn, int E) {
    int e = blockIdx.x * blockDim.x + threadIdx.x;
    if (e >= E) return;
    float a = r[e * 3 + 0], b = r[e * 3 + 1], c = r[e * 3 + 2];
    float l = sqrtf(a * a + b * b + c * c);
    bl[e] = l;
    float inv = 1.0f / l;
    rn[e * 3 + 0] = a * inv;
    rn[e * 3 + 1] = b * inv;
    rn[e * 3 + 2] = c * inv;
}

__global__ void k_hist(const int* __restrict__ idx, int* __restrict__ cnt, int M) {
    int t = blockIdx.x * blockDim.x + threadIdx.x;
    if (t < M) atomicAdd(&cnt[idx[t]], 1);
}

// ---- 3-phase exclusive scan (used for edge-CSR over N) ----
__global__ __launch_bounds__(256) void k_scan_part(
    const int* __restrict__ cnt, int* __restrict__ bsum, int M) {
    __shared__ int sm[4];
    int tid = threadIdx.x;
    int i = blockIdx.x * 256 + tid;
    int v = (i < M) ? cnt[i] : 0;
    for (int off = 32; off > 0; off >>= 1) v += __shfl_xor(v, off, 64);
    if ((tid & 63) == 0) sm[tid >> 6] = v;
    __syncthreads();
    if (tid == 0) bsum[blockIdx.x] = sm[0] + sm[1] + sm[2] + sm[3];
}

__global__ __launch_bounds__(1024) void k_scan_mid(int* __restrict__ bsum, int nb) {
    __shared__ int sm[1024];
    int tid = threadIdx.x;
    int v = (tid < nb) ? bsum[tid] : 0;
    sm[tid] = v;
    __syncthreads();
    for (int off = 1; off < 1024; off <<= 1) {
        int u = (tid >= off) ? sm[tid - off] : 0;
        __syncthreads();
        sm[tid] += u;
        __syncthreads();
    }
    if (tid < nb) bsum[tid] = sm[tid] - v;
}

// also zeroes cnt after reading (folds the post-hist memset dispatch)
__global__ __launch_bounds__(256) void k_scan_final(
    int* __restrict__ cnt, const int* __restrict__ bsum,
    int* __restrict__ rowp, int M, int total) {
    __shared__ int sm[256];
    int tid = threadIdx.x;
    int i = blockIdx.x * 256 + tid;
    int v = (i < M) ? cnt[i] : 0;
    sm[tid] = v;
    __syncthreads();
    for (int off = 1; off < 256; off <<= 1) {
        int u = (tid >= off) ? sm[tid - off] : 0;
        __syncthreads();
        sm[tid] += u;
        __syncthreads();
    }
    if (i < M) {
        rowp[i] = bsum[blockIdx.x] + sm[tid] - v;
        cnt[i] = 0;
    }
    if (i == 0) rowp[M] = total;
}

// ---- two-level bucket sort of triplets by t_dst ----
// bucket b holds edges [b*512, b*512+512)

__global__ __launch_bounds__(512) void k_bhist(
    const int* __restrict__ td, int* __restrict__ gbcnt, int T, int NB) {
    __shared__ int h[NBMAX];
    int tid = threadIdx.x;
    for (int i = tid; i < NBMAX; i += 512) h[i] = 0;
    __syncthreads();
    int t0 = blockIdx.x * 4096;
    #pragma unroll
    for (int i = 0; i < 8; ++i) {
        int t = t0 + tid + i * 512;
        if (t < T) atomicAdd(&h[td[t] >> BSH], 1);
    }
    __syncthreads();
    for (int b = tid; b < NB; b += 512)
        if (h[b]) atomicAdd(&gbcnt[b], h[b]);
}

__global__ __launch_bounds__(512) void k_bscan(
    const int* __restrict__ gbcnt, int* __restrict__ bbase, int NB, int total) {
    __shared__ int sm[512];
    int tid = threadIdx.x;
    int v = (tid < NB) ? gbcnt[tid] : 0;
    sm[tid] = v;
    __syncthreads();
    for (int off = 1; off < 512; off <<= 1) {
        int u = (tid >= off) ? sm[tid - off] : 0;
        __syncthreads();
        sm[tid] += u;
        __syncthreads();
    }
    if (tid < NB) bbase[tid] = sm[tid] - v;
    if (tid == 0) bbase[NB] = total;
}

// passA: bin 4096 triplets into LDS by bucket, flush runs coalesced.
__global__ __launch_bounds__(512) void k_passA(
    const int* __restrict__ ts, const int* __restrict__ td,
    const float* __restrict__ rn, const int* __restrict__ bbase,
    int* __restrict__ bcur, int2* __restrict__ ipair, float* __restrict__ idv,
    int T, int NB) {
    __shared__ int   std_[4096];
    __shared__ int   ssrc[4096];
    __shared__ float sdv[4096];
    __shared__ int lbcnt[NBMAX], lbase[NBMAX], lpos[NBMAX], lgst[NBMAX],
                   lbb[NBMAX];
    __shared__ int ssc[512];
    int tid = threadIdx.x;
    int t0 = blockIdx.x * 4096;
    int total = min(4096, T - t0);
    for (int i = tid; i < NBMAX; i += 512) lbcnt[i] = 0;
    for (int i = tid; i < NB; i += 512) lbb[i] = bbase[i];
    __syncthreads();
    int   mtd[8], msrc[8];
    float md[8];
    #pragma unroll
    for (int i = 0; i < 8; ++i) {
        int idx = tid + i * 512;
        mtd[i] = -1;
        if (idx < total) {
            int t = t0 + idx;
            int a = ts[t], b = td[t];
            float d = rn[a * 3 + 0] * rn[b * 3 + 0]
                    + rn[a * 3 + 1] * rn[b * 3 + 1]
                    + rn[a * 3 + 2] * rn[b * 3 + 2];
            d = fminf(1.0f, fmaxf(-1.0f, d));
            mtd[i] = b; msrc[i] = a; md[i] = d;
            atomicAdd(&lbcnt[b >> BSH], 1);
        }
    }
    __syncthreads();
    // scan block-local bucket counts (NB <= 320 <= 512)
    int v = (tid < NB) ? lbcnt[tid] : 0;
    ssc[tid] = v;
    __syncthreads();
    for (int off = 1; off < 512; off <<= 1) {
        int u = (tid >= off) ? ssc[tid - off] : 0;
        __syncthreads();
        ssc[tid] += u;
        __syncthreads();
    }
    if (tid < NB) {
        int ex = ssc[tid] - v;
        lbase[tid] = ex;
        lpos[tid] = ex;
    }
    __syncthreads();
    // place into LDS staging grouped by bucket
    #pragma unroll
    for (int i = 0; i < 8; ++i) {
        if (mtd[i] >= 0) {
            int bin = mtd[i] >> BSH;
            int p = atomicAdd(&lpos[bin], 1);
            std_[p] = mtd[i]; ssrc[p] = msrc[i]; sdv[p] = md[i];
        }
    }
    __syncthreads();
    // reserve global runs: one atomic per (block, bucket)
    for (int b = tid; b < NB; b += 512)
        if (lbcnt[b]) lgst[b] = atomicAdd(&bcur[b], lbcnt[b]);
    __syncthreads();
    // coalesced flush of runs
    for (int j = tid; j < total; j += 512) {
        int bin = std_[j] >> BSH;
        int dest = lbb[bin] + lgst[bin] + (j - lbase[bin]);
        ipair[dest] = make_int2(std_[j], ssrc[j]);
        idv[dest] = sdv[j];
    }
}

// passB: one block per bucket; in-LDS edge hist + scan -> rowp (coalesced)
// and final packed placement flushed coalesced.
__global__ __launch_bounds__(512) void k_passB(
    const int2* __restrict__ ipair, const float* __restrict__ idv,
    const int* __restrict__ bbase, int2* __restrict__ packed,
    int* __restrict__ rowp, int E, int T) {
    __shared__ int2 spk[CAPB];
    __shared__ int hcnt[512], lcur[512], ssc[512];
    int tid = threadIdx.x;
    int b = blockIdx.x;
    int ibeg = bbase[b], iend = bbase[b + 1];
    int nb = iend - ibeg;
    int e0 = b << BSH;
    hcnt[tid] = 0;
    __syncthreads();
    for (int j = ibeg + tid; j < iend; j += 512)
        atomicAdd(&hcnt[ipair[j].x - e0], 1);
    __syncthreads();
    int v = hcnt[tid];
    ssc[tid] = v;
    __syncthreads();
    for (int off = 1; off < 512; off <<= 1) {
        int u = (tid >= off) ? ssc[tid - off] : 0;
        __syncthreads();
        ssc[tid] += u;
        __syncthreads();
    }
    int excl = ssc[tid] - v;
    lcur[tid] = excl;
    int e = e0 + tid;
    if (e < E) rowp[e] = ibeg + excl;
    if (b == 0 && tid == 0) rowp[E] = T;
    __syncthreads();
    bool staged = (nb <= CAPB);
    for (int j = ibeg + tid; j < iend; j += 512) {
        int2 pr = ipair[j];
        int pos = atomicAdd(&lcur[pr.x - e0], 1);
        int2 out = make_int2(pr.y, __float_as_int(idv[j]));
        if (staged) spk[pos] = out;
        else packed[ibeg + pos] = out;
    }
    __syncthreads();
    if (staged)
        for (int j = tid; j < nb; j += 512) packed[ibeg + j] = spk[j];
}

// epos[e] = CSR slot of edge e under its destination node (for msg layout)
__global__ void k_escatter(const int* __restrict__ gd, const int* __restrict__ erowp,
                           int* __restrict__ cursor, int* __restrict__ epos, int E) {
    int e = blockIdx.x * blockDim.x + threadIdx.x;
    if (e >= E) return;
    int n = gd[e];
    int pos = erowp[n] + atomicAdd(&cursor[n], 1);
    epos[e] = pos;
}

// ---- degree bucket sort of edges (by triplet-segment length) ----
__global__ __launch_bounds__(256) void k_deghist(
    const int* __restrict__ rowp, int* __restrict__ dcnt, int E) {
    __shared__ int h[256];
    int tid = threadIdx.x;
    h[tid] = 0;
    __syncthreads();
    int e = blockIdx.x * 256 + tid;
    if (e < E) {
        int d = rowp[e + 1] - rowp[e];
        if (d > 255) d = 255;
        atomicAdd(&h[d], 1);
    }
    __syncthreads();
    if (h[tid]) atomicAdd(&dcnt[tid], h[tid]);
}

__global__ __launch_bounds__(256) void k_degscatter(
    const int* __restrict__ rowp, const int* __restrict__ doff,
    int* __restrict__ dcur, int* __restrict__ eperm, int E) {
    __shared__ int lcnt[256];
    __shared__ int base[256];
    int tid = threadIdx.x;
    lcnt[tid] = 0;
    __syncthreads();
    int e = blockIdx.x * 256 + tid;
    int d = 0, rk = 0;
    if (e < E) {
        d = rowp[e + 1] - rowp[e];
        if (d > 255) d = 255;
        rk = atomicAdd(&lcnt[d], 1);
    }
    __syncthreads();
    if (lcnt[tid]) base[tid] = atomicAdd(&dcur[tid], lcnt[tid]);
    __syncthreads();
    // DESCENDING degree order (LPT): longest-running waves dispatch first,
    // short waves backfill the tail (R24: 57us -> balances the drain).
    if (e < E) eperm[E - 1 - (doff[d] + base[d] + rk)] = e;
}

// 32x32 tiled transpose + cast: src fp32 [K][Nn] -> dst bf16 [Nn][K].
// blockIdx.z = layer (strided), batching 3 layers into one dispatch.
__global__ __launch_bounds__(256) void k_castT(
    const float* __restrict__ src0, bf16_t* __restrict__ dst0, int K, int Nn) {
    __shared__ float tile[32][33];
    const float* src = src0 + (size_t)blockIdx.z * K * Nn;
    bf16_t* dst = dst0 + (size_t)blockIdx.z * K * Nn;
    int k0 = blockIdx.x * 32, n0 = blockIdx.y * 32;
    int tx = threadIdx.x & 31, ty = threadIdx.x >> 5;
    #pragma unroll
    for (int i = 0; i < 4; ++i) {
        int row = ty + i * 8;
        tile[row][tx] = src[(size_t)(k0 + row) * Nn + n0 + tx];
    }
    __syncthreads();
    #pragma unroll
    for (int i = 0; i < 4; ++i) {
        int row = ty + i * 8;
        dst[(size_t)(n0 + row) * K + k0 + tx] = f2bf(tile[tx][row]);
    }
}

// MFMA node_proj: xs = x@Wsrc + bs, xd = x@Wdst + bd (bf16 out, R26).
// R25: Wst/Wdt staged into LDS (32KB each, padded rows).
__global__ __launch_bounds__(256) void k_node_proj(
    const bf16_t* __restrict__ xb,
    const bf16_t* __restrict__ Wst, const float* __restrict__ bs,
    const bf16_t* __restrict__ Wdt, const float* __restrict__ bd,
    bf16_t* __restrict__ xs, bf16_t* __restrict__ xd, int N) {
    __shared__ bf16_t wsl[64 * WPAD];
    __shared__ bf16_t wdl[64 * WPAD];
    int tid = threadIdx.x;
    for (int i = tid; i < 2048; i += 256) {
        int row = i >> 5, inw = i & 31;
        *(uint4*)&wsl[row * WPAD + inw * 8] =
            *(const uint4*)&Wst[(size_t)row * DMODEL + inw * 8];
        *(uint4*)&wdl[row * WPAD + inw * 8] =
            *(const uint4*)&Wdt[(size_t)row * DMODEL + inw * 8];
    }
    __syncthreads();
    int w = tid >> 6, lane = tid & 63;
    int col = lane & 15, quad = lane >> 4;
    int m0 = blockIdx.x * 64 + w * 16;
    f4 as[4] = {{0.f,0.f,0.f,0.f},{0.f,0.f,0.f,0.f},
                {0.f,0.f,0.f,0.f},{0.f,0.f,0.f,0.f}};
    f4 ad[4] = {{0.f,0.f,0.f,0.f},{0.f,0.f,0.f,0.f},
                {0.f,0.f,0.f,0.f},{0.f,0.f,0.f,0.f}};
    #pragma unroll
    for (int k0 = 0; k0 < DMODEL; k0 += 32) {
        s8v a = *(const s8v*)&xb[(size_t)(m0 + col) * DMODEL + k0 + quad * 8];
        #pragma unroll
        for (int t = 0; t < 4; ++t) {
            s8v b1v = *(const s8v*)&wsl[(t * 16 + col) * WPAD + k0 + quad * 8];
            as[t] = __builtin_amdgcn_mfma_f32_16x16x32_bf16(a, b1v, as[t], 0, 0, 0);
            s8v b2v = *(const s8v*)&wdl[(t * 16 + col) * WPAD + k0 + quad * 8];
            ad[t] = __builtin_amdgcn_mfma_f32_16x16x32_bf16(a, b2v, ad[t], 0, 0, 0);
        }
    }
    #pragma unroll
    for (int t = 0; t < 4; ++t) {
        int c = t * 16 + col;
        float bsv = bs[c], bdv = bd[c];
        #pragma unroll
        for (int r = 0; r < 4; ++r) {
            int m = m0 + quad * 4 + r;
            if (m < N) {
                xs[(size_t)m * DM + c] = f2bf(as[t][r] + bsv);
                xd[(size_t)m * DM + c] = f2bf(ad[t][r] + bdv);
            }
        }
    }
}

// MFMA k_xij: xij[e][c] = (RBF(bl[e]) @ Wedge)[c] + xs[gs[e]][c] + xd[gd[e]][c] + be[c]
// R25: Wedgt staged into LDS. R26: xs/xd bf16 (fits per-XCD L2 -> cheap gather).
__global__ __launch_bounds__(256) void k_xij(
    const float* __restrict__ bl, const bf16_t* __restrict__ Wedgt,
    const float* __restrict__ be,
    const bf16_t* __restrict__ xs, const bf16_t* __restrict__ xd,
    const int* __restrict__ gs, const int* __restrict__ gd,
    bf16_t* __restrict__ xij, int E) {
    __shared__ bf16_t wel[64 * WPAD];
    int tid = threadIdx.x;
    for (int i = tid; i < 2048; i += 256) {
        int row = i >> 5, inw = i & 31;
        *(uint4*)&wel[row * WPAD + inw * 8] =
            *(const uint4*)&Wedgt[(size_t)row * DMODEL + inw * 8];
    }
    __syncthreads();
    int w = tid >> 6, lane = tid & 63;
    int col = lane & 15, quad = lane >> 4;
    int m0 = blockIdx.x * 64 + w * 16;
    const float step = 8.0f / 255.0f;
    const float gamma = (255.0f / 8.0f) * (255.0f / 8.0f);
    int me = m0 + col;
    float blv = (me < E) ? bl[me] : 0.f;
    f4 acc[4] = {{0.f,0.f,0.f,0.f},{0.f,0.f,0.f,0.f},
                 {0.f,0.f,0.f,0.f},{0.f,0.f,0.f,0.f}};
    #pragma unroll
    for (int k0 = 0; k0 < DMODEL; k0 += 32) {
        s8v a;
        #pragma unroll
        for (int j = 0; j < 8; ++j) {
            float c = (float)(k0 + quad * 8 + j) * step;
            float dd = blv - c;
            a[j] = (short)f2bf(__expf(-gamma * dd * dd));
        }
        #pragma unroll
        for (int t = 0; t < 4; ++t) {
            s8v b = *(const s8v*)&wel[(t * 16 + col) * WPAD + k0 + quad * 8];
            acc[t] = __builtin_amdgcn_mfma_f32_16x16x32_bf16(a, b, acc[t], 0, 0, 0);
        }
    }
    #pragma unroll
    for (int r = 0; r < 4; ++r) {
        int e = m0 + quad * 4 + r;
        if (e >= E) continue;
        int s = gs[e], d2 = gd[e];
        #pragma unroll
        for (int t = 0; t < 4; ++t) {
            int c = t * 16 + col;
            float v = acc[t][r] + bf2f(xs[(size_t)s * DM + c])
                    + bf2f(xd[(size_t)d2 * DM + c]) + be[c];
            xij[(size_t)e * DM + c] = f2bf(v);
        }
    }
}

// Fused logit+softmax+attend: 4 lanes per edge (degree-sorted via eperm),
// 16 channels per lane. Chebyshev T_k(d); 2-shfl reduce. R27: msg written
// at the edge's CSR slot epos[e] so k_aggregate reads sequentially.
__global__ __launch_bounds__(256) void k_edge_attn(
    const bf16_t* __restrict__ xij, const int2* __restrict__ packed,
    const int* __restrict__ rowp, const float* __restrict__ attn_l,
    const int* __restrict__ eperm, const int* __restrict__ epos,
    bf16_t* __restrict__ msg, int E) {
    int gtid = blockIdx.x * 256 + threadIdx.x;
    int ei = gtid >> 2;
    if (ei >= E) return;
    int q = gtid & 3;                  // channel block [16q, 16q+16)
    int e = eperm[ei];
    int beg = rowp[e], end = rowp[e + 1];

    float av[16];
    #pragma unroll
    for (int c = 0; c < 16; ++c) av[c] = attn_l[q * 16 + c];

    // my 16 channels of this edge's xij row (32B)
    uint4 xe0, xe1;
    {
        const uint4* xer = (const uint4*)&xij[(size_t)e * DM + q * 16];
        xe0 = xer[0]; xe1 = xer[1];
    }
    float acc[16];
    #pragma unroll
    for (int c = 0; c < 16; ++c) acc[c] = 0.f;
    float den = 0.f;

    if (beg < end) {
        // depth-1 pipeline priming
        int2 pk0 = packed[beg];
        int2 pk1 = (beg + 1 < end) ? packed[beg + 1] : pk0;
        const uint4* s0 = (const uint4*)&xij[(size_t)pk0.x * DM + q * 16];
        uint4 nsa = s0[0], nsb = s0[1];
        for (int p = beg; p < end; ++p) {
            float d = __int_as_float(pk0.y);
            uint4 xa = nsa, xb = nsb;
            if (p + 1 < end) {
                const uint4* sn = (const uint4*)&xij[(size_t)pk1.x * DM + q * 16];
                nsa = sn[0]; nsb = sn[1];
                pk0 = pk1;
                if (p + 2 < end) pk1 = packed[p + 2];
            }
            float d2 = d + d;
            // ladder: seeds T_{16q}, T_{16q+1} via 2TmTn = T_{m+n} + T_{|m-n|}
            float t2  = fmaf(d2, d, -1.f);
            float t3  = fmaf(d2, t2, -d);
            float t4  = fmaf(t2 + t2, t2, -1.f);
            float t7  = fmaf(t4 + t4, t3, -d);
            float t8  = fmaf(t4 + t4, t4, -1.f);
            float t15 = fmaf(t8 + t8, t7, -d);
            float t16 = fmaf(t8 + t8, t8, -1.f);
            float t17 = fmaf(t16 + t16, d, -t15);
            float t31 = fmaf(t16 + t16, t15, -d);
            float t32 = fmaf(t16 + t16, t16, -1.f);
            float t33 = fmaf(t32 + t32, d, -t31);
            float t48 = fmaf(t32 + t32, t16, -t16);
            float t49 = fmaf(t32 + t32, t17, -t15);
            float za, zb;                        // T_{16q}, T_{16q+1}
            if (q == 0)      { za = 1.f;  zb = d;   }
            else if (q == 1) { za = t16;  zb = t17; }
            else if (q == 2) { za = t32;  zb = t33; }
            else             { za = t48;  zb = t49; }
            float logit = 0.f;
            #define CH2(uw, ew, c)                                            \
            {                                                                 \
                float u0 = za + bf_lo(uw) + bf_lo(ew);                        \
                float zn = fmaf(d2, zb, -za); za = zb; zb = zn;               \
                float u1 = za + bf_hi(uw) + bf_hi(ew);                        \
                zn = fmaf(d2, zb, -za); za = zb; zb = zn;                     \
                logit = fmaf(silu_f(u0), av[c], logit);                       \
                logit = fmaf(silu_f(u1), av[c + 1], logit);                   \
            }
            CH2(xa.x, xe0.x, 0);
            CH2(xa.y, xe0.y, 2);
            CH2(xa.z, xe0.z, 4);
            CH2(xa.w, xe0.w, 6);
            CH2(xb.x, xe1.x, 8);
            CH2(xb.y, xe1.y, 10);
            CH2(xb.z, xe1.z, 12);
            CH2(xb.w, xe1.w, 14);
            #undef CH2
            // sum logit across the 4-lane group
            logit += __shfl_xor(logit, 1, 64);
            logit += __shfl_xor(logit, 2, 64);
            float wg = __expf(logit);
            den += wg;
            acc[0]  = fmaf(wg, bf_lo(xa.x), acc[0]);
            acc[1]  = fmaf(wg, bf_hi(xa.x), acc[1]);
            acc[2]  = fmaf(wg, bf_lo(xa.y), acc[2]);
            acc[3]  = fmaf(wg, bf_hi(xa.y), acc[3]);
            acc[4]  = fmaf(wg, bf_lo(xa.z), acc[4]);
            acc[5]  = fmaf(wg, bf_hi(xa.z), acc[5]);
            acc[6]  = fmaf(wg, bf_lo(xa.w), acc[6]);
            acc[7]  = fmaf(wg, bf_hi(xa.w), acc[7]);
            acc[8]  = fmaf(wg, bf_lo(xb.x), acc[8]);
            acc[9]  = fmaf(wg, bf_hi(xb.x), acc[9]);
            acc[10] = fmaf(wg, bf_lo(xb.y), acc[10]);
            acc[11] = fmaf(wg, bf_hi(xb.y), acc[11]);
            acc[12] = fmaf(wg, bf_lo(xb.z), acc[12]);
            acc[13] = fmaf(wg, bf_hi(xb.z), acc[13]);
            acc[14] = fmaf(wg, bf_lo(xb.w), acc[14]);
            acc[15] = fmaf(wg, bf_hi(xb.w), acc[15]);
        }
    }
    float inv = (den > 0.f) ? 1.f / den : 0.f;
    uint4 o0, o1;
    o0.x = (unsigned int)f2bf(acc[0] * inv)  | ((unsigned int)f2bf(acc[1] * inv) << 16);
    o0.y = (unsigned int)f2bf(acc[2] * inv)  | ((unsigned int)f2bf(acc[3] * inv) << 16);
    o0.z = (unsigned int)f2bf(acc[4] * inv)  | ((unsigned int)f2bf(acc[5] * inv) << 16);
    o0.w = (unsigned int)f2bf(acc[6] * inv)  | ((unsigned int)f2bf(acc[7] * inv) << 16);
    o1.x = (unsigned int)f2bf(acc[8] * inv)  | ((unsigned int)f2bf(acc[9] * inv) << 16);
    o1.y = (unsigned int)f2bf(acc[10] * inv) | ((unsigned int)f2bf(acc[11] * inv) << 16);
    o1.z = (unsigned int)f2bf(acc[12] * inv) | ((unsigned int)f2bf(acc[13] * inv) << 16);
    o1.w = (unsigned int)f2bf(acc[14] * inv) | ((unsigned int)f2bf(acc[15] * inv) << 16);
    int mrow = epos[e];
    uint4* op = (uint4*)&msg[(size_t)mrow * DM + q * 16];
    op[0] = o0;
    op[1] = o1;
}

// thread per (node, channel-quad): sum bf16 msg rows (now CSR-contiguous).
__global__ __launch_bounds__(256) void k_aggregate(
    const bf16_t* __restrict__ msg, const int* __restrict__ erowp,
    bf16_t* __restrict__ ft, int N) {
    int gtid = blockIdx.x * 256 + threadIdx.x;
    int n = gtid >> 4;
    if (n >= N) return;
    int quad = gtid & 15;
    int beg = erowp[n], end = erowp[n + 1];
    float a0 = 0.f, a1 = 0.f, a2 = 0.f, a3 = 0.f;
    for (int j = beg; j < end; ++j) {
        uint2 uv = *(const uint2*)&msg[(size_t)j * DM + quad * 4];
        a0 += bf_lo(uv.x); a1 += bf_hi(uv.x);
        a2 += bf_lo(uv.y); a3 += bf_hi(uv.y);
    }
    ushort4 o = {f2bf(a0), f2bf(a1), f2bf(a2), f2bf(a3)};
    *(ushort4*)&ft[(size_t)n * DM + quad * 4] = o;
}

// Fused FFN: x = silu(ft@W1 + b1) @ W2 + b2; h never leaves the CU.
// Grid (N/64, 4): blockIdx.y owns 64 output cols. Block = 64 rows, 4 waves.
// Weights stream through double-buffered LDS (pad-72 rows). R23.
__global__ __launch_bounds__(256) void k_ffn_fused(
    const bf16_t* __restrict__ ft, const bf16_t* __restrict__ W1t,
    const float* __restrict__ b1, const bf16_t* __restrict__ W2t,
    const float* __restrict__ b2, bf16_t* __restrict__ x, int N) {
    __shared__ bf16_t w1s[2][64 * 72];
    __shared__ bf16_t w2s[2][64 * 72];
    __shared__ bf16_t hld[4][16 * 72];
    __shared__ float b1s[HDIM];
    int tid = threadIdx.x;
    int w = tid >> 6, lane = tid & 63;
    int col = lane & 15, quad = lane >> 4;
    int m0 = blockIdx.x * 64 + w * 16;
    int c0 = blockIdx.y * 64;                 // this block's output columns
    bf16_t* myl = hld[w];

    // bias table -> LDS once
    #pragma unroll
    for (int j = 0; j < 4; ++j) b1s[tid + j * 256] = b1[tid + j * 256];

    // ft A-fragments for this wave's 16 rows (k = 0..63), held all kernel
    s8v fa0 = *(const s8v*)&ft[(size_t)(m0 + col) * DM + quad * 8];
    s8v fa1 = *(const s8v*)&ft[(size_t)(m0 + col) * DM + 32 + quad * 8];

    // staging geometry: piece idx = r*256+tid -> row = idx>>3, kblk = idx&7
    int srow0 = tid >> 3;            // r=0 rows 0..31
    int srow1 = 32 + srow0;          // r=1 rows 32..63
    int skb = tid & 7;

    f4 acc[4] = {{0.f,0.f,0.f,0.f},{0.f,0.f,0.f,0.f},
                 {0.f,0.f,0.f,0.f},{0.f,0.f,0.f,0.f}};

    // ---- prologue: stage chunk 0 into buffer 0 ----
    {
        uint4 a0 = *(const uint4*)&W1t[(size_t)srow0 * DM + skb * 8];
        uint4 a1 = *(const uint4*)&W1t[(size_t)srow1 * DM + skb * 8];
        uint4 c0v = *(const uint4*)&W2t[(size_t)(c0 + srow0) * HDIM + skb * 8];
        uint4 c1v = *(const uint4*)&W2t[(size_t)(c0 + srow1) * HDIM + skb * 8];
        *(uint4*)&w1s[0][srow0 * 72 + skb * 8] = a0;
        *(uint4*)&w1s[0][srow1 * 72 + skb * 8] = a1;
        *(uint4*)&w2s[0][srow0 * 72 + skb * 8] = c0v;
        *(uint4*)&w2s[0][srow1 * 72 + skb * 8] = c1v;
    }
    __syncthreads();

    #pragma unroll 1
    for (int kc = 0; kc < 16; ++kc) {         // h-col chunks of 64
        int cb = kc & 1, nb = cb ^ 1;
        int ch0 = kc * 64;
        int chn = (kc < 15) ? ch0 + 64 : ch0;  // clamped (load redundant on last)
        // issue next-chunk global loads into regs (no use until after barrier)
        uint4 na0 = *(const uint4*)&W1t[(size_t)(chn + srow0) * DM + skb * 8];
        uint4 na1 = *(const uint4*)&W1t[(size_t)(chn + srow1) * DM + skb * 8];
        uint4 nc0 = *(const uint4*)&W2t[(size_t)(c0 + srow0) * HDIM + chn + skb * 8];
        uint4 nc1 = *(const uint4*)&W2t[(size_t)(c0 + srow1) * HDIM + chn + skb * 8];
        // ---- compute current chunk entirely from LDS ----
        #pragma unroll
        for (int th = 0; th < 4; ++th) {
            s8v wb0 = *(const s8v*)&w1s[cb][(th * 16 + col) * 72 + quad * 8];
            s8v wb1 = *(const s8v*)&w1s[cb][(th * 16 + col) * 72 + 32 + quad * 8];
            f4 hv = {0.f, 0.f, 0.f, 0.f};
            hv = __builtin_amdgcn_mfma_f32_16x16x32_bf16(fa0, wb0, hv, 0, 0, 0);
            hv = __builtin_amdgcn_mfma_f32_16x16x32_bf16(fa1, wb1, hv, 0, 0, 0);
            float bb = b1s[ch0 + th * 16 + col];
            #pragma unroll
            for (int r = 0; r < 4; ++r)
                myl[(quad * 4 + r) * 72 + th * 16 + col] =
                    f2bf(silu_f(hv[r] + bb));
        }
        // A-fragments of h (wave-private tile; compiler emits lgkmcnt waits)
        s8v ha0 = *(const s8v*)&myl[col * 72 + quad * 8];
        s8v ha1 = *(const s8v*)&myl[col * 72 + 32 + quad * 8];
        #pragma unroll
        for (int t2 = 0; t2 < 4; ++t2) {
            s8v vb0 = *(const s8v*)&w2s[cb][(t2 * 16 + col) * 72 + quad * 8];
            s8v vb1 = *(const s8v*)&w2s[cb][(t2 * 16 + col) * 72 + 32 + quad * 8];
            acc[t2] = __builtin_amdgcn_mfma_f32_16x16x32_bf16(ha0, vb0, acc[t2], 0, 0, 0);
            acc[t2] = __builtin_amdgcn_mfma_f32_16x16x32_bf16(ha1, vb1, acc[t2], 0, 0, 0);
        }
        __syncthreads();                       // all waves done reading buf nb
        if (kc < 15) {
            *(uint4*)&w1s[nb][srow0 * 72 + skb * 8] = na0;
            *(uint4*)&w1s[nb][srow1 * 72 + skb * 8] = na1;
            *(uint4*)&w2s[nb][srow0 * 72 + skb * 8] = nc0;
            *(uint4*)&w2s[nb][srow1 * 72 + skb * 8] = nc1;
        }
        __syncthreads();                       // buf nb ready for next iter
    }
    #pragma unroll
    for (int t2 = 0; t2 < 4; ++t2) {
        int c = c0 + t2 * 16 + col;
        float bb = b2[c];
        #pragma unroll
        for (int r = 0; r < 4; ++r) {
            int m = m0 + quad * 4 + r;
            if (m < N) x[(size_t)m * DMODEL + c] = f2bf(acc[t2][r] + bb);
        }
    }
}

// grid-stride dot over bf16 x, one atomic per block.
__global__ __launch_bounds__(256) void k_out_reduce(
    const bf16_t* __restrict__ x, const float* __restrict__ Wfc,
    float* __restrict__ acc, int NT) {
    __shared__ float sm[4];
    int tid = threadIdx.x;
    float v = 0.f;
    int np = NT / 2;
    const unsigned int* xp = (const unsigned int*)x;
    for (int i = blockIdx.x * blockDim.x + tid; i < np; i += gridDim.x * blockDim.x) {
        unsigned int u = xp[i];
        int c = (2 * i) & (DMODEL - 1);
        v = fmaf(bf_lo(u), Wfc[c], v);
        v = fmaf(bf_hi(u), Wfc[c + 1], v);
    }
    for (int off = 32; off > 0; off >>= 1) v += __shfl_xor(v, off, 64);
    if ((tid & 63) == 0) sm[tid >> 6] = v;
    __syncthreads();
    if (tid == 0) {
        float s = sm[0] + sm[1] + sm[2] + sm[3];
        atomicAdd(acc, s);
    }
}

__global__ void k_out_final(const float* __restrict__ acc, const float* __restrict__ bfc,
                            float* __restrict__ out, float invN) {
    out[0] = acc[0] * invN + bfc[0];
}

extern "C" void kernel_launch(void* const* d_in, const int* in_sizes, int n_in,
                              void* d_out, int out_size, void* d_ws, size_t ws_size,
                              hipStream_t stream) {
    const int*   an    = (const int*)d_in[0];
    const int*   gs    = (const int*)d_in[1];
    const int*   gd    = (const int*)d_in[2];
    const int*   ts    = (const int*)d_in[3];
    const int*   td    = (const int*)d_in[4];
    const float* r     = (const float*)d_in[5];
    const float* emb   = (const float*)d_in[6];
    const float* Wsrc  = (const float*)d_in[7];
    const float* bsrc  = (const float*)d_in[8];
    const float* Wdst  = (const float*)d_in[9];
    const float* bdst  = (const float*)d_in[10];
    const float* Wedge = (const float*)d_in[11];
    const float* bedge = (const float*)d_in[12];
    const float* attn  = (const float*)d_in[13];
    const float* W1    = (const float*)d_in[14];
    const float* b1    = (const float*)d_in[15];
    const float* W2    = (const float*)d_in[16];
    const float* b2    = (const float*)d_in[17];
    const float* Wfc   = (const float*)d_in[18];
    const float* bfc   = (const float*)d_in[19];

    const int N = in_sizes[0];
    const int E = in_sizes[1];
    const int T = in_sizes[3];
    const int NB = (E + 511) >> BSH;          // triplet-sort buckets

    char* w = (char*)d_ws;
    size_t off = 0;
    auto alloc = [&](size_t bytes) {
        void* p = w + off;
        off += (bytes + 255) & ~(size_t)255;
        return p;
    };
    bf16_t* xb     = (bf16_t*)alloc((size_t)(N + 64) * DMODEL * 2);
    float*  rn     = (float*) alloc((size_t)E * 3 * 4);
    float*  bl     = (float*) alloc(((size_t)E + 64) * 4);
    int*    rowp   = (int*)   alloc(((size_t)E + 1) * 4);
    int*    bsum   = (int*)   alloc(4096);
    int2*   packed = (int2*)  alloc((size_t)T * 8);
    int2*   ipair  = (int2*)  alloc((size_t)T * 8);
    float*  idv    = (float*) alloc((size_t)T * 4);
    int*    gbcnt  = (int*)   alloc(NBMAX * 4);   // NBMAX*4 = 1280 (256-mult):
    int*    bcur   = (int*)   alloc(NBMAX * 4);   //  gbcnt+bcur contiguous
    int*    bbase  = (int*)   alloc((NBMAX + 1) * 4);
    int*    dcnt   = (int*)   alloc(1024);        // dcnt+dcur contiguous
    int*    dcur   = (int*)   alloc(1024);
    int*    ecnt   = (int*)   alloc((size_t)N * 4);
    int*    erowp  = (int*)   alloc(((size_t)N + 1) * 4);
    int*    epos   = (int*)   alloc((size_t)E * 4);
    int*    eperm  = (int*)   alloc((size_t)E * 4);
    bf16_t* xs     = (bf16_t*)alloc((size_t)N * DM * 2);
    bf16_t* xd     = (bf16_t*)alloc((size_t)N * DM * 2);
    bf16_t* xij    = (bf16_t*)alloc((size_t)E * DM * 2);
    bf16_t* msg    = (bf16_t*)alloc((size_t)E * DM * 2);
    bf16_t* ft     = (bf16_t*)alloc((size_t)(N + 64) * DM * 2);
    bf16_t* W1t    = (bf16_t*)alloc((size_t)3 * HDIM * DM * 2);
    bf16_t* W2t    = (bf16_t*)alloc((size_t)3 * DMODEL * HDIM * 2);
    bf16_t* Wedgt  = (bf16_t*)alloc((size_t)3 * DM * DMODEL * 2);
    bf16_t* Wst    = (bf16_t*)alloc((size_t)3 * DM * DMODEL * 2);
    bf16_t* Wdt    = (bf16_t*)alloc((size_t)3 * DM * DMODEL * 2);
    float*  accs   = (float*) alloc(64);
    (void)ws_size; (void)n_in; (void)out_size;

    const int nbScanN = (N + 255) / 256;
    const int nbT = (T + 4095) / 4096;

    // ---- setup (layer-invariant) ----
    k_embed<<<N, 256, 0, stream>>>(an, emb, xb);
    k_edge_geom<<<(E + 255) / 256, 256, 0, stream>>>(r, bl, rn, E);
    // weight transposes, 3 layers batched per dispatch (blockIdx.z)
    k_castT<<<dim3(DM / 32, HDIM / 32, 3), 256, 0, stream>>>(W1, W1t, DM, HDIM);
    k_castT<<<dim3(HDIM / 32, DMODEL / 32, 3), 256, 0, stream>>>(W2, W2t, HDIM, DMODEL);
    k_castT<<<dim3(DMODEL / 32, DM / 32, 3), 256, 0, stream>>>(Wedge, Wedgt, DMODEL, DM);
    k_castT<<<dim3(DMODEL / 32, DM / 32, 3), 256, 0, stream>>>(Wsrc, Wst, DMODEL, DM);
    k_castT<<<dim3(DMODEL / 32, DM / 32, 3), 256, 0, stream>>>(Wdst, Wdt, DMODEL, DM);
    // triplet CSR by t_dst: two-level bucket sort, all writes coalesced
    hipMemsetAsync(gbcnt, 0, (size_t)2 * NBMAX * 4, stream);   // gbcnt+bcur
    k_bhist<<<nbT, 512, 0, stream>>>(td, gbcnt, T, NB);
    k_bscan<<<1, 512, 0, stream>>>(gbcnt, bbase, NB, T);
    k_passA<<<nbT, 512, 0, stream>>>(ts, td, rn, bbase, bcur, ipair, idv, T, NB);
    k_passB<<<NB, 512, 0, stream>>>(ipair, idv, bbase, packed, rowp, E, T);
    // degree-sorted edge permutation (for k_edge_attn load balance)
    hipMemsetAsync(dcnt, 0, 2048, stream);                     // dcnt+dcur
    k_deghist<<<(E + 255) / 256, 256, 0, stream>>>(rowp, dcnt, E);
    k_scan_mid<<<1, 1024, 0, stream>>>(dcnt, 256);
    k_degscatter<<<(E + 255) / 256, 256, 0, stream>>>(rowp, dcnt, dcur, eperm, E);
    // edge CSR by gd (k_scan_final re-zeroes ecnt for k_escatter)
    hipMemsetAsync(ecnt, 0, (size_t)N * 4, stream);
    k_hist<<<(E + 255) / 256, 256, 0, stream>>>(gd, ecnt, E);
    k_scan_part<<<nbScanN, 256, 0, stream>>>(ecnt, bsum, N);
    k_scan_mid<<<1, 1024, 0, stream>>>(bsum, nbScanN);
    k_scan_final<<<nbScanN, 256, 0, stream>>>(ecnt, bsum, erowp, N, E);
    k_escatter<<<(E + 255) / 256, 256, 0, stream>>>(gd, erowp, ecnt, epos, E);

    // ---- layers ----
    for (int l = 0; l < 3; ++l) {
        k_node_proj<<<(N + 63) / 64, 256, 0, stream>>>(
            xb, Wst + (size_t)l * DM * DMODEL, bsrc + l * DM,
            Wdt + (size_t)l * DM * DMODEL, bdst + l * DM, xs, xd, N);
        k_xij<<<(E + 63) / 64, 256, 0, stream>>>(
            bl, Wedgt + (size_t)l * DM * DMODEL, bedge + l * DM,
            xs, xd, gs, gd, xij, E);
        k_edge_attn<<<(E * 4 + 255) / 256, 256, 0, stream>>>(
            xij, packed, rowp, attn + l * DM, eperm, epos, msg, E);
        k_aggregate<<<(N * 16 + 255) / 256, 256, 0, stream>>>(
            msg, erowp, ft, N);
        k_ffn_fused<<<dim3((N + 63) / 64, 4), 256, 0, stream>>>(
            ft, W1t + (size_t)l * HDIM * DM, b1 + l * HDIM,
            W2t + (size_t)l * DMODEL * HDIM, b2 + l * DMODEL, xb, N);
    }

    // ---- output head ----
    hipMemsetAsync(accs, 0, 4, stream);
    k_out_reduce<<<120, 256, 0, stream>>>(xb, Wfc, accs, N * DMODEL);
    k_out_final<<<1, 1, 0, stream>>>(accs, bfc, (float*)d_out, 1.0f / (float)N);
}

// Round 14
// 577.961 us; speedup vs baseline: 1.6222x; 1.0313x over previous
//
#include <hip/hip_runtime.h>
#include <math.h>

// M3GNet-like GNN forward. N=10000 nodes, E=160000 edges, T=1200000 triplets,
// D=256, DM=64, H=1024, L=3, output = scalar mean energy (fp32).
//
// R28: finish the dispatch-count attack (R27 confirmed ~3us/dispatch):
//  - single memset (zeroed buffers made contiguous)
//  - k_prep = embed + edge_geom (block-range split)
//  - k_castT_all = all 15 weight-transpose grids in one 1104-block dispatch
//  - k_deg_ghist = degree-hist + gd-hist (same E grid)
//  - k_scan2 = the two independent 1-block scans in one dispatch
//  - k_degscat_final = degscatter + erowp scan_final in one dispatch
//  - k_out_reduce self-finalizes (last-block pattern, device-scope atomics)
//  All bit-identical. ~39 -> ~27 dispatches.

#define DM 64
#define DMODEL 256
#define HDIM 1024
#define WPAD 264

#define BSH 9            // log2(edges per bucket)
#define NBMAX 320        // max buckets (E <= 163840)
#define CAPB 4608        // passB LDS staging capacity (bucket ~3840+-62)

typedef unsigned short bf16_t;
typedef __attribute__((ext_vector_type(8))) short s8v;    // 8 bf16 (4 VGPRs)
typedef __attribute__((ext_vector_type(4))) float f4;     // MFMA acc

__device__ __forceinline__ bf16_t f2bf(float f) {
    unsigned int u = __float_as_uint(f);
    return (bf16_t)((u + 0x7FFFu + ((u >> 16) & 1u)) >> 16);   // RNE
}
__device__ __forceinline__ float bf_lo(unsigned int u) {
    return __uint_as_float(u << 16);
}
__device__ __forceinline__ float bf_hi(unsigned int u) {
    return __uint_as_float(u & 0xFFFF0000u);
}
__device__ __forceinline__ float bf2f(bf16_t v) {
    return __uint_as_float((unsigned int)v << 16);
}
__device__ __forceinline__ float silu_f(float u) {
    return u * __builtin_amdgcn_rcpf(1.f + __expf(-u));
}

// embed (blocks [0,N)) + edge_geom (blocks [N, N+ceil(E/256)))
__global__ __launch_bounds__(256) void k_prep(
    const int* __restrict__ an, const float* __restrict__ emb,
    bf16_t* __restrict__ x, const float* __restrict__ r,
    float* __restrict__ bl, float* __restrict__ rn, int N, int E) {
    if ((int)blockIdx.x < N) {
        int n = blockIdx.x;
        int d = threadIdx.x;
        x[n * DMODEL + d] = f2bf(emb[an[n] * DMODEL + d]);
    } else {
        int e = (blockIdx.x - N) * 256 + threadIdx.x;
        if (e >= E) return;
        float a = r[e * 3 + 0], b = r[e * 3 + 1], c = r[e * 3 + 2];
        float l = sqrtf(a * a + b * b + c * c);
        bl[e] = l;
        float inv = 1.0f / l;
        rn[e * 3 + 0] = a * inv;
        rn[e * 3 + 1] = b * inv;
        rn[e * 3 + 2] = c * inv;
    }
}

// all 15 weight transposes (32x32 tiles) in one dispatch; arithmetic decode.
__global__ __launch_bounds__(256) void k_castT_all(
    const float* __restrict__ W1, const float* __restrict__ W2,
    const float* __restrict__ Wedge, const float* __restrict__ Wsrc,
    const float* __restrict__ Wdst,
    bf16_t* __restrict__ W1t, bf16_t* __restrict__ W2t,
    bf16_t* __restrict__ Wedgt, bf16_t* __restrict__ Wst,
    bf16_t* __restrict__ Wdt) {
    __shared__ float tile[32][33];
    int id = blockIdx.x;
    const float* src; bf16_t* dst; int K, Nn, k0, n0;
    if (id < 192) {                       // W1: [64][1024] x3, 64 tiles/layer
        int layer = id / 64, t = id % 64;
        src = W1 + (size_t)layer * DM * HDIM;
        dst = W1t + (size_t)layer * HDIM * DM;
        K = DM; Nn = HDIM; k0 = (t % 2) * 32; n0 = (t / 2) * 32;
    } else if (id < 960) {                // W2: [1024][256] x3, 256 tiles/layer
        int rem = id - 192, layer = rem / 256, t = rem % 256;
        src = W2 + (size_t)layer * HDIM * DMODEL;
        dst = W2t + (size_t)layer * DMODEL * HDIM;
        K = HDIM; Nn = DMODEL; k0 = (t % 32) * 32; n0 = (t / 32) * 32;
    } else {                              // Wedge/Wsrc/Wdst: [256][64] x3, 16/layer
        int rem = id - 960, which = rem / 48, r2 = rem % 48;
        int layer = r2 / 16, t = r2 % 16;
        const float* s3[3] = {Wedge, Wsrc, Wdst};
        bf16_t* d3[3] = {Wedgt, Wst, Wdt};
        src = s3[which] + (size_t)layer * DMODEL * DM;
        dst = d3[which] + (size_t)layer * DM * DMODEL;
        K = DMODEL; Nn = DM; k0 = (t % 8) * 32; n0 = (t / 8) * 32;
    }
    int tx = threadIdx.x & 31, ty = threadIdx.x >> 5;
    #pragma unroll
    for (int i = 0; i < 4; ++i) {
        int row = ty + i * 8;
        tile[row][tx] = src[(size_t)(k0 + row) * Nn + n0 + tx];
    }
    __syncthreads();
    #pragma unroll
    for (int i = 0; i < 4; ++i) {
        int row = ty + i * 8;
        dst[(size_t)(n0 + row) * K + k0 + tx] = f2bf(tile[tx][row]);
    }
}

// ---- scan helpers ----
__global__ __launch_bounds__(256) void k_scan_part(
    const int* __restrict__ cnt, int* __restrict__ bsum, int M) {
    __shared__ int sm[4];
    int tid = threadIdx.x;
    int i = blockIdx.x * 256 + tid;
    int v = (i < M) ? cnt[i] : 0;
    for (int off = 32; off > 0; off >>= 1) v += __shfl_xor(v, off, 64);
    if ((tid & 63) == 0) sm[tid >> 6] = v;
    __syncthreads();
    if (tid == 0) bsum[blockIdx.x] = sm[0] + sm[1] + sm[2] + sm[3];
}

__device__ __forceinline__ void scan_mid_body(int* bsum, int nb) {
    __shared__ int sm[1024];
    int tid = threadIdx.x;
    int v = (tid < nb) ? bsum[tid] : 0;
    sm[tid] = v;
    __syncthreads();
    for (int off = 1; off < 1024; off <<= 1) {
        int u = (tid >= off) ? sm[tid - off] : 0;
        __syncthreads();
        sm[tid] += u;
        __syncthreads();
    }
    if (tid < nb) bsum[tid] = sm[tid] - v;
}

// two independent 1-block scans: block 0 -> dcnt(256), block 1 -> bsum(nbN)
__global__ __launch_bounds__(1024) void k_scan2(
    int* __restrict__ dcnt, int* __restrict__ bsum, int nbN) {
    if (blockIdx.x == 0) scan_mid_body(dcnt, 256);
    else scan_mid_body(bsum, nbN);
}

// ---- two-level bucket sort of triplets by t_dst ----
__global__ __launch_bounds__(512) void k_bhist(
    const int* __restrict__ td, int* __restrict__ gbcnt, int T, int NB) {
    __shared__ int h[NBMAX];
    int tid = threadIdx.x;
    for (int i = tid; i < NBMAX; i += 512) h[i] = 0;
    __syncthreads();
    int t0 = blockIdx.x * 4096;
    #pragma unroll
    for (int i = 0; i < 8; ++i) {
        int t = t0 + tid + i * 512;
        if (t < T) atomicAdd(&h[td[t] >> BSH], 1);
    }
    __syncthreads();
    for (int b = tid; b < NB; b += 512)
        if (h[b]) atomicAdd(&gbcnt[b], h[b]);
}

__global__ __launch_bounds__(512) void k_bscan(
    const int* __restrict__ gbcnt, int* __restrict__ bbase, int NB, int total) {
    __shared__ int sm[512];
    int tid = threadIdx.x;
    int v = (tid < NB) ? gbcnt[tid] : 0;
    sm[tid] = v;
    __syncthreads();
    for (int off = 1; off < 512; off <<= 1) {
        int u = (tid >= off) ? sm[tid - off] : 0;
        __syncthreads();
        sm[tid] += u;
        __syncthreads();
    }
    if (tid < NB) bbase[tid] = sm[tid] - v;
    if (tid == 0) bbase[NB] = total;
}

__global__ __launch_bounds__(512) void k_passA(
    const int* __restrict__ ts, const int* __restrict__ td,
    const float* __restrict__ rn, const int* __restrict__ bbase,
    int* __restrict__ bcur, int2* __restrict__ ipair, float* __restrict__ idv,
    int T, int NB) {
    __shared__ int   std_[4096];
    __shared__ int   ssrc[4096];
    __shared__ float sdv[4096];
    __shared__ int lbcnt[NBMAX], lbase[NBMAX], lpos[NBMAX], lgst[NBMAX],
                   lbb[NBMAX];
    __shared__ int ssc[512];
    int tid = threadIdx.x;
    int t0 = blockIdx.x * 4096;
    int total = min(4096, T - t0);
    for (int i = tid; i < NBMAX; i += 512) lbcnt[i] = 0;
    for (int i = tid; i < NB; i += 512) lbb[i] = bbase[i];
    __syncthreads();
    int   mtd[8], msrc[8];
    float md[8];
    #pragma unroll
    for (int i = 0; i < 8; ++i) {
        int idx = tid + i * 512;
        mtd[i] = -1;
        if (idx < total) {
            int t = t0 + idx;
            int a = ts[t], b = td[t];
            float d = rn[a * 3 + 0] * rn[b * 3 + 0]
                    + rn[a * 3 + 1] * rn[b * 3 + 1]
                    + rn[a * 3 + 2] * rn[b * 3 + 2];
            d = fminf(1.0f, fmaxf(-1.0f, d));
            mtd[i] = b; msrc[i] = a; md[i] = d;
            atomicAdd(&lbcnt[b >> BSH], 1);
        }
    }
    __syncthreads();
    int v = (tid < NB) ? lbcnt[tid] : 0;
    ssc[tid] = v;
    __syncthreads();
    for (int off = 1; off < 512; off <<= 1) {
        int u = (tid >= off) ? ssc[tid - off] : 0;
        __syncthreads();
        ssc[tid] += u;
        __syncthreads();
    }
    if (tid < NB) {
        int ex = ssc[tid] - v;
        lbase[tid] = ex;
        lpos[tid] = ex;
    }
    __syncthreads();
    #pragma unroll
    for (int i = 0; i < 8; ++i) {
        if (mtd[i] >= 0) {
            int bin = mtd[i] >> BSH;
            int p = atomicAdd(&lpos[bin], 1);
            std_[p] = mtd[i]; ssrc[p] = msrc[i]; sdv[p] = md[i];
        }
    }
    __syncthreads();
    for (int b = tid; b < NB; b += 512)
        if (lbcnt[b]) lgst[b] = atomicAdd(&bcur[b], lbcnt[b]);
    __syncthreads();
    for (int j = tid; j < total; j += 512) {
        int bin = std_[j] >> BSH;
        int dest = lbb[bin] + lgst[bin] + (j - lbase[bin]);
        ipair[dest] = make_int2(std_[j], ssrc[j]);
        idv[dest] = sdv[j];
    }
}

__global__ __launch_bounds__(512) void k_passB(
    const int2* __restrict__ ipair, const float* __restrict__ idv,
    const int* __restrict__ bbase, int2* __restrict__ packed,
    int* __restrict__ rowp, int E, int T) {
    __shared__ int2 spk[CAPB];
    __shared__ int hcnt[512], lcur[512], ssc[512];
    int tid = threadIdx.x;
    int b = blockIdx.x;
    int ibeg = bbase[b], iend = bbase[b + 1];
    int nb = iend - ibeg;
    int e0 = b << BSH;
    hcnt[tid] = 0;
    __syncthreads();
    for (int j = ibeg + tid; j < iend; j += 512)
        atomicAdd(&hcnt[ipair[j].x - e0], 1);
    __syncthreads();
    int v = hcnt[tid];
    ssc[tid] = v;
    __syncthreads();
    for (int off = 1; off < 512; off <<= 1) {
        int u = (tid >= off) ? ssc[tid - off] : 0;
        __syncthreads();
        ssc[tid] += u;
        __syncthreads();
    }
    int excl = ssc[tid] - v;
    lcur[tid] = excl;
    int e = e0 + tid;
    if (e < E) rowp[e] = ibeg + excl;
    if (b == 0 && tid == 0) rowp[E] = T;
    __syncthreads();
    bool staged = (nb <= CAPB);
    for (int j = ibeg + tid; j < iend; j += 512) {
        int2 pr = ipair[j];
        int pos = atomicAdd(&lcur[pr.x - e0], 1);
        int2 out = make_int2(pr.y, __float_as_int(idv[j]));
        if (staged) spk[pos] = out;
        else packed[ibeg + pos] = out;
    }
    __syncthreads();
    if (staged)
        for (int j = tid; j < nb; j += 512) packed[ibeg + j] = spk[j];
}

// merged: triplet-degree LDS hist (dcnt) + gd hist (ecnt), one E-grid pass
__global__ __launch_bounds__(256) void k_deg_ghist(
    const int* __restrict__ rowp, int* __restrict__ dcnt,
    const int* __restrict__ gd, int* __restrict__ ecnt, int E) {
    __shared__ int h[256];
    int tid = threadIdx.x;
    h[tid] = 0;
    __syncthreads();
    int e = blockIdx.x * 256 + tid;
    if (e < E) {
        int d = rowp[e + 1] - rowp[e];
        if (d > 255) d = 255;
        atomicAdd(&h[d], 1);
        atomicAdd(&ecnt[gd[e]], 1);
    }
    __syncthreads();
    if (h[tid]) atomicAdd(&dcnt[tid], h[tid]);
}

// merged: degscatter (blocks [0, nbE)) + erowp scan_final (blocks [nbE, +nbN))
__global__ __launch_bounds__(256) void k_degscat_final(
    const int* __restrict__ rowp, const int* __restrict__ doff,
    int* __restrict__ dcur, int* __restrict__ eperm, int E, int nbE,
    int* __restrict__ ecnt, const int* __restrict__ bsum,
    int* __restrict__ erowp, int N) {
    int tid = threadIdx.x;
    if ((int)blockIdx.x < nbE) {
        __shared__ int lcnt[256];
        __shared__ int base[256];
        lcnt[tid] = 0;
        __syncthreads();
        int e = blockIdx.x * 256 + tid;
        int d = 0, rk = 0;
        if (e < E) {
            d = rowp[e + 1] - rowp[e];
            if (d > 255) d = 255;
            rk = atomicAdd(&lcnt[d], 1);
        }
        __syncthreads();
        if (lcnt[tid]) base[tid] = atomicAdd(&dcur[tid], lcnt[tid]);
        __syncthreads();
        // DESCENDING degree order (LPT; R24)
        if (e < E) eperm[E - 1 - (doff[d] + base[d] + rk)] = e;
    } else {
        __shared__ int sm[256];
        int bb = blockIdx.x - nbE;
        int i = bb * 256 + tid;
        int v = (i < N) ? ecnt[i] : 0;
        sm[tid] = v;
        __syncthreads();
        for (int off = 1; off < 256; off <<= 1) {
            int u = (tid >= off) ? sm[tid - off] : 0;
            __syncthreads();
            sm[tid] += u;
            __syncthreads();
        }
        if (i < N) {
            erowp[i] = bsum[bb] + sm[tid] - v;
            ecnt[i] = 0;                       // cursor for escatter
        }
        if (i == 0) erowp[N] = E;
    }
}

// epos[e] = CSR slot of edge e under its destination node (for msg layout)
__global__ void k_escatter(const int* __restrict__ gd, const int* __restrict__ erowp,
                           int* __restrict__ cursor, int* __restrict__ epos, int E) {
    int e = blockIdx.x * blockDim.x + threadIdx.x;
    if (e >= E) return;
    int n = gd[e];
    int pos = erowp[n] + atomicAdd(&cursor[n], 1);
    epos[e] = pos;
}

// MFMA node_proj: xs = x@Wsrc + bs, xd = x@Wdst + bd (bf16 out, R26).
__global__ __launch_bounds__(256) void k_node_proj(
    const bf16_t* __restrict__ xb,
    const bf16_t* __restrict__ Wst, const float* __restrict__ bs,
    const bf16_t* __restrict__ Wdt, const float* __restrict__ bd,
    bf16_t* __restrict__ xs, bf16_t* __restrict__ xd, int N) {
    __shared__ bf16_t wsl[64 * WPAD];
    __shared__ bf16_t wdl[64 * WPAD];
    int tid = threadIdx.x;
    for (int i = tid; i < 2048; i += 256) {
        int row = i >> 5, inw = i & 31;
        *(uint4*)&wsl[row * WPAD + inw * 8] =
            *(const uint4*)&Wst[(size_t)row * DMODEL + inw * 8];
        *(uint4*)&wdl[row * WPAD + inw * 8] =
            *(const uint4*)&Wdt[(size_t)row * DMODEL + inw * 8];
    }
    __syncthreads();
    int w = tid >> 6, lane = tid & 63;
    int col = lane & 15, quad = lane >> 4;
    int m0 = blockIdx.x * 64 + w * 16;
    f4 as[4] = {{0.f,0.f,0.f,0.f},{0.f,0.f,0.f,0.f},
                {0.f,0.f,0.f,0.f},{0.f,0.f,0.f,0.f}};
    f4 ad[4] = {{0.f,0.f,0.f,0.f},{0.f,0.f,0.f,0.f},
                {0.f,0.f,0.f,0.f},{0.f,0.f,0.f,0.f}};
    #pragma unroll
    for (int k0 = 0; k0 < DMODEL; k0 += 32) {
        s8v a = *(const s8v*)&xb[(size_t)(m0 + col) * DMODEL + k0 + quad * 8];
        #pragma unroll
        for (int t = 0; t < 4; ++t) {
            s8v b1v = *(const s8v*)&wsl[(t * 16 + col) * WPAD + k0 + quad * 8];
            as[t] = __builtin_amdgcn_mfma_f32_16x16x32_bf16(a, b1v, as[t], 0, 0, 0);
            s8v b2v = *(const s8v*)&wdl[(t * 16 + col) * WPAD + k0 + quad * 8];
            ad[t] = __builtin_amdgcn_mfma_f32_16x16x32_bf16(a, b2v, ad[t], 0, 0, 0);
        }
    }
    #pragma unroll
    for (int t = 0; t < 4; ++t) {
        int c = t * 16 + col;
        float bsv = bs[c], bdv = bd[c];
        #pragma unroll
        for (int r = 0; r < 4; ++r) {
            int m = m0 + quad * 4 + r;
            if (m < N) {
                xs[(size_t)m * DM + c] = f2bf(as[t][r] + bsv);
                xd[(size_t)m * DM + c] = f2bf(ad[t][r] + bdv);
            }
        }
    }
}

// MFMA k_xij: xij[e][c] = (RBF(bl[e]) @ Wedge)[c] + xs[gs[e]][c] + xd[gd[e]][c] + be[c]
__global__ __launch_bounds__(256) void k_xij(
    const float* __restrict__ bl, const bf16_t* __restrict__ Wedgt,
    const float* __restrict__ be,
    const bf16_t* __restrict__ xs, const bf16_t* __restrict__ xd,
    const int* __restrict__ gs, const int* __restrict__ gd,
    bf16_t* __restrict__ xij, int E) {
    __shared__ bf16_t wel[64 * WPAD];
    int tid = threadIdx.x;
    for (int i = tid; i < 2048; i += 256) {
        int row = i >> 5, inw = i & 31;
        *(uint4*)&wel[row * WPAD + inw * 8] =
            *(const uint4*)&Wedgt[(size_t)row * DMODEL + inw * 8];
    }
    __syncthreads();
    int w = tid >> 6, lane = tid & 63;
    int col = lane & 15, quad = lane >> 4;
    int m0 = blockIdx.x * 64 + w * 16;
    const float step = 8.0f / 255.0f;
    const float gamma = (255.0f / 8.0f) * (255.0f / 8.0f);
    int me = m0 + col;
    float blv = (me < E) ? bl[me] : 0.f;
    f4 acc[4] = {{0.f,0.f,0.f,0.f},{0.f,0.f,0.f,0.f},
                 {0.f,0.f,0.f,0.f},{0.f,0.f,0.f,0.f}};
    #pragma unroll
    for (int k0 = 0; k0 < DMODEL; k0 += 32) {
        s8v a;
        #pragma unroll
        for (int j = 0; j < 8; ++j) {
            float c = (float)(k0 + quad * 8 + j) * step;
            float dd = blv - c;
            a[j] = (short)f2bf(__expf(-gamma * dd * dd));
        }
        #pragma unroll
        for (int t = 0; t < 4; ++t) {
            s8v b = *(const s8v*)&wel[(t * 16 + col) * WPAD + k0 + quad * 8];
            acc[t] = __builtin_amdgcn_mfma_f32_16x16x32_bf16(a, b, acc[t], 0, 0, 0);
        }
    }
    #pragma unroll
    for (int r = 0; r < 4; ++r) {
        int e = m0 + quad * 4 + r;
        if (e >= E) continue;
        int s = gs[e], d2 = gd[e];
        #pragma unroll
        for (int t = 0; t < 4; ++t) {
            int c = t * 16 + col;
            float v = acc[t][r] + bf2f(xs[(size_t)s * DM + c])
                    + bf2f(xd[(size_t)d2 * DM + c]) + be[c];
            xij[(size_t)e * DM + c] = f2bf(v);
        }
    }
}

// Fused logit+softmax+attend: 4 lanes per edge (degree-sorted via eperm),
// 16 channels per lane. Chebyshev T_k(d); 2-shfl reduce. msg at epos[e].
__global__ __launch_bounds__(256) void k_edge_attn(
    const bf16_t* __restrict__ xij, const int2* __restrict__ packed,
    const int* __restrict__ rowp, const float* __restrict__ attn_l,
    const int* __restrict__ eperm, const int* __restrict__ epos,
    bf16_t* __restrict__ msg, int E) {
    int gtid = blockIdx.x * 256 + threadIdx.x;
    int ei = gtid >> 2;
    if (ei >= E) return;
    int q = gtid & 3;                  // channel block [16q, 16q+16)
    int e = eperm[ei];
    int beg = rowp[e], end = rowp[e + 1];

    float av[16];
    #pragma unroll
    for (int c = 0; c < 16; ++c) av[c] = attn_l[q * 16 + c];

    uint4 xe0, xe1;
    {
        const uint4* xer = (const uint4*)&xij[(size_t)e * DM + q * 16];
        xe0 = xer[0]; xe1 = xer[1];
    }
    float acc[16];
    #pragma unroll
    for (int c = 0; c < 16; ++c) acc[c] = 0.f;
    float den = 0.f;

    if (beg < end) {
        int2 pk0 = packed[beg];
        int2 pk1 = (beg + 1 < end) ? packed[beg + 1] : pk0;
        const uint4* s0 = (const uint4*)&xij[(size_t)pk0.x * DM + q * 16];
        uint4 nsa = s0[0], nsb = s0[1];
        for (int p = beg; p < end; ++p) {
            float d = __int_as_float(pk0.y);
            uint4 xa = nsa, xb = nsb;
            if (p + 1 < end) {
                const uint4* sn = (const uint4*)&xij[(size_t)pk1.x * DM + q * 16];
                nsa = sn[0]; nsb = sn[1];
                pk0 = pk1;
                if (p + 2 < end) pk1 = packed[p + 2];
            }
            float d2 = d + d;
            float t2  = fmaf(d2, d, -1.f);
            float t3  = fmaf(d2, t2, -d);
            float t4  = fmaf(t2 + t2, t2, -1.f);
            float t7  = fmaf(t4 + t4, t3, -d);
            float t8  = fmaf(t4 + t4, t4, -1.f);
            float t15 = fmaf(t8 + t8, t7, -d);
            float t16 = fmaf(t8 + t8, t8, -1.f);
            float t17 = fmaf(t16 + t16, d, -t15);
            float t31 = fmaf(t16 + t16, t15, -d);
            float t32 = fmaf(t16 + t16, t16, -1.f);
            float t33 = fmaf(t32 + t32, d, -t31);
            float t48 = fmaf(t32 + t32, t16, -t16);
            float t49 = fmaf(t32 + t32, t17, -t15);
            float za, zb;                        // T_{16q}, T_{16q+1}
            if (q == 0)      { za = 1.f;  zb = d;   }
            else if (q == 1) { za = t16;  zb = t17; }
            else if (q == 2) { za = t32;  zb = t33; }
            else             { za = t48;  zb = t49; }
            float logit = 0.f;
            #define CH2(uw, ew, c)                                            \
            {                                                                 \
                float u0 = za + bf_lo(uw) + bf_lo(ew);                        \
                float zn = fmaf(d2, zb, -za); za = zb; zb = zn;               \
                float u1 = za + bf_hi(uw) + bf_hi(ew);                        \
                zn = fmaf(d2, zb, -za); za = zb; zb = zn;                     \
                logit = fmaf(silu_f(u0), av[c], logit);                       \
                logit = fmaf(silu_f(u1), av[c + 1], logit);                   \
            }
            CH2(xa.x, xe0.x, 0);
            CH2(xa.y, xe0.y, 2);
            CH2(xa.z, xe0.z, 4);
            CH2(xa.w, xe0.w, 6);
            CH2(xb.x, xe1.x, 8);
            CH2(xb.y, xe1.y, 10);
            CH2(xb.z, xe1.z, 12);
            CH2(xb.w, xe1.w, 14);
            #undef CH2
            logit += __shfl_xor(logit, 1, 64);
            logit += __shfl_xor(logit, 2, 64);
            float wg = __expf(logit);
            den += wg;
            acc[0]  = fmaf(wg, bf_lo(xa.x), acc[0]);
            acc[1]  = fmaf(wg, bf_hi(xa.x), acc[1]);
            acc[2]  = fmaf(wg, bf_lo(xa.y), acc[2]);
            acc[3]  = fmaf(wg, bf_hi(xa.y), acc[3]);
            acc[4]  = fmaf(wg, bf_lo(xa.z), acc[4]);
            acc[5]  = fmaf(wg, bf_hi(xa.z), acc[5]);
            acc[6]  = fmaf(wg, bf_lo(xa.w), acc[6]);
            acc[7]  = fmaf(wg, bf_hi(xa.w), acc[7]);
            acc[8]  = fmaf(wg, bf_lo(xb.x), acc[8]);
            acc[9]  = fmaf(wg, bf_hi(xb.x), acc[9]);
            acc[10] = fmaf(wg, bf_lo(xb.y), acc[10]);
            acc[11] = fmaf(wg, bf_hi(xb.y), acc[11]);
            acc[12] = fmaf(wg, bf_lo(xb.z), acc[12]);
            acc[13] = fmaf(wg, bf_hi(xb.z), acc[13]);
            acc[14] = fmaf(wg, bf_lo(xb.w), acc[14]);
            acc[15] = fmaf(wg, bf_hi(xb.w), acc[15]);
        }
    }
    float inv = (den > 0.f) ? 1.f / den : 0.f;
    uint4 o0, o1;
    o0.x = (unsigned int)f2bf(acc[0] * inv)  | ((unsigned int)f2bf(acc[1] * inv) << 16);
    o0.y = (unsigned int)f2bf(acc[2] * inv)  | ((unsigned int)f2bf(acc[3] * inv) << 16);
    o0.z = (unsigned int)f2bf(acc[4] * inv)  | ((unsigned int)f2bf(acc[5] * inv) << 16);
    o0.w = (unsigned int)f2bf(acc[6] * inv)  | ((unsigned int)f2bf(acc[7] * inv) << 16);
    o1.x = (unsigned int)f2bf(acc[8] * inv)  | ((unsigned int)f2bf(acc[9] * inv) << 16);
    o1.y = (unsigned int)f2bf(acc[10] * inv) | ((unsigned int)f2bf(acc[11] * inv) << 16);
    o1.z = (unsigned int)f2bf(acc[12] * inv) | ((unsigned int)f2bf(acc[13] * inv) << 16);
    o1.w = (unsigned int)f2bf(acc[14] * inv) | ((unsigned int)f2bf(acc[15] * inv) << 16);
    int mrow = epos[e];
    uint4* op = (uint4*)&msg[(size_t)mrow * DM + q * 16];
    op[0] = o0;
    op[1] = o1;
}

// thread per (node, channel-quad): sum bf16 msg rows (CSR-contiguous).
__global__ __launch_bounds__(256) void k_aggregate(
    const bf16_t* __restrict__ msg, const int* __restrict__ erowp,
    bf16_t* __restrict__ ft, int N) {
    int gtid = blockIdx.x * 256 + threadIdx.x;
    int n = gtid >> 4;
    if (n >= N) return;
    int quad = gtid & 15;
    int beg = erowp[n], end = erowp[n + 1];
    float a0 = 0.f, a1 = 0.f, a2 = 0.f, a3 = 0.f;
    for (int j = beg; j < end; ++j) {
        uint2 uv = *(const uint2*)&msg[(size_t)j * DM + quad * 4];
        a0 += bf_lo(uv.x); a1 += bf_hi(uv.x);
        a2 += bf_lo(uv.y); a3 += bf_hi(uv.y);
    }
    ushort4 o = {f2bf(a0), f2bf(a1), f2bf(a2), f2bf(a3)};
    *(ushort4*)&ft[(size_t)n * DM + quad * 4] = o;
}

// Fused FFN: x = silu(ft@W1 + b1) @ W2 + b2; h never leaves the CU. (R23)
__global__ __launch_bounds__(256) void k_ffn_fused(
    const bf16_t* __restrict__ ft, const bf16_t* __restrict__ W1t,
    const float* __restrict__ b1, const bf16_t* __restrict__ W2t,
    const float* __restrict__ b2, bf16_t* __restrict__ x, int N) {
    __shared__ bf16_t w1s[2][64 * 72];
    __shared__ bf16_t w2s[2][64 * 72];
    __shared__ bf16_t hld[4][16 * 72];
    __shared__ float b1s[HDIM];
    int tid = threadIdx.x;
    int w = tid >> 6, lane = tid & 63;
    int col = lane & 15, quad = lane >> 4;
    int m0 = blockIdx.x * 64 + w * 16;
    int c0 = blockIdx.y * 64;
    bf16_t* myl = hld[w];

    #pragma unroll
    for (int j = 0; j < 4; ++j) b1s[tid + j * 256] = b1[tid + j * 256];

    s8v fa0 = *(const s8v*)&ft[(size_t)(m0 + col) * DM + quad * 8];
    s8v fa1 = *(const s8v*)&ft[(size_t)(m0 + col) * DM + 32 + quad * 8];

    int srow0 = tid >> 3;
    int srow1 = 32 + srow0;
    int skb = tid & 7;

    f4 acc[4] = {{0.f,0.f,0.f,0.f},{0.f,0.f,0.f,0.f},
                 {0.f,0.f,0.f,0.f},{0.f,0.f,0.f,0.f}};

    {
        uint4 a0 = *(const uint4*)&W1t[(size_t)srow0 * DM + skb * 8];
        uint4 a1 = *(const uint4*)&W1t[(size_t)srow1 * DM + skb * 8];
        uint4 c0v = *(const uint4*)&W2t[(size_t)(c0 + srow0) * HDIM + skb * 8];
        uint4 c1v = *(const uint4*)&W2t[(size_t)(c0 + srow1) * HDIM + skb * 8];
        *(uint4*)&w1s[0][srow0 * 72 + skb * 8] = a0;
        *(uint4*)&w1s[0][srow1 * 72 + skb * 8] = a1;
        *(uint4*)&w2s[0][srow0 * 72 + skb * 8] = c0v;
        *(uint4*)&w2s[0][srow1 * 72 + skb * 8] = c1v;
    }
    __syncthreads();

    #pragma unroll 1
    for (int kc = 0; kc < 16; ++kc) {
        int cb = kc & 1, nb = cb ^ 1;
        int ch0 = kc * 64;
        int chn = (kc < 15) ? ch0 + 64 : ch0;
        uint4 na0 = *(const uint4*)&W1t[(size_t)(chn + srow0) * DM + skb * 8];
        uint4 na1 = *(const uint4*)&W1t[(size_t)(chn + srow1) * DM + skb * 8];
        uint4 nc0 = *(const uint4*)&W2t[(size_t)(c0 + srow0) * HDIM + chn + skb * 8];
        uint4 nc1 = *(const uint4*)&W2t[(size_t)(c0 + srow1) * HDIM + chn + skb * 8];
        #pragma unroll
        for (int th = 0; th < 4; ++th) {
            s8v wb0 = *(const s8v*)&w1s[cb][(th * 16 + col) * 72 + quad * 8];
            s8v wb1 = *(const s8v*)&w1s[cb][(th * 16 + col) * 72 + 32 + quad * 8];
            f4 hv = {0.f, 0.f, 0.f, 0.f};
            hv = __builtin_amdgcn_mfma_f32_16x16x32_bf16(fa0, wb0, hv, 0, 0, 0);
            hv = __builtin_amdgcn_mfma_f32_16x16x32_bf16(fa1, wb1, hv, 0, 0, 0);
            float bb = b1s[ch0 + th * 16 + col];
            #pragma unroll
            for (int r = 0; r < 4; ++r)
                myl[(quad * 4 + r) * 72 + th * 16 + col] =
                    f2bf(silu_f(hv[r] + bb));
        }
        s8v ha0 = *(const s8v*)&myl[col * 72 + quad * 8];
        s8v ha1 = *(const s8v*)&myl[col * 72 + 32 + quad * 8];
        #pragma unroll
        for (int t2 = 0; t2 < 4; ++t2) {
            s8v vb0 = *(const s8v*)&w2s[cb][(t2 * 16 + col) * 72 + quad * 8];
            s8v vb1 = *(const s8v*)&w2s[cb][(t2 * 16 + col) * 72 + 32 + quad * 8];
            acc[t2] = __builtin_amdgcn_mfma_f32_16x16x32_bf16(ha0, vb0, acc[t2], 0, 0, 0);
            acc[t2] = __builtin_amdgcn_mfma_f32_16x16x32_bf16(ha1, vb1, acc[t2], 0, 0, 0);
        }
        __syncthreads();
        if (kc < 15) {
            *(uint4*)&w1s[nb][srow0 * 72 + skb * 8] = na0;
            *(uint4*)&w1s[nb][srow1 * 72 + skb * 8] = na1;
            *(uint4*)&w2s[nb][srow0 * 72 + skb * 8] = nc0;
            *(uint4*)&w2s[nb][srow1 * 72 + skb * 8] = nc1;
        }
        __syncthreads();
    }
    #pragma unroll
    for (int t2 = 0; t2 < 4; ++t2) {
        int c = c0 + t2 * 16 + col;
        float bb = b2[c];
        #pragma unroll
        for (int r = 0; r < 4; ++r) {
            int m = m0 + quad * 4 + r;
            if (m < N) x[(size_t)m * DMODEL + c] = f2bf(acc[t2][r] + bb);
        }
    }
}

// grid-stride dot over bf16 x; self-finalizing (last block writes output).
__global__ __launch_bounds__(256) void k_out_reduce(
    const bf16_t* __restrict__ x, const float* __restrict__ Wfc,
    float* __restrict__ acc, const float* __restrict__ bfc,
    float* __restrict__ out, float invN, int NT) {
    __shared__ float sm[4];
    int tid = threadIdx.x;
    float v = 0.f;
    int np = NT / 2;
    const unsigned int* xp = (const unsigned int*)x;
    for (int i = blockIdx.x * blockDim.x + tid; i < np; i += gridDim.x * blockDim.x) {
        unsigned int u = xp[i];
        int c = (2 * i) & (DMODEL - 1);
        v = fmaf(bf_lo(u), Wfc[c], v);
        v = fmaf(bf_hi(u), Wfc[c + 1], v);
    }
    for (int off = 32; off > 0; off >>= 1) v += __shfl_xor(v, off, 64);
    if ((tid & 63) == 0) sm[tid >> 6] = v;
    __syncthreads();
    if (tid == 0) {
        float s = sm[0] + sm[1] + sm[2] + sm[3];
        atomicAdd(&acc[0], s);
        __threadfence();
        unsigned int prev = atomicAdd((unsigned int*)&acc[1], 1u);
        if (prev == gridDim.x - 1) {
            float tot = atomicAdd(&acc[0], 0.0f);   // coherent read of final sum
            out[0] = tot * invN + bfc[0];
        }
    }
}

extern "C" void kernel_launch(void* const* d_in, const int* in_sizes, int n_in,
                              void* d_out, int out_size, void* d_ws, size_t ws_size,
                              hipStream_t stream) {
    const int*   an    = (const int*)d_in[0];
    const int*   gs    = (const int*)d_in[1];
    const int*   gd    = (const int*)d_in[2];
    const int*   ts    = (const int*)d_in[3];
    const int*   td    = (const int*)d_in[4];
    const float* r     = (const float*)d_in[5];
    const float* emb   = (const float*)d_in[6];
    const float* Wsrc  = (const float*)d_in[7];
    const float* bsrc  = (const float*)d_in[8];
    const float* Wdst  = (const float*)d_in[9];
    const float* bdst  = (const float*)d_in[10];
    const float* Wedge = (const float*)d_in[11];
    const float* bedge = (const float*)d_in[12];
    const float* attn  = (const float*)d_in[13];
    const float* W1    = (const float*)d_in[14];
    const float* b1    = (const float*)d_in[15];
    const float* W2    = (const float*)d_in[16];
    const float* b2    = (const float*)d_in[17];
    const float* Wfc   = (const float*)d_in[18];
    const float* bfc   = (const float*)d_in[19];

    const int N = in_sizes[0];
    const int E = in_sizes[1];
    const int T = in_sizes[3];
    const int NB = (E + 511) >> BSH;          // triplet-sort buckets

    char* w = (char*)d_ws;
    size_t off = 0;
    auto alloc = [&](size_t bytes) {
        void* p = w + off;
        off += (bytes + 255) & ~(size_t)255;
        return p;
    };
    // ---- zero region (one memset covers all of these, in order) ----
    int*    gbcnt  = (int*)   alloc(NBMAX * 4);   // 1280 (256-mult)
    int*    bcur   = (int*)   alloc(NBMAX * 4);   // 1280
    int*    dcnt   = (int*)   alloc(1024);
    int*    dcur   = (int*)   alloc(1024);
    int*    ecnt   = (int*)   alloc((size_t)N * 4);          // -> 40192 padded
    float*  accs   = (float*) alloc(64);                     // -> 256 padded
    const size_t zero_bytes = (size_t)(1280 + 1280 + 1024 + 1024 + 40192 + 256);
    // ---- rest ----
    bf16_t* xb     = (bf16_t*)alloc((size_t)(N + 64) * DMODEL * 2);
    float*  rn     = (float*) alloc((size_t)E * 3 * 4);
    float*  bl     = (float*) alloc(((size_t)E + 64) * 4);
    int*    rowp   = (int*)   alloc(((size_t)E + 1) * 4);
    int*    bsum   = (int*)   alloc(4096);
    int2*   packed = (int2*)  alloc((size_t)T * 8);
    int2*   ipair  = (int2*)  alloc((size_t)T * 8);
    float*  idv    = (float*) alloc((size_t)T * 4);
    int*    bbase  = (int*)   alloc((NBMAX + 1) * 4);
    int*    erowp  = (int*)   alloc(((size_t)N + 1) * 4);
    int*    epos   = (int*)   alloc((size_t)E * 4);
    int*    eperm  = (int*)   alloc((size_t)E * 4);
    bf16_t* xs     = (bf16_t*)alloc((size_t)N * DM * 2);
    bf16_t* xd     = (bf16_t*)alloc((size_t)N * DM * 2);
    bf16_t* xij    = (bf16_t*)alloc((size_t)E * DM * 2);
    bf16_t* msg    = (bf16_t*)alloc((size_t)E * DM * 2);
    bf16_t* ft     = (bf16_t*)alloc((size_t)(N + 64) * DM * 2);
    bf16_t* W1t    = (bf16_t*)alloc((size_t)3 * HDIM * DM * 2);
    bf16_t* W2t    = (bf16_t*)alloc((size_t)3 * DMODEL * HDIM * 2);
    bf16_t* Wedgt  = (bf16_t*)alloc((size_t)3 * DM * DMODEL * 2);
    bf16_t* Wst    = (bf16_t*)alloc((size_t)3 * DM * DMODEL * 2);
    bf16_t* Wdt    = (bf16_t*)alloc((size_t)3 * DM * DMODEL * 2);
    (void)ws_size; (void)n_in; (void)out_size;

    const int nbScanN = (N + 255) / 256;      // 40
    const int nbE = (E + 255) / 256;          // 625
    const int nbT = (T + 4095) / 4096;

    // ---- setup ----
    hipMemsetAsync(gbcnt, 0, zero_bytes, stream);            // all counters+accs
    k_prep<<<N + nbE, 256, 0, stream>>>(an, emb, xb, r, bl, rn, N, E);
    k_castT_all<<<1104, 256, 0, stream>>>(W1, W2, Wedge, Wsrc, Wdst,
                                          W1t, W2t, Wedgt, Wst, Wdt);
    // triplet CSR by t_dst: two-level bucket sort
    k_bhist<<<nbT, 512, 0, stream>>>(td, gbcnt, T, NB);
    k_bscan<<<1, 512, 0, stream>>>(gbcnt, bbase, NB, T);
    k_passA<<<nbT, 512, 0, stream>>>(ts, td, rn, bbase, bcur, ipair, idv, T, NB);
    k_passB<<<NB, 512, 0, stream>>>(ipair, idv, bbase, packed, rowp, E, T);
    // degree hist + gd hist (merged), then the two scans (merged), then
    // degscatter + erowp scan_final (merged), then escatter
    k_deg_ghist<<<nbE, 256, 0, stream>>>(rowp, dcnt, gd, ecnt, E);
    k_scan_part<<<nbScanN, 256, 0, stream>>>(ecnt, bsum, N);
    k_scan2<<<2, 1024, 0, stream>>>(dcnt, bsum, nbScanN);
    k_degscat_final<<<nbE + nbScanN, 256, 0, stream>>>(
        rowp, dcnt, dcur, eperm, E, nbE, ecnt, bsum, erowp, N);
    k_escatter<<<nbE, 256, 0, stream>>>(gd, erowp, ecnt, epos, E);

    // ---- layers ----
    for (int l = 0; l < 3; ++l) {
        k_node_proj<<<(N + 63) / 64, 256, 0, stream>>>(
            xb, Wst + (size_t)l * DM * DMODEL, bsrc + l * DM,
            Wdt + (size_t)l * DM * DMODEL, bdst + l * DM, xs, xd, N);
        k_xij<<<(E + 63) / 64, 256, 0, stream>>>(
            bl, Wedgt + (size_t)l * DM * DMODEL, bedge + l * DM,
            xs, xd, gs, gd, xij, E);
        k_edge_attn<<<(E * 4 + 255) / 256, 256, 0, stream>>>(
            xij, packed, rowp, attn + l * DM, eperm, epos, msg, E);
        k_aggregate<<<(N * 16 + 255) / 256, 256, 0, stream>>>(
            msg, erowp, ft, N);
        k_ffn_fused<<<dim3((N + 63) / 64, 4), 256, 0, stream>>>(
            ft, W1t + (size_t)l * HDIM * DM, b1 + l * HDIM,
            W2t + (size_t)l * DMODEL * HDIM, b2 + l * DMODEL, xb, N);
    }

    // ---- output head (self-finalizing) ----
    k_out_reduce<<<120, 256, 0, stream>>>(xb, Wfc, accs, bfc, (float*)d_out,
                                          1.0f / (float)N, N * DMODEL);
}